// Round 1
// baseline (4809.959 us; speedup 1.0000x reference)
//
#include <hip/hip_runtime.h>
#include <math.h>

// Traffic foundation model: emb-concat proj -> RMSNorm -> 2x(attn + top2-MoE) -> RMSNorm
// Round 0: correct fp32 implementation. B=4 S=1024 D=768 H=12 HD=64 L=2 E=8 F=3072 K=2
// T = B*S = 4096 tokens.

#define TTOK 4096
#define DMODEL 768
#define SEQLEN 1024
#define NHEAD 12
#define HDIM 64
#define NEXP 8
#define FDIM 3072
#define MAXSLOT 8704   // 8192 slots + up to 8*63 padding, 64-aligned

// ---------------------------------------------------------------- small kernels

__global__ void rope_cache_k(float* __restrict__ cosb, float* __restrict__ sinb) {
  int s = blockIdx.x, i = threadIdx.x;                 // grid 1024 x 32
  float inv = powf(10000.0f, -(float)i / 32.0f);       // 10000^(-i/32)
  float a = (float)s * inv;
  cosb[s * 32 + i] = cosf(a);
  sinb[s * 32 + i] = sinf(a);
}

__global__ void build_ctx_k(const int* ts, const int* dow, const int* mon, const int* hol,
                            const int* loc, const int* road, const int* wth,
                            const float* te, const float* de, const float* me, const float* he,
                            const float* le, const float* re, const float* we,
                            float* __restrict__ ctx) {
  int b = blockIdx.x;
  int j = blockIdx.y * 256 + threadIdx.x;              // grid (4,6) x 256 -> j<1536
  float v;
  if (j < 192)       v = te[ts[b] * 192 + j];
  else if (j < 384)  v = de[dow[b] * 192 + (j - 192)];
  else if (j < 576)  v = me[mon[b] * 192 + (j - 384)];
  else if (j < 768)  v = he[hol[b] * 192 + (j - 576)];
  else if (j < 1152) v = le[loc[b] * 384 + (j - 768)];
  else if (j < 1344) v = re[road[b] * 192 + (j - 1152)];
  else               v = we[wth[b] * 192 + (j - 1344)];
  ctx[b * 1536 + j] = v;
}

// biasB[b][d] = proj_b[d] + sum_j ctx[b][j] * proj_w[768+j][d]
__global__ void build_bias_k(const float* __restrict__ ctx, const float* __restrict__ pw,
                             const float* __restrict__ pb, float* __restrict__ biasB) {
  int b = blockIdx.x;
  int d = blockIdx.y * 256 + threadIdx.x;              // grid (4,3) x 256
  float s = pb[d];
  const float* cb = ctx + b * 1536;
  for (int j = 0; j < 1536; ++j) s += cb[j] * pw[(size_t)(768 + j) * 768 + d];
  biasB[b * 768 + d] = s;
}

__global__ __launch_bounds__(256) void rmsnorm_k(const float* __restrict__ xin,
                                                 const float* __restrict__ w,
                                                 float* __restrict__ y) {
  int t = blockIdx.x;
  int tid = threadIdx.x;
  const float* xr = xin + (size_t)t * 768;
  float v0 = xr[tid], v1 = xr[tid + 256], v2 = xr[tid + 512];
  float ss = v0 * v0 + v1 * v1 + v2 * v2;
  #pragma unroll
  for (int o = 32; o > 0; o >>= 1) ss += __shfl_xor(ss, o);
  __shared__ float wss[4];
  if ((tid & 63) == 0) wss[tid >> 6] = ss;
  __syncthreads();
  float tot = wss[0] + wss[1] + wss[2] + wss[3];
  float inv = 1.0f / sqrtf(tot / 768.0f + 1e-6f);
  float* yr = y + (size_t)t * 768;
  yr[tid]       = v0 * inv * w[tid];
  yr[tid + 256] = v1 * inv * w[tid + 256];
  yr[tid + 512] = v2 * inv * w[tid + 512];
}

__global__ __launch_bounds__(256) void rope_apply_k(float* __restrict__ q, float* __restrict__ k,
                                                    const float* __restrict__ cosb,
                                                    const float* __restrict__ sinb) {
  int idx = blockIdx.x * 256 + threadIdx.x;            // grid 6144 -> T*H*32
  int j = idx & 31;
  int hh = (idx >> 5) % 12;
  int t = idx / 384;
  int s = t & 1023;
  float c = cosb[s * 32 + j], sn = sinb[s * 32 + j];
  size_t base = (size_t)t * 768 + hh * 64 + j;
  float q1 = q[base], q2 = q[base + 32];
  q[base]      = q1 * c - q2 * sn;
  q[base + 32] = q2 * c + q1 * sn;
  float k1 = k[base], k2 = k[base + 32];
  k[base]      = k1 * c - k2 * sn;
  k[base + 32] = k2 * c + k1 * sn;
}

// ---------------------------------------------------------------- generic fp32 GEMM
// C[M,N] = A[M,K] @ W[K,N]. BM=BN=64 BK=16, 256 threads, 4x4 per thread.
// MODE 0: store. MODE 1: A-row gather + per-(row/1024) bias add, store. MODE 2: C += result.
template <int MODE>
__global__ __launch_bounds__(256) void gemm_f32(const float* __restrict__ A,
                                                const float* __restrict__ W,
                                                float* __restrict__ C, int M, int N, int K,
                                                const int* __restrict__ gather,
                                                const float* __restrict__ rowBias) {
  __shared__ float As[16][68];  // [k][m], pad 68 keeps float4 reads 16B-aligned
  __shared__ float Bs[16][68];  // [k][n]
  int tid = threadIdx.x;
  int m0 = blockIdx.y * 64, n0 = blockIdx.x * 64;
  int lr = tid >> 2, lc = (tid & 3) << 2;   // A loader: row 0..63, col 0/4/8/12
  int br = tid >> 4, bc = (tid & 15) << 2;  // B loader: row 0..15, col 0..60
  const float* Arow;
  if (MODE == 1) Arow = A + (size_t)gather[m0 + lr] * K;
  else           Arow = A + (size_t)(m0 + lr) * K;
  float acc[4][4] = {};
  int ty4 = (tid >> 4) << 2, tx4 = (tid & 15) << 2;
  for (int k0 = 0; k0 < K; k0 += 16) {
    float4 av = *(const float4*)(Arow + k0 + lc);
    As[lc + 0][lr] = av.x; As[lc + 1][lr] = av.y; As[lc + 2][lr] = av.z; As[lc + 3][lr] = av.w;
    *(float4*)&Bs[br][bc] = *(const float4*)(W + (size_t)(k0 + br) * N + n0 + bc);
    __syncthreads();
    #pragma unroll
    for (int kk = 0; kk < 16; ++kk) {
      float4 a4 = *(const float4*)&As[kk][ty4];
      float4 b4 = *(const float4*)&Bs[kk][tx4];
      float aa[4] = {a4.x, a4.y, a4.z, a4.w};
      float bb[4] = {b4.x, b4.y, b4.z, b4.w};
      #pragma unroll
      for (int i = 0; i < 4; ++i)
        #pragma unroll
        for (int j = 0; j < 4; ++j) acc[i][j] += aa[i] * bb[j];
    }
    __syncthreads();
  }
  #pragma unroll
  for (int i = 0; i < 4; ++i) {
    int row = m0 + ty4 + i;
    #pragma unroll
    for (int j = 0; j < 4; ++j) {
      int col = n0 + tx4 + j;
      float v = acc[i][j];
      if (MODE == 1) v += rowBias[(row >> 10) * 768 + col];
      size_t idx = (size_t)row * N + col;
      if (MODE == 2) C[idx] += v;
      else           C[idx] = v;
    }
  }
}

// ---------------------------------------------------------------- attention (flash-style, fp32)
// grid (32 qtiles, 12 heads, 4 batch), 256 threads. 32q x 32k tiles, online softmax.
__global__ __launch_bounds__(256) void attn_k(const float* __restrict__ qg,
                                              const float* __restrict__ kg,
                                              const float* __restrict__ vg,
                                              float* __restrict__ og) {
  int qt = blockIdx.x, h = blockIdx.y, b = blockIdx.z;
  int q0 = qt * 32;
  int tid = threadIdx.x;
  __shared__ float qs[64][33];   // [d][qrow] transposed: kills stride-64 bank conflicts
  __shared__ float ks[64][33];   // [d][krow]
  __shared__ float vs[32][64];   // [krow][d]
  __shared__ float ps[32][33];
  __shared__ float rowm[32], rowl[32], rowc[32];
  int lr = tid >> 3;             // 0..31 (tile row for loads)
  int lc8 = (tid & 7) << 3;      // 0..56 (d-chunk for loads)
  size_t qbase = ((size_t)(b * 1024 + q0 + lr)) * 768 + h * 64 + lc8;
  float4 qa = *(const float4*)(qg + qbase);
  float4 qb4 = *(const float4*)(qg + qbase + 4);
  qs[lc8 + 0][lr] = qa.x;  qs[lc8 + 1][lr] = qa.y;  qs[lc8 + 2][lr] = qa.z;  qs[lc8 + 3][lr] = qa.w;
  qs[lc8 + 4][lr] = qb4.x; qs[lc8 + 5][lr] = qb4.y; qs[lc8 + 6][lr] = qb4.z; qs[lc8 + 7][lr] = qb4.w;
  if (tid < 32) { rowm[tid] = -3.0e38f; rowl[tid] = 0.0f; }
  float acc[8] = {0, 0, 0, 0, 0, 0, 0, 0};
  int myq = tid >> 3;            // 0..31: my query row
  int g = tid & 7;               // 8-lane group within the row (same wave)
  for (int kt = 0; kt <= qt; ++kt) {
    int k0 = kt * 32;
    size_t kbase = ((size_t)(b * 1024 + k0 + lr)) * 768 + h * 64 + lc8;
    float4 ka = *(const float4*)(kg + kbase);
    float4 kb4 = *(const float4*)(kg + kbase + 4);
    ks[lc8 + 0][lr] = ka.x;  ks[lc8 + 1][lr] = ka.y;  ks[lc8 + 2][lr] = ka.z;  ks[lc8 + 3][lr] = ka.w;
    ks[lc8 + 4][lr] = kb4.x; ks[lc8 + 5][lr] = kb4.y; ks[lc8 + 6][lr] = kb4.z; ks[lc8 + 7][lr] = kb4.w;
    *(float4*)&vs[lr][lc8]     = *(const float4*)(vg + kbase);
    *(float4*)&vs[lr][lc8 + 4] = *(const float4*)(vg + kbase + 4);
    __syncthreads();
    // scores: thread computes 4 keys (kc..kc+3) for row myq
    int kc = g << 2;
    float sc0 = 0, sc1 = 0, sc2 = 0, sc3 = 0;
    #pragma unroll 8
    for (int d = 0; d < 64; ++d) {
      float qv = qs[d][myq];
      sc0 += qv * ks[d][kc + 0];
      sc1 += qv * ks[d][kc + 1];
      sc2 += qv * ks[d][kc + 2];
      sc3 += qv * ks[d][kc + 3];
    }
    int qgl = q0 + myq;
    float s4[4] = {sc0, sc1, sc2, sc3};
    float mx = -3.0e38f;
    #pragma unroll
    for (int j = 0; j < 4; ++j) {
      s4[j] = (k0 + kc + j <= qgl) ? s4[j] * 0.125f : -3.0e38f;  // 1/sqrt(64), causal
      mx = fmaxf(mx, s4[j]);
    }
    mx = fmaxf(mx, __shfl_xor(mx, 4));
    mx = fmaxf(mx, __shfl_xor(mx, 2));
    mx = fmaxf(mx, __shfl_xor(mx, 1));
    float mold = rowm[myq];
    float mnew = fmaxf(mold, mx);
    float lsum = 0.0f;
    #pragma unroll
    for (int j = 0; j < 4; ++j) {
      float pp = expf(s4[j] - mnew);
      ps[myq][kc + j] = pp;
      lsum += pp;
    }
    lsum += __shfl_xor(lsum, 4);
    lsum += __shfl_xor(lsum, 2);
    lsum += __shfl_xor(lsum, 1);
    if (g == 0) {
      float c = expf(mold - mnew);
      rowc[myq] = c;
      rowl[myq] = rowl[myq] * c + lsum;
      rowm[myq] = mnew;
    }
    __syncthreads();
    float c = rowc[myq];
    #pragma unroll
    for (int j = 0; j < 8; ++j) acc[j] *= c;
    int db = g << 3;
    #pragma unroll 4
    for (int kk2 = 0; kk2 < 32; ++kk2) {
      float pp = ps[myq][kk2];
      #pragma unroll
      for (int j = 0; j < 8; ++j) acc[j] += pp * vs[kk2][db + j];
    }
    __syncthreads();
  }
  float invl = 1.0f / rowl[myq];
  size_t ob = ((size_t)(b * 1024 + q0 + myq)) * 768 + h * 64 + (g << 3);
  float4 o1 = make_float4(acc[0] * invl, acc[1] * invl, acc[2] * invl, acc[3] * invl);
  float4 o2 = make_float4(acc[4] * invl, acc[5] * invl, acc[6] * invl, acc[7] * invl);
  *(float4*)(og + ob) = o1;
  *(float4*)(og + ob + 4) = o2;
}

// ---------------------------------------------------------------- MoE routing
// wave per token: exact fp32 logits -> softmax -> top2 (first-occurrence ties = jax.top_k)
__global__ __launch_bounds__(256) void router_k(const float* __restrict__ xn,
                                                const float* __restrict__ rw,
                                                int* __restrict__ tk_idx, float* __restrict__ tk_w,
                                                int* __restrict__ cnt, float* __restrict__ psum) {
  __shared__ float bps[8];
  __shared__ int bcnt[8];
  int tid = threadIdx.x;
  if (tid < 8) { bps[tid] = 0.0f; bcnt[tid] = 0; }
  __syncthreads();
  int t = blockIdx.x * 4 + (tid >> 6);                 // grid 1024 x 256
  int lane = tid & 63;
  const float* xr = xn + (size_t)t * 768;
  float p[8] = {};
  for (int d = lane; d < 768; d += 64) {
    float xv = xr[d];
    const float* wr = rw + (size_t)d * 8;
    #pragma unroll
    for (int e = 0; e < 8; ++e) p[e] += xv * wr[e];
  }
  #pragma unroll
  for (int e = 0; e < 8; ++e) {
    float v = p[e];
    #pragma unroll
    for (int o = 32; o > 0; o >>= 1) v += __shfl_xor(v, o);
    p[e] = v;
  }
  if (lane == 0) {
    float mx = p[0];
    #pragma unroll
    for (int e = 1; e < 8; ++e) mx = fmaxf(mx, p[e]);
    float s = 0.0f;
    #pragma unroll
    for (int e = 0; e < 8; ++e) { p[e] = expf(p[e] - mx); s += p[e]; }
    float invs = 1.0f / s;
    #pragma unroll
    for (int e = 0; e < 8; ++e) p[e] *= invs;
    int i1 = 0; float v1 = p[0];
    #pragma unroll
    for (int e = 1; e < 8; ++e) if (p[e] > v1) { v1 = p[e]; i1 = e; }
    int i2 = (i1 == 0) ? 1 : 0; float v2 = p[i2];
    #pragma unroll
    for (int e = 0; e < 8; ++e) if (e != i1 && p[e] > v2) { v2 = p[e]; i2 = e; }
    float wsum = v1 + v2;
    tk_idx[t * 2] = i1; tk_idx[t * 2 + 1] = i2;
    tk_w[t * 2] = v1 / wsum; tk_w[t * 2 + 1] = v2 / wsum;
    atomicAdd(&bcnt[i1], 1); atomicAdd(&bcnt[i2], 1);
    #pragma unroll
    for (int e = 0; e < 8; ++e) atomicAdd(&bps[e], p[e]);
  }
  __syncthreads();
  if (tid < 8) {
    atomicAdd(&cnt[tid], bcnt[tid]);
    atomicAdd(&psum[tid], bps[tid]);
  }
}

// 64-aligned padded prefix offsets + aux-loss accumulation (single thread, trivial)
__global__ void moe_offsets_k(const int* __restrict__ cnt, int* __restrict__ offs,
                              const float* __restrict__ psum, float* __restrict__ aux) {
  if (threadIdx.x == 0) {
    int o = 0; float a = 0.0f;
    for (int e = 0; e < 8; ++e) {
      offs[e] = o;
      o += (cnt[e] + 63) & ~63;
      a += ((float)cnt[e] / 4096.0f) * (psum[e] / 4096.0f);
    }
    offs[8] = o;
    aux[0] += a * 8.0f;                                // * E
  }
}

__global__ void moe_fill_k(const int* __restrict__ tk_idx, const int* __restrict__ offs,
                           int* __restrict__ fill, int* __restrict__ slot_token,
                           int* __restrict__ tk_slot) {
  int i = blockIdx.x * 256 + threadIdx.x;              // grid 32 -> 8192 = T*K
  int e = tk_idx[i];
  int pos = atomicAdd(&fill[e], 1);
  int slot = offs[e] + pos;
  slot_token[slot] = i >> 1;
  tk_slot[i] = slot;
}

// expert stage A: h[slot] = silu(x@Wg[e]) * (x@Wu[e]), gathered rows, fused dual-GEMM
__global__ __launch_bounds__(256) void moe_gu_k(const float* __restrict__ xn,
                                                const float* __restrict__ Wg,
                                                const float* __restrict__ Wu,
                                                float* __restrict__ h,
                                                const int* __restrict__ slot_token,
                                                const int* __restrict__ offs) {
  __shared__ int so[9];
  __shared__ float As[16][68], Bg[16][68], Bu[16][68];
  int tid = threadIdx.x;
  if (tid < 9) so[tid] = offs[tid];
  __syncthreads();
  int sb = blockIdx.y * 64;                            // grid (48, 136)
  if (sb >= so[8]) return;
  int e = 0;
  #pragma unroll
  for (int i = 1; i < 8; ++i) if (sb >= so[i]) e = i;  // 64-blocks never straddle experts
  const float* Wge = Wg + (size_t)e * 768 * 3072;
  const float* Wue = Wu + (size_t)e * 768 * 3072;
  int n0 = blockIdx.x * 64;
  int lr = tid >> 2, lc = (tid & 3) << 2;
  int br = tid >> 4, bc = (tid & 15) << 2;
  int tok = slot_token[sb + lr];
  const float* Arow = xn + (size_t)(tok < 0 ? 0 : tok) * 768;
  float accg[4][4] = {}, accu[4][4] = {};
  int ty4 = (tid >> 4) << 2, tx4 = (tid & 15) << 2;
  for (int k0 = 0; k0 < 768; k0 += 16) {
    float4 av = make_float4(0.f, 0.f, 0.f, 0.f);
    if (tok >= 0) av = *(const float4*)(Arow + k0 + lc);
    As[lc + 0][lr] = av.x; As[lc + 1][lr] = av.y; As[lc + 2][lr] = av.z; As[lc + 3][lr] = av.w;
    *(float4*)&Bg[br][bc] = *(const float4*)(Wge + (size_t)(k0 + br) * 3072 + n0 + bc);
    *(float4*)&Bu[br][bc] = *(const float4*)(Wue + (size_t)(k0 + br) * 3072 + n0 + bc);
    __syncthreads();
    #pragma unroll
    for (int kk = 0; kk < 16; ++kk) {
      float4 a4 = *(const float4*)&As[kk][ty4];
      float4 g4 = *(const float4*)&Bg[kk][tx4];
      float4 u4 = *(const float4*)&Bu[kk][tx4];
      float aa[4] = {a4.x, a4.y, a4.z, a4.w};
      float gg[4] = {g4.x, g4.y, g4.z, g4.w};
      float uu[4] = {u4.x, u4.y, u4.z, u4.w};
      #pragma unroll
      for (int i = 0; i < 4; ++i)
        #pragma unroll
        for (int j = 0; j < 4; ++j) { accg[i][j] += aa[i] * gg[j]; accu[i][j] += aa[i] * uu[j]; }
    }
    __syncthreads();
  }
  #pragma unroll
  for (int i = 0; i < 4; ++i) {
    size_t rowoff = (size_t)(sb + ty4 + i) * 3072 + n0 + tx4;
    #pragma unroll
    for (int j = 0; j < 4; ++j) {
      float gv = accg[i][j], uv = accu[i][j];
      h[rowoff + j] = gv / (1.0f + expf(-gv)) * uv;    // silu(g)*u
    }
  }
}

// expert stage B: os[slot] = h[slot] @ Wd[e]  (K=3072)
__global__ __launch_bounds__(256) void moe_d_k(const float* __restrict__ h,
                                               const float* __restrict__ Wd,
                                               float* __restrict__ os,
                                               const int* __restrict__ offs) {
  __shared__ int so[9];
  __shared__ float As[16][68], Bs[16][68];
  int tid = threadIdx.x;
  if (tid < 9) so[tid] = offs[tid];
  __syncthreads();
  int sb = blockIdx.y * 64;                            // grid (12, 136)
  if (sb >= so[8]) return;
  int e = 0;
  #pragma unroll
  for (int i = 1; i < 8; ++i) if (sb >= so[i]) e = i;
  const float* Wde = Wd + (size_t)e * 3072 * 768;
  int n0 = blockIdx.x * 64;
  int lr = tid >> 2, lc = (tid & 3) << 2;
  int br = tid >> 4, bc = (tid & 15) << 2;
  const float* Arow = h + (size_t)(sb + lr) * 3072;
  float acc[4][4] = {};
  int ty4 = (tid >> 4) << 2, tx4 = (tid & 15) << 2;
  for (int k0 = 0; k0 < 3072; k0 += 16) {
    float4 av = *(const float4*)(Arow + k0 + lc);
    As[lc + 0][lr] = av.x; As[lc + 1][lr] = av.y; As[lc + 2][lr] = av.z; As[lc + 3][lr] = av.w;
    *(float4*)&Bs[br][bc] = *(const float4*)(Wde + (size_t)(k0 + br) * 768 + n0 + bc);
    __syncthreads();
    #pragma unroll
    for (int kk = 0; kk < 16; ++kk) {
      float4 a4 = *(const float4*)&As[kk][ty4];
      float4 b4 = *(const float4*)&Bs[kk][tx4];
      float aa[4] = {a4.x, a4.y, a4.z, a4.w};
      float bb[4] = {b4.x, b4.y, b4.z, b4.w};
      #pragma unroll
      for (int i = 0; i < 4; ++i)
        #pragma unroll
        for (int j = 0; j < 4; ++j) acc[i][j] += aa[i] * bb[j];
    }
    __syncthreads();
  }
  #pragma unroll
  for (int i = 0; i < 4; ++i) {
    size_t rowoff = (size_t)(sb + ty4 + i) * 768 + n0 + tx4;
    #pragma unroll
    for (int j = 0; j < 4; ++j) os[rowoff + j] = acc[i][j];
  }
}

// x[t] += w0*os[slot0] + w1*os[slot1]  (deterministic combine, no atomics)
__global__ void moe_combine_k(float* __restrict__ x, const float* __restrict__ os,
                              const int* __restrict__ tk_slot, const float* __restrict__ tk_w) {
  int t = blockIdx.x;                                  // grid 4096 x 192
  int d = threadIdx.x << 2;
  int s0 = tk_slot[t * 2], s1 = tk_slot[t * 2 + 1];
  float w0 = tk_w[t * 2], w1 = tk_w[t * 2 + 1];
  const float4 a = *(const float4*)(os + (size_t)s0 * 768 + d);
  const float4 b = *(const float4*)(os + (size_t)s1 * 768 + d);
  float4 c = *(const float4*)(x + (size_t)t * 768 + d);
  c.x += w0 * a.x + w1 * b.x;
  c.y += w0 * a.y + w1 * b.y;
  c.z += w0 * a.z + w1 * b.z;
  c.w += w0 * a.w + w1 * b.w;
  *(float4*)(x + (size_t)t * 768 + d) = c;
}

__global__ void write_aux_k(const float* __restrict__ aux, float* __restrict__ out) {
  out[0] = aux[0];
}

// ---------------------------------------------------------------- host launcher

extern "C" void kernel_launch(void* const* d_in, const int* in_sizes, int n_in,
                              void* d_out, int out_size, void* d_ws, size_t ws_size,
                              hipStream_t stream) {
  const int* input_ids      = (const int*)d_in[0];
  const int* time_slots     = (const int*)d_in[1];
  const int* day_of_week    = (const int*)d_in[2];
  const int* month          = (const int*)d_in[3];
  const int* is_holiday     = (const int*)d_in[4];
  const int* location_ids   = (const int*)d_in[5];
  const int* road_types     = (const int*)d_in[6];
  const int* weather_states = (const int*)d_in[7];
  const float* word_emb     = (const float*)d_in[8];
  const float* time_emb     = (const float*)d_in[9];
  const float* dow_emb      = (const float*)d_in[10];
  const float* month_emb    = (const float*)d_in[11];
  const float* hol_emb      = (const float*)d_in[12];
  const float* loc_emb      = (const float*)d_in[13];
  const float* road_emb     = (const float*)d_in[14];
  const float* weather_emb  = (const float*)d_in[15];
  const float* proj_w       = (const float*)d_in[16];
  const float* proj_b       = (const float*)d_in[17];
  const float* emb_norm_w   = (const float*)d_in[18];
  const float* norm1_w      = (const float*)d_in[19];
  const float* Wq           = (const float*)d_in[20];
  const float* Wk           = (const float*)d_in[21];
  const float* Wv           = (const float*)d_in[22];
  const float* Wo           = (const float*)d_in[23];
  const float* norm2_w      = (const float*)d_in[24];
  const float* router_w     = (const float*)d_in[25];
  const float* Wg           = (const float*)d_in[26];
  const float* Wu           = (const float*)d_in[27];
  const float* Wd           = (const float*)d_in[28];
  const float* final_norm_w = (const float*)d_in[29];
  float* out = (float*)d_out;

  const size_t TD = (size_t)TTOK * DMODEL;             // 3,145,728
  // ---- workspace carve-up (~210 MB total) ----
  float* p = (float*)d_ws;
  float* x   = p; p += TD;
  float* xn  = p; p += TD;
  float* qb  = p; p += TD;
  float* kb  = p; p += TD;
  float* vb  = p; p += TD;
  float* ax  = p; p += TD;
  float* hb  = p; p += (size_t)MAXSLOT * FDIM;         // 107 MB
  float* ob  = p; p += (size_t)MAXSLOT * DMODEL;       // 27 MB
  float* cosb = p; p += 1024 * 32;
  float* sinb = p; p += 1024 * 32;
  float* ctx  = p; p += 4 * 1536;
  float* biasB = p; p += 4 * 768;
  float* tk_w = p; p += 8192;
  int* cnt  = (int*)p; p += 8;                         // [cnt|fill|psum] = one 96B memset
  int* fill = (int*)p; p += 8;
  float* psum = p; p += 8;
  float* auxa = p; p += 4;                             // 1 used + pad
  int* offs = (int*)p; p += 12;                        // 9 used + pad
  int* tk_idx = (int*)p; p += 8192;
  int* tk_slot = (int*)p; p += 8192;
  int* slot_token = (int*)p; p += MAXSLOT;

  hipMemsetAsync(auxa, 0, 4, stream);
  rope_cache_k<<<dim3(1024), dim3(32), 0, stream>>>(cosb, sinb);
  build_ctx_k<<<dim3(4, 6), dim3(256), 0, stream>>>(time_slots, day_of_week, month, is_holiday,
      location_ids, road_types, weather_states, time_emb, dow_emb, month_emb, hol_emb,
      loc_emb, road_emb, weather_emb, ctx);
  build_bias_k<<<dim3(4, 3), dim3(256), 0, stream>>>(ctx, proj_w, proj_b, biasB);
  // x_pre = word_emb[ids] @ proj_w[0:768] + biasB[b]   (context part folded into biasB)
  gemm_f32<1><<<dim3(12, 64), dim3(256), 0, stream>>>(word_emb, proj_w, xn, TTOK, 768, 768,
                                                      input_ids, biasB);
  rmsnorm_k<<<dim3(TTOK), dim3(256), 0, stream>>>(xn, emb_norm_w, x);

  for (int l = 0; l < 2; ++l) {
    const float* wq = Wq + (size_t)l * 768 * 768;
    const float* wk = Wk + (size_t)l * 768 * 768;
    const float* wv = Wv + (size_t)l * 768 * 768;
    const float* wo = Wo + (size_t)l * 768 * 768;
    const float* rw = router_w + (size_t)l * 768 * 8;
    const float* wg = Wg + (size_t)l * NEXP * 768 * FDIM;
    const float* wu = Wu + (size_t)l * NEXP * 768 * FDIM;
    const float* wd = Wd + (size_t)l * NEXP * FDIM * 768;

    rmsnorm_k<<<dim3(TTOK), dim3(256), 0, stream>>>(x, norm1_w + l * 768, xn);
    gemm_f32<0><<<dim3(12, 64), dim3(256), 0, stream>>>(xn, wq, qb, TTOK, 768, 768, nullptr, nullptr);
    gemm_f32<0><<<dim3(12, 64), dim3(256), 0, stream>>>(xn, wk, kb, TTOK, 768, 768, nullptr, nullptr);
    gemm_f32<0><<<dim3(12, 64), dim3(256), 0, stream>>>(xn, wv, vb, TTOK, 768, 768, nullptr, nullptr);
    rope_apply_k<<<dim3(6144), dim3(256), 0, stream>>>(qb, kb, cosb, sinb);
    attn_k<<<dim3(32, 12, 4), dim3(256), 0, stream>>>(qb, kb, vb, ax);
    gemm_f32<2><<<dim3(12, 64), dim3(256), 0, stream>>>(ax, wo, x, TTOK, 768, 768, nullptr, nullptr);

    rmsnorm_k<<<dim3(TTOK), dim3(256), 0, stream>>>(x, norm2_w + l * 768, xn);
    hipMemsetAsync(cnt, 0, 96, stream);                       // cnt+fill+psum
    hipMemsetAsync(slot_token, 0xFF, MAXSLOT * 4, stream);    // all-slots = -1 (padding)
    router_k<<<dim3(1024), dim3(256), 0, stream>>>(xn, rw, tk_idx, tk_w, cnt, psum);
    moe_offsets_k<<<dim3(1), dim3(64), 0, stream>>>(cnt, offs, psum, auxa);
    moe_fill_k<<<dim3(32), dim3(256), 0, stream>>>(tk_idx, offs, fill, slot_token, tk_slot);
    moe_gu_k<<<dim3(48, 136), dim3(256), 0, stream>>>(xn, wg, wu, hb, slot_token, offs);
    moe_d_k<<<dim3(12, 136), dim3(256), 0, stream>>>(hb, wd, ob, offs);
    moe_combine_k<<<dim3(TTOK), dim3(192), 0, stream>>>(x, ob, tk_slot, tk_w);
  }

  rmsnorm_k<<<dim3(TTOK), dim3(256), 0, stream>>>(x, final_norm_w, out);
  write_aux_k<<<dim3(1), dim3(1), 0, stream>>>(auxa, out + TD);
}

// Round 3
// 2997.790 us; speedup vs baseline: 1.6045x; 1.6045x over previous
//
#include <hip/hip_runtime.h>
#include <math.h>

// Traffic foundation model, round 2.
// Routing-critical GEMMs (proj, QKV, Wo, layer-0 MoE) use split-3 bf16 MFMA
// "emulated fp32": A = ah+am+al, B = bh+bm+bl (exact 24-bit splits), 6 MFMA
// terms (hh,hm,mh,hl,lh,mm) -> f32-equivalent accuracy at MFMA-pipe speed.
// Layer-1 MoE experts (feed no router) stay plain bf16 MFMA. Router exact f32.
// Attention f32 math (round-0 proven). B=4 S=1024 D=768 H=12 HD=64 L=2 E=8 F=3072.

#define TTOK 4096
#define FDIM 3072
#define MAXSLOT 9216   // 8192 + 8*127 pad, 128-aligned offsets

typedef __attribute__((ext_vector_type(8))) short short8;
typedef __attribute__((ext_vector_type(4))) float f32x4;

__device__ __forceinline__ float bf2f(unsigned short u) {
  return __uint_as_float(((unsigned int)u) << 16);
}
__device__ __forceinline__ unsigned short f2bf(float f) {
  unsigned int u = __float_as_uint(f);
  u += 0x7fffu + ((u >> 16) & 1u);
  return (unsigned short)(u >> 16);
}
// exact 3-way bf16 split: a ~= h + m + l to ~24 mantissa bits
__device__ __forceinline__ void split3f(float a, unsigned short& h, unsigned short& m,
                                        unsigned short& l) {
  h = f2bf(a);
  float r = a - bf2f(h);
  m = f2bf(r);
  r -= bf2f(m);
  l = f2bf(r);
}
__device__ __forceinline__ void gload16(const void* g, void* l) {
  __builtin_amdgcn_global_load_lds((const __attribute__((address_space(1))) unsigned int*)g,
                                   (__attribute__((address_space(3))) unsigned int*)l, 16, 0, 0);
}

// 6-term split-3 MFMA accumulate (smallest terms first)
#define MFMA_TERM(ACC, PA, PB)                                                              \
  _Pragma("unroll") for (int i_ = 0; i_ < 4; ++i_)                                          \
      _Pragma("unroll") for (int j_ = 0; j_ < 4; ++j_)                                      \
          ACC[i_][j_] = __builtin_amdgcn_mfma_f32_16x16x32_bf16(af[PA][i_], bf[PB][j_],     \
                                                                ACC[i_][j_], 0, 0, 0);
#define MFMA_SPLIT3(ACC)  \
  MFMA_TERM(ACC, 0, 2) MFMA_TERM(ACC, 2, 0) MFMA_TERM(ACC, 1, 1) \
  MFMA_TERM(ACC, 0, 1) MFMA_TERM(ACC, 1, 0) MFMA_TERM(ACC, 0, 0)

// ---------------------------------------------------------------- small kernels

__global__ void rope_cache_k(float* __restrict__ cosb, float* __restrict__ sinb) {
  int s = blockIdx.x, i = threadIdx.x;                 // grid 1024 x 32
  float inv = powf(10000.0f, -(float)i / 32.0f);
  float a = (float)s * inv;
  cosb[s * 32 + i] = cosf(a);
  sinb[s * 32 + i] = sinf(a);
}

__global__ void build_ctx_k(const int* ts, const int* dow, const int* mon, const int* hol,
                            const int* loc, const int* road, const int* wth,
                            const float* te, const float* de, const float* me, const float* he,
                            const float* le, const float* re, const float* we,
                            float* __restrict__ ctx) {
  int b = blockIdx.x;
  int j = blockIdx.y * 256 + threadIdx.x;              // grid (4,6) x 256
  float v;
  if (j < 192)       v = te[ts[b] * 192 + j];
  else if (j < 384)  v = de[dow[b] * 192 + (j - 192)];
  else if (j < 576)  v = me[mon[b] * 192 + (j - 384)];
  else if (j < 768)  v = he[hol[b] * 192 + (j - 576)];
  else if (j < 1152) v = le[loc[b] * 384 + (j - 768)];
  else if (j < 1344) v = re[road[b] * 192 + (j - 1152)];
  else               v = we[wth[b] * 192 + (j - 1344)];
  ctx[b * 1536 + j] = v;
}

// biasB[b][d] = proj_b[d] + sum_j ctx[b][j] * proj_w[768+j][d]  (exact f32)
__global__ void build_bias_k(const float* __restrict__ ctx, const float* __restrict__ pw,
                             const float* __restrict__ pb, float* __restrict__ biasB) {
  int b = blockIdx.x;
  int d = blockIdx.y * 256 + threadIdx.x;              // grid (4,3) x 256
  float s = pb[d];
  const float* cb = ctx + b * 1536;
  for (int j = 0; j < 1536; ++j) s += cb[j] * pw[(size_t)(768 + j) * 768 + d];
  biasB[b * 768 + d] = s;
}

// transpose + split-3: dst[p][n][k] = split(src[k][n]). grid (N/32, K/32, batch), block (32,8)
__global__ void tconv3_k(const float* __restrict__ src, unsigned short* __restrict__ dst,
                         size_t dPS, int K, int N, size_t sstride, size_t dstride) {
  __shared__ float tile[32][33];
  src += (size_t)blockIdx.z * sstride;
  size_t dbase = (size_t)blockIdx.z * dstride;
  int n0 = blockIdx.x * 32, k0 = blockIdx.y * 32;
  int tx = threadIdx.x, ty = threadIdx.y;
  #pragma unroll
  for (int r = 0; r < 4; ++r)
    tile[ty + r * 8][tx] = src[(size_t)(k0 + ty + r * 8) * N + n0 + tx];
  __syncthreads();
  #pragma unroll
  for (int r = 0; r < 4; ++r) {
    int n = n0 + ty + r * 8;
    unsigned short h, m, lo;
    split3f(tile[tx][ty + r * 8], h, m, lo);
    size_t di = dbase + (size_t)n * K + k0 + tx;
    dst[di] = h; dst[di + dPS] = m; dst[di + 2 * dPS] = lo;
  }
}

// transpose-convert single plane (plain bf16, for layer-1 experts)
__global__ void tconv_k(const float* __restrict__ src, unsigned short* __restrict__ dst,
                        int K, int N, size_t sstride, size_t dstride) {
  __shared__ unsigned short tile[32][33];
  src += (size_t)blockIdx.z * sstride;
  unsigned short* d = dst + (size_t)blockIdx.z * dstride;
  int n0 = blockIdx.x * 32, k0 = blockIdx.y * 32;
  int tx = threadIdx.x, ty = threadIdx.y;
  #pragma unroll
  for (int r = 0; r < 4; ++r)
    tile[ty + r * 8][tx] = f2bf(src[(size_t)(k0 + ty + r * 8) * N + n0 + tx]);
  __syncthreads();
  #pragma unroll
  for (int r = 0; r < 4; ++r) {
    int n = n0 + ty + r * 8;
    d[(size_t)n * K + k0 + tx] = tile[tx][ty + r * 8];
  }
}

// gather word_emb rows -> 3 planes. grid 4096 x 192
__global__ void gconv3_k(const float* __restrict__ we, const int* __restrict__ ids,
                         unsigned short* __restrict__ x3, size_t pPS) {
  int t = blockIdx.x;
  int d = threadIdx.x << 2;
  float4 v = *(const float4*)(we + (size_t)ids[t] * 768 + d);
  ushort4 vh, vm, vl;
  split3f(v.x, vh.x, vm.x, vl.x);
  split3f(v.y, vh.y, vm.y, vl.y);
  split3f(v.z, vh.z, vm.z, vl.z);
  split3f(v.w, vh.w, vm.w, vl.w);
  size_t o = (size_t)t * 768 + d;
  *(ushort4*)(x3 + o) = vh;
  *(ushort4*)(x3 + pPS + o) = vm;
  *(ushort4*)(x3 + 2 * pPS + o) = vl;
}

// OUT: 0 f32 only; 1 3-plane only; 2 f32 + 3-plane; 3 f32 + single-bf16(plane0)
template <int OUT>
__global__ __launch_bounds__(256) void rmsnorm_k(const float* __restrict__ xin,
                                                 const float* __restrict__ w,
                                                 float* __restrict__ yf,
                                                 unsigned short* __restrict__ yb, size_t pPS) {
  int t = blockIdx.x;
  int tid = threadIdx.x;
  const float* xr = xin + (size_t)t * 768;
  float v0 = xr[tid], v1 = xr[tid + 256], v2 = xr[tid + 512];
  float ss = v0 * v0 + v1 * v1 + v2 * v2;
  #pragma unroll
  for (int o = 32; o > 0; o >>= 1) ss += __shfl_xor(ss, o);
  __shared__ float wss[4];
  if ((tid & 63) == 0) wss[tid >> 6] = ss;
  __syncthreads();
  float tot = wss[0] + wss[1] + wss[2] + wss[3];
  float inv = 1.0f / sqrtf(tot / 768.0f + 1e-6f);
  float o0 = v0 * inv * w[tid], o1 = v1 * inv * w[tid + 256], o2 = v2 * inv * w[tid + 512];
  if (OUT != 1) {
    float* yr = yf + (size_t)t * 768;
    yr[tid] = o0; yr[tid + 256] = o1; yr[tid + 512] = o2;
  }
  if (OUT == 1 || OUT == 2) {
    unsigned short* yr = yb + (size_t)t * 768;
    unsigned short h, m, l;
    split3f(o0, h, m, l); yr[tid] = h;       yr[tid + pPS] = m;       yr[tid + 2 * pPS] = l;
    split3f(o1, h, m, l); yr[tid + 256] = h; yr[tid + 256 + pPS] = m; yr[tid + 256 + 2 * pPS] = l;
    split3f(o2, h, m, l); yr[tid + 512] = h; yr[tid + 512 + pPS] = m; yr[tid + 512 + 2 * pPS] = l;
  }
  if (OUT == 3) {
    unsigned short* yr = yb + (size_t)t * 768;
    yr[tid] = f2bf(o0); yr[tid + 256] = f2bf(o1); yr[tid + 512] = f2bf(o2);
  }
}

// rope in-place on f32 qkv [T][2304] (q at 0, k at 768)
__global__ __launch_bounds__(256) void rope_apply_k(float* __restrict__ qkv,
                                                    const float* __restrict__ cosb,
                                                    const float* __restrict__ sinb) {
  int idx = blockIdx.x * 256 + threadIdx.x;            // grid 6144
  int j = idx & 31;
  int hh = (idx >> 5) % 12;
  int t = idx / 384;
  int s = t & 1023;
  float c = cosb[s * 32 + j], sn = sinb[s * 32 + j];
  size_t base = (size_t)t * 2304 + hh * 64 + j;
  float q1 = qkv[base], q2 = qkv[base + 32];
  qkv[base]      = q1 * c - q2 * sn;
  qkv[base + 32] = q2 * c + q1 * sn;
  size_t kb = base + 768;
  float k1 = qkv[kb], k2 = qkv[kb + 32];
  qkv[kb]      = k1 * c - k2 * sn;
  qkv[kb + 32] = k2 * c + k1 * sn;
}

// ---------------------------------------------------------------- split-3 dense GEMM
// C[M,N] = A@BT^T, A/BT 3-plane bf16 (plane strides aPS/bPS). 128x128 tile, 4 waves.
// EPI: 0 f32 store; 2 f32 +=; 3 f32 store + per-batch bias
template <int EPI>
__global__ __launch_bounds__(256) void gemm3(const unsigned short* __restrict__ A, size_t aPS,
                                             const unsigned short* __restrict__ BT, size_t bPS,
                                             float* __restrict__ Cf, int N, int K,
                                             const float* __restrict__ rowBias) {
  __shared__ __align__(16) unsigned short As[3][4096];
  __shared__ __align__(16) unsigned short Bs[3][4096];
  int tid = threadIdx.x, w = tid >> 6, l = tid & 63, lr = l & 15, lg = l >> 4;
  int m0 = blockIdx.y * 128, n0 = blockIdx.x * 128;
  size_t aoff = (size_t)(m0 + 32 * w + lr) * K + lg * 8;
  size_t boff = (size_t)(n0 + 32 * w + lr) * K + lg * 8;
  size_t aoff1 = aoff + (size_t)16 * K, boff1 = boff + (size_t)16 * K;
  f32x4 acc[4][4];
  #pragma unroll
  for (int i = 0; i < 4; ++i)
    #pragma unroll
    for (int j = 0; j < 4; ++j) acc[i][j] = (f32x4){0.f, 0.f, 0.f, 0.f};
  int wr = w >> 1, wc = w & 1;
  for (int k0 = 0; k0 < K; k0 += 32) {
    #pragma unroll
    for (int p = 0; p < 3; ++p) {
      gload16(A + p * aPS + aoff + k0,  &As[p][1024 * w]);
      gload16(A + p * aPS + aoff1 + k0, &As[p][1024 * w + 512]);
      gload16(BT + p * bPS + boff + k0,  &Bs[p][1024 * w]);
      gload16(BT + p * bPS + boff1 + k0, &Bs[p][1024 * w + 512]);
    }
    __syncthreads();
    short8 af[3][4], bf[3][4];
    #pragma unroll
    for (int p = 0; p < 3; ++p)
      #pragma unroll
      for (int i = 0; i < 4; ++i) {
        af[p][i] = *(const short8*)(&As[p][(wr * 4 + i) * 512 + l * 8]);
        bf[p][i] = *(const short8*)(&Bs[p][(wc * 4 + i) * 512 + l * 8]);
      }
    MFMA_SPLIT3(acc)
    __syncthreads();
  }
  int colb = n0 + wc * 64 + lr;
  int rowb = m0 + wr * 64 + lg * 4;
  #pragma unroll
  for (int i = 0; i < 4; ++i)
    #pragma unroll
    for (int j = 0; j < 4; ++j) {
      int col = colb + j * 16;
      #pragma unroll
      for (int r = 0; r < 4; ++r) {
        int row = rowb + i * 16 + r;
        size_t idx = (size_t)row * N + col;
        float v = acc[i][j][r];
        if (EPI == 0)      Cf[idx] = v;
        else if (EPI == 2) Cf[idx] += v;
        else               Cf[idx] = v + rowBias[(row >> 10) * 768 + col];
      }
    }
}

// split-3 MoE gate/up GEMM, gathered A rows. FUSE 0: store f32 (g pass);
// FUSE 1: read g, out = silu(g)*u (u pass). N=3072, K=768.
template <int FUSE>
__global__ __launch_bounds__(256) void gemm3_gu(const unsigned short* __restrict__ X3, size_t xPS,
    const unsigned short* __restrict__ W3, size_t wPS, float* __restrict__ outb,
    const float* __restrict__ gin, const int* __restrict__ slot_token,
    const int* __restrict__ offs, const unsigned short* __restrict__ zp) {
  __shared__ __align__(16) unsigned short As[3][4096];
  __shared__ __align__(16) unsigned short Bs[3][4096];
  int sb = blockIdx.y * 128;
  if (sb >= offs[8]) return;
  int e = 0;
  #pragma unroll
  for (int i = 1; i < 8; ++i) if (sb >= offs[i]) e = i;
  int tid = threadIdx.x, w = tid >> 6, l = tid & 63, lr = l & 15, lg = l >> 4;
  int n0 = blockIdx.x * 128;
  const unsigned short* WE = W3 + (size_t)e * FDIM * 768;
  int t0 = slot_token[sb + 32 * w + lr];
  int t1 = slot_token[sb + 32 * w + 16 + lr];
  const unsigned short* a0[3];
  const unsigned short* a1[3];
  #pragma unroll
  for (int p = 0; p < 3; ++p) {
    a0[p] = (t0 < 0 ? zp : X3 + p * xPS + (size_t)t0 * 768) + lg * 8;
    a1[p] = (t1 < 0 ? zp : X3 + p * xPS + (size_t)t1 * 768) + lg * 8;
  }
  size_t boff = (size_t)(n0 + 32 * w + lr) * 768 + lg * 8;
  size_t boff1 = boff + (size_t)16 * 768;
  f32x4 acc[4][4];
  #pragma unroll
  for (int i = 0; i < 4; ++i)
    #pragma unroll
    for (int j = 0; j < 4; ++j) acc[i][j] = (f32x4){0.f, 0.f, 0.f, 0.f};
  int wr = w >> 1, wc = w & 1;
  for (int k0 = 0; k0 < 768; k0 += 32) {
    #pragma unroll
    for (int p = 0; p < 3; ++p) {
      gload16(a0[p] + k0, &As[p][1024 * w]);
      gload16(a1[p] + k0, &As[p][1024 * w + 512]);
      gload16(WE + p * wPS + boff + k0,  &Bs[p][1024 * w]);
      gload16(WE + p * wPS + boff1 + k0, &Bs[p][1024 * w + 512]);
    }
    __syncthreads();
    short8 af[3][4], bf[3][4];
    #pragma unroll
    for (int p = 0; p < 3; ++p)
      #pragma unroll
      for (int i = 0; i < 4; ++i) {
        af[p][i] = *(const short8*)(&As[p][(wr * 4 + i) * 512 + l * 8]);
        bf[p][i] = *(const short8*)(&Bs[p][(wc * 4 + i) * 512 + l * 8]);
      }
    MFMA_SPLIT3(acc)
    __syncthreads();
  }
  int colb = n0 + wc * 64 + lr;
  int rowb = sb + wr * 64 + lg * 4;
  #pragma unroll
  for (int i = 0; i < 4; ++i)
    #pragma unroll
    for (int j = 0; j < 4; ++j) {
      int col = colb + j * 16;
      #pragma unroll
      for (int r = 0; r < 4; ++r) {
        size_t idx = (size_t)(rowb + i * 16 + r) * FDIM + col;
        float v = acc[i][j][r];
        if (FUSE == 0) outb[idx] = v;
        else {
          float g = gin[idx];
          outb[idx] = g / (1.0f + expf(-g)) * v;       // silu(g)*u
        }
      }
    }
}

// split-3 MoE down GEMM: A = h (f32, split in-kernel), B = wd planes. N=768, K=3072.
__global__ __launch_bounds__(256) void gemm3_dn(const float* __restrict__ hbf,
    const unsigned short* __restrict__ W3, size_t wPS, float* __restrict__ ob,
    const int* __restrict__ offs) {
  __shared__ __align__(16) unsigned short As[3][4096];
  __shared__ __align__(16) unsigned short Bs[3][4096];
  int sb = blockIdx.y * 128;
  if (sb >= offs[8]) return;
  int e = 0;
  #pragma unroll
  for (int i = 1; i < 8; ++i) if (sb >= offs[i]) e = i;
  int tid = threadIdx.x, w = tid >> 6, l = tid & 63, lr = l & 15, lg = l >> 4;
  int n0 = blockIdx.x * 128;
  const unsigned short* WE = W3 + (size_t)e * 768 * FDIM;
  size_t boff = (size_t)(n0 + 32 * w + lr) * FDIM + lg * 8;
  size_t boff1 = boff + (size_t)16 * FDIM;
  const float* ha0 = hbf + (size_t)(sb + 32 * w + lr) * FDIM + lg * 8;
  const float* ha1 = ha0 + (size_t)16 * FDIM;
  f32x4 acc[4][4];
  #pragma unroll
  for (int i = 0; i < 4; ++i)
    #pragma unroll
    for (int j = 0; j < 4; ++j) acc[i][j] = (f32x4){0.f, 0.f, 0.f, 0.f};
  int wr = w >> 1, wc = w & 1;
  for (int k0 = 0; k0 < FDIM; k0 += 32) {
    #pragma unroll
    for (int p = 0; p < 3; ++p) {
      gload16(WE + p * wPS + boff + k0,  &Bs[p][1024 * w]);
      gload16(WE + p * wPS + boff1 + k0, &Bs[p][1024 * w + 512]);
    }
    // A: load f32, split to 3 planes, ds_write (lane-linear, same layout as gload16)
    {
      float4 v0 = *(const float4*)(ha0 + k0);
      float4 v1 = *(const float4*)(ha0 + k0 + 4);
      float va[8] = {v0.x, v0.y, v0.z, v0.w, v1.x, v1.y, v1.z, v1.w};
      short8 sh, sm, sl;
      #pragma unroll
      for (int q = 0; q < 8; ++q) {
        unsigned short a, b, c;
        split3f(va[q], a, b, c);
        sh[q] = (short)a; sm[q] = (short)b; sl[q] = (short)c;
      }
      *(short8*)(&As[0][1024 * w + l * 8]) = sh;
      *(short8*)(&As[1][1024 * w + l * 8]) = sm;
      *(short8*)(&As[2][1024 * w + l * 8]) = sl;
      v0 = *(const float4*)(ha1 + k0);
      v1 = *(const float4*)(ha1 + k0 + 4);
      float vb[8] = {v0.x, v0.y, v0.z, v0.w, v1.x, v1.y, v1.z, v1.w};
      #pragma unroll
      for (int q = 0; q < 8; ++q) {
        unsigned short a, b, c;
        split3f(vb[q], a, b, c);
        sh[q] = (short)a; sm[q] = (short)b; sl[q] = (short)c;
      }
      *(short8*)(&As[0][1024 * w + 512 + l * 8]) = sh;
      *(short8*)(&As[1][1024 * w + 512 + l * 8]) = sm;
      *(short8*)(&As[2][1024 * w + 512 + l * 8]) = sl;
    }
    __syncthreads();
    short8 af[3][4], bf[3][4];
    #pragma unroll
    for (int p = 0; p < 3; ++p)
      #pragma unroll
      for (int i = 0; i < 4; ++i) {
        af[p][i] = *(const short8*)(&As[p][(wr * 4 + i) * 512 + l * 8]);
        bf[p][i] = *(const short8*)(&Bs[p][(wc * 4 + i) * 512 + l * 8]);
      }
    MFMA_SPLIT3(acc)
    __syncthreads();
  }
  int colb = n0 + wc * 64 + lr;
  int rowb = sb + wr * 64 + lg * 4;
  #pragma unroll
  for (int i = 0; i < 4; ++i)
    #pragma unroll
    for (int j = 0; j < 4; ++j) {
      int col = colb + j * 16;
      #pragma unroll
      for (int r = 0; r < 4; ++r)
        ob[(size_t)(rowb + i * 16 + r) * 768 + col] = acc[i][j][r];
    }
}

// ---------------------------------------------------------------- plain bf16 GEMMs (layer-1 MoE)

__global__ __launch_bounds__(256) void gemm_gu(const unsigned short* __restrict__ xnb,
    const unsigned short* __restrict__ wgT, const unsigned short* __restrict__ wuT,
    unsigned short* __restrict__ hb, const int* __restrict__ slot_token,
    const int* __restrict__ offs, const unsigned short* __restrict__ zp) {
  __shared__ __align__(16) unsigned short As[4096], Bg[4096], Bu[4096];
  int sb = blockIdx.y * 128;
  if (sb >= offs[8]) return;
  int e = 0;
  #pragma unroll
  for (int i = 1; i < 8; ++i) if (sb >= offs[i]) e = i;
  int tid = threadIdx.x, w = tid >> 6, l = tid & 63, lr = l & 15, lg = l >> 4;
  int n0 = blockIdx.x * 128;
  int t0 = slot_token[sb + 32 * w + lr];
  int t1 = slot_token[sb + 32 * w + 16 + lr];
  const unsigned short* ga0 = (t0 < 0 ? zp : xnb + (size_t)t0 * 768) + lg * 8;
  const unsigned short* ga1 = (t1 < 0 ? zp : xnb + (size_t)t1 * 768) + lg * 8;
  const unsigned short* WgE = wgT + (size_t)e * FDIM * 768;
  const unsigned short* WuE = wuT + (size_t)e * FDIM * 768;
  const unsigned short* gg0 = WgE + (size_t)(n0 + 32 * w + lr) * 768 + lg * 8;
  const unsigned short* gg1 = gg0 + 16 * 768;
  const unsigned short* gu0 = WuE + (size_t)(n0 + 32 * w + lr) * 768 + lg * 8;
  const unsigned short* gu1 = gu0 + 16 * 768;
  f32x4 ag[4][4], au[4][4];
  #pragma unroll
  for (int i = 0; i < 4; ++i)
    #pragma unroll
    for (int j = 0; j < 4; ++j) {
      ag[i][j] = (f32x4){0.f, 0.f, 0.f, 0.f};
      au[i][j] = (f32x4){0.f, 0.f, 0.f, 0.f};
    }
  int wr = w >> 1, wc = w & 1;
  for (int k0 = 0; k0 < 768; k0 += 32) {
    gload16(ga0 + k0, As + 1024 * w);
    gload16(ga1 + k0, As + 1024 * w + 512);
    gload16(gg0 + k0, Bg + 1024 * w);
    gload16(gg1 + k0, Bg + 1024 * w + 512);
    gload16(gu0 + k0, Bu + 1024 * w);
    gload16(gu1 + k0, Bu + 1024 * w + 512);
    __syncthreads();
    short8 af[4];
    #pragma unroll
    for (int i = 0; i < 4; ++i) af[i] = *(const short8*)(As + (wr * 4 + i) * 512 + l * 8);
    #pragma unroll
    for (int j = 0; j < 4; ++j) {
      short8 bg = *(const short8*)(Bg + (wc * 4 + j) * 512 + l * 8);
      short8 bu = *(const short8*)(Bu + (wc * 4 + j) * 512 + l * 8);
      #pragma unroll
      for (int i = 0; i < 4; ++i) {
        ag[i][j] = __builtin_amdgcn_mfma_f32_16x16x32_bf16(af[i], bg, ag[i][j], 0, 0, 0);
        au[i][j] = __builtin_amdgcn_mfma_f32_16x16x32_bf16(af[i], bu, au[i][j], 0, 0, 0);
      }
    }
    __syncthreads();
  }
  int colb = n0 + wc * 64 + lr;
  int rowb = sb + wr * 64 + lg * 4;
  #pragma unroll
  for (int i = 0; i < 4; ++i)
    #pragma unroll
    for (int j = 0; j < 4; ++j) {
      int col = colb + j * 16;
      #pragma unroll
      for (int r = 0; r < 4; ++r) {
        float g = ag[i][j][r], u = au[i][j][r];
        hb[(size_t)(rowb + i * 16 + r) * FDIM + col] = f2bf(g / (1.0f + expf(-g)) * u);
      }
    }
}

__global__ __launch_bounds__(256) void gemm_d(const unsigned short* __restrict__ hb,
    const unsigned short* __restrict__ wdT, unsigned short* __restrict__ ob,
    const int* __restrict__ offs) {
  __shared__ __align__(16) unsigned short As[4096], Bs[4096];
  int sb = blockIdx.y * 128;
  if (sb >= offs[8]) return;
  int e = 0;
  #pragma unroll
  for (int i = 1; i < 8; ++i) if (sb >= offs[i]) e = i;
  int tid = threadIdx.x, w = tid >> 6, l = tid & 63, lr = l & 15, lg = l >> 4;
  int n0 = blockIdx.x * 128;
  const unsigned short* ga0 = hb + (size_t)(sb + 32 * w + lr) * FDIM + lg * 8;
  const unsigned short* ga1 = ga0 + (size_t)16 * FDIM;
  const unsigned short* WdE = wdT + (size_t)e * 768 * FDIM;
  const unsigned short* gb0 = WdE + (size_t)(n0 + 32 * w + lr) * FDIM + lg * 8;
  const unsigned short* gb1 = gb0 + (size_t)16 * FDIM;
  f32x4 acc[4][4];
  #pragma unroll
  for (int i = 0; i < 4; ++i)
    #pragma unroll
    for (int j = 0; j < 4; ++j) acc[i][j] = (f32x4){0.f, 0.f, 0.f, 0.f};
  int wr = w >> 1, wc = w & 1;
  for (int k0 = 0; k0 < FDIM; k0 += 32) {
    gload16(ga0 + k0, As + 1024 * w);
    gload16(ga1 + k0, As + 1024 * w + 512);
    gload16(gb0 + k0, Bs + 1024 * w);
    gload16(gb1 + k0, Bs + 1024 * w + 512);
    __syncthreads();
    short8 af[4], bf[4];
    #pragma unroll
    for (int i = 0; i < 4; ++i) af[i] = *(const short8*)(As + (wr * 4 + i) * 512 + l * 8);
    #pragma unroll
    for (int j = 0; j < 4; ++j) bf[j] = *(const short8*)(Bs + (wc * 4 + j) * 512 + l * 8);
    #pragma unroll
    for (int i = 0; i < 4; ++i)
      #pragma unroll
      for (int j = 0; j < 4; ++j)
        acc[i][j] = __builtin_amdgcn_mfma_f32_16x16x32_bf16(af[i], bf[j], acc[i][j], 0, 0, 0);
    __syncthreads();
  }
  int colb = n0 + wc * 64 + lr;
  int rowb = sb + wr * 64 + lg * 4;
  #pragma unroll
  for (int i = 0; i < 4; ++i)
    #pragma unroll
    for (int j = 0; j < 4; ++j) {
      int col = colb + j * 16;
      #pragma unroll
      for (int r = 0; r < 4; ++r)
        ob[(size_t)(rowb + i * 16 + r) * 768 + col] = f2bf(acc[i][j][r]);
    }
}

// ---------------------------------------------------------------- attention (f32, round-0 proven)
__global__ __launch_bounds__(256) void attn_k(const float* __restrict__ qkv,
                                              unsigned short* __restrict__ ax3, size_t pPS) {
  int qt = blockIdx.x, hd = blockIdx.y, b = blockIdx.z;
  int q0 = qt * 32;
  int tid = threadIdx.x;
  __shared__ float qs[64][33];
  __shared__ float ks[64][33];
  __shared__ float vs[32][64];
  __shared__ float ps[32][33];
  __shared__ float rowm[32], rowl[32], rowc[32];
  int lr = tid >> 3;
  int lc8 = (tid & 7) << 3;
  size_t qbase = ((size_t)(b * 1024 + q0 + lr)) * 2304 + hd * 64 + lc8;
  float4 qa = *(const float4*)(qkv + qbase);
  float4 qb4 = *(const float4*)(qkv + qbase + 4);
  qs[lc8 + 0][lr] = qa.x;  qs[lc8 + 1][lr] = qa.y;  qs[lc8 + 2][lr] = qa.z;  qs[lc8 + 3][lr] = qa.w;
  qs[lc8 + 4][lr] = qb4.x; qs[lc8 + 5][lr] = qb4.y; qs[lc8 + 6][lr] = qb4.z; qs[lc8 + 7][lr] = qb4.w;
  if (tid < 32) { rowm[tid] = -3.0e38f; rowl[tid] = 0.0f; }
  float acc[8] = {0, 0, 0, 0, 0, 0, 0, 0};
  int myq = tid >> 3;
  int g = tid & 7;
  for (int kt = 0; kt <= qt; ++kt) {
    int k0 = kt * 32;
    size_t kbase = ((size_t)(b * 1024 + k0 + lr)) * 2304 + 768 + hd * 64 + lc8;
    float4 ka = *(const float4*)(qkv + kbase);
    float4 kb4 = *(const float4*)(qkv + kbase + 4);
    ks[lc8 + 0][lr] = ka.x;  ks[lc8 + 1][lr] = ka.y;  ks[lc8 + 2][lr] = ka.z;  ks[lc8 + 3][lr] = ka.w;
    ks[lc8 + 4][lr] = kb4.x; ks[lc8 + 5][lr] = kb4.y; ks[lc8 + 6][lr] = kb4.z; ks[lc8 + 7][lr] = kb4.w;
    *(float4*)&vs[lr][lc8]     = *(const float4*)(qkv + kbase + 768);
    *(float4*)&vs[lr][lc8 + 4] = *(const float4*)(qkv + kbase + 772);
    __syncthreads();
    int kc = g << 2;
    float sc0 = 0, sc1 = 0, sc2 = 0, sc3 = 0;
    #pragma unroll 8
    for (int d = 0; d < 64; ++d) {
      float qv = qs[d][myq];
      sc0 += qv * ks[d][kc + 0];
      sc1 += qv * ks[d][kc + 1];
      sc2 += qv * ks[d][kc + 2];
      sc3 += qv * ks[d][kc + 3];
    }
    int qgl = q0 + myq;
    float s4[4] = {sc0, sc1, sc2, sc3};
    float mx = -3.0e38f;
    #pragma unroll
    for (int j = 0; j < 4; ++j) {
      s4[j] = (k0 + kc + j <= qgl) ? s4[j] * 0.125f : -3.0e38f;
      mx = fmaxf(mx, s4[j]);
    }
    mx = fmaxf(mx, __shfl_xor(mx, 4));
    mx = fmaxf(mx, __shfl_xor(mx, 2));
    mx = fmaxf(mx, __shfl_xor(mx, 1));
    float mold = rowm[myq];
    float mnew = fmaxf(mold, mx);
    float lsum = 0.0f;
    #pragma unroll
    for (int j = 0; j < 4; ++j) {
      float pp = expf(s4[j] - mnew);
      ps[myq][kc + j] = pp;
      lsum += pp;
    }
    lsum += __shfl_xor(lsum, 4);
    lsum += __shfl_xor(lsum, 2);
    lsum += __shfl_xor(lsum, 1);
    if (g == 0) {
      float c = expf(mold - mnew);
      rowc[myq] = c;
      rowl[myq] = rowl[myq] * c + lsum;
      rowm[myq] = mnew;
    }
    __syncthreads();
    float c = rowc[myq];
    #pragma unroll
    for (int j = 0; j < 8; ++j) acc[j] *= c;
    int db = g << 3;
    #pragma unroll 4
    for (int kk2 = 0; kk2 < 32; ++kk2) {
      float pp = ps[myq][kk2];
      #pragma unroll
      for (int j = 0; j < 8; ++j) acc[j] += pp * vs[kk2][db + j];
    }
    __syncthreads();
  }
  float invl = 1.0f / rowl[myq];
  size_t obase = ((size_t)(b * 1024 + q0 + myq)) * 768 + hd * 64 + (g << 3);
  short8 vh, vm, vl;
  #pragma unroll
  for (int j = 0; j < 8; ++j) {
    unsigned short a, b2, c2;
    split3f(acc[j] * invl, a, b2, c2);
    vh[j] = (short)a; vm[j] = (short)b2; vl[j] = (short)c2;
  }
  *(short8*)(ax3 + obase) = vh;
  *(short8*)(ax3 + pPS + obase) = vm;
  *(short8*)(ax3 + 2 * pPS + obase) = vl;
}

// ---------------------------------------------------------------- MoE routing (exact f32)
__global__ __launch_bounds__(256) void router_k(const float* __restrict__ xn,
                                                const float* __restrict__ rw,
                                                int* __restrict__ tk_idx, float* __restrict__ tk_w,
                                                int* __restrict__ cnt, float* __restrict__ psum) {
  __shared__ float bps[8];
  __shared__ int bcnt[8];
  int tid = threadIdx.x;
  if (tid < 8) { bps[tid] = 0.0f; bcnt[tid] = 0; }
  __syncthreads();
  int t = blockIdx.x * 4 + (tid >> 6);
  int lane = tid & 63;
  const float* xr = xn + (size_t)t * 768;
  float p[8] = {};
  for (int d = lane; d < 768; d += 64) {
    float xv = xr[d];
    const float* wr = rw + (size_t)d * 8;
    #pragma unroll
    for (int e = 0; e < 8; ++e) p[e] += xv * wr[e];
  }
  #pragma unroll
  for (int e = 0; e < 8; ++e) {
    float v = p[e];
    #pragma unroll
    for (int o = 32; o > 0; o >>= 1) v += __shfl_xor(v, o);
    p[e] = v;
  }
  if (lane == 0) {
    float mx = p[0];
    #pragma unroll
    for (int e = 1; e < 8; ++e) mx = fmaxf(mx, p[e]);
    float s = 0.0f;
    #pragma unroll
    for (int e = 0; e < 8; ++e) { p[e] = expf(p[e] - mx); s += p[e]; }
    float invs = 1.0f / s;
    #pragma unroll
    for (int e = 0; e < 8; ++e) p[e] *= invs;
    int i1 = 0; float v1 = p[0];
    #pragma unroll
    for (int e = 1; e < 8; ++e) if (p[e] > v1) { v1 = p[e]; i1 = e; }
    int i2 = (i1 == 0) ? 1 : 0; float v2 = p[i2];
    #pragma unroll
    for (int e = 0; e < 8; ++e) if (e != i1 && p[e] > v2) { v2 = p[e]; i2 = e; }
    float wsum = v1 + v2;
    tk_idx[t * 2] = i1; tk_idx[t * 2 + 1] = i2;
    tk_w[t * 2] = v1 / wsum; tk_w[t * 2 + 1] = v2 / wsum;
    atomicAdd(&bcnt[i1], 1); atomicAdd(&bcnt[i2], 1);
    #pragma unroll
    for (int e = 0; e < 8; ++e) atomicAdd(&bps[e], p[e]);
  }
  __syncthreads();
  if (tid < 8) {
    atomicAdd(&cnt[tid], bcnt[tid]);
    atomicAdd(&psum[tid], bps[tid]);
  }
}

__global__ void moe_offsets_k(const int* __restrict__ cnt, int* __restrict__ offs,
                              const float* __restrict__ psum, float* __restrict__ aux) {
  if (threadIdx.x == 0) {
    int o = 0; float a = 0.0f;
    for (int e = 0; e < 8; ++e) {
      offs[e] = o;
      o += (cnt[e] + 127) & ~127;
      a += ((float)cnt[e] / 4096.0f) * (psum[e] / 4096.0f);
    }
    offs[8] = o;
    aux[0] += a * 8.0f;
  }
}

__global__ void moe_fill_k(const int* __restrict__ tk_idx, const int* __restrict__ offs,
                           int* __restrict__ fill, int* __restrict__ slot_token,
                           int* __restrict__ tk_slot) {
  int i = blockIdx.x * 256 + threadIdx.x;              // grid 32
  int e = tk_idx[i];
  int pos = atomicAdd(&fill[e], 1);
  int slot = offs[e] + pos;
  slot_token[slot] = i >> 1;
  tk_slot[i] = slot;
}

template <int BF>  // 0: os f32; 1: os bf16
__global__ void moe_combine_k(float* __restrict__ x, const void* __restrict__ osv,
                              const int* __restrict__ tk_slot, const float* __restrict__ tk_w) {
  int t = blockIdx.x;                                  // grid 4096 x 192
  int d = threadIdx.x << 2;
  int s0 = tk_slot[t * 2], s1 = tk_slot[t * 2 + 1];
  float w0 = tk_w[t * 2], w1 = tk_w[t * 2 + 1];
  float a0, a1, a2, a3, b0, b1, b2, b3;
  if (BF == 0) {
    const float* os = (const float*)osv;
    float4 a = *(const float4*)(os + (size_t)s0 * 768 + d);
    float4 b = *(const float4*)(os + (size_t)s1 * 768 + d);
    a0 = a.x; a1 = a.y; a2 = a.z; a3 = a.w;
    b0 = b.x; b1 = b.y; b2 = b.z; b3 = b.w;
  } else {
    const unsigned short* os = (const unsigned short*)osv;
    ushort4 a = *(const ushort4*)(os + (size_t)s0 * 768 + d);
    ushort4 b = *(const ushort4*)(os + (size_t)s1 * 768 + d);
    a0 = bf2f(a.x); a1 = bf2f(a.y); a2 = bf2f(a.z); a3 = bf2f(a.w);
    b0 = bf2f(b.x); b1 = bf2f(b.y); b2 = bf2f(b.z); b3 = bf2f(b.w);
  }
  float4 c = *(const float4*)(x + (size_t)t * 768 + d);
  c.x += w0 * a0 + w1 * b0;
  c.y += w0 * a1 + w1 * b1;
  c.z += w0 * a2 + w1 * b2;
  c.w += w0 * a3 + w1 * b3;
  *(float4*)(x + (size_t)t * 768 + d) = c;
}

__global__ void write_aux_k(const float* __restrict__ aux, float* __restrict__ out) {
  out[0] = aux[0];
}

// ---------------------------------------------------------------- host launcher

extern "C" void kernel_launch(void* const* d_in, const int* in_sizes, int n_in,
                              void* d_out, int out_size, void* d_ws, size_t ws_size,
                              hipStream_t stream) {
  const int* input_ids      = (const int*)d_in[0];
  const int* time_slots     = (const int*)d_in[1];
  const int* day_of_week    = (const int*)d_in[2];
  const int* month          = (const int*)d_in[3];
  const int* is_holiday     = (const int*)d_in[4];
  const int* location_ids   = (const int*)d_in[5];
  const int* road_types     = (const int*)d_in[6];
  const int* weather_states = (const int*)d_in[7];
  const float* word_emb     = (const float*)d_in[8];
  const float* time_emb     = (const float*)d_in[9];
  const float* dow_emb      = (const float*)d_in[10];
  const float* month_emb    = (const float*)d_in[11];
  const float* hol_emb      = (const float*)d_in[12];
  const float* loc_emb      = (const float*)d_in[13];
  const float* road_emb     = (const float*)d_in[14];
  const float* weather_emb  = (const float*)d_in[15];
  const float* proj_w       = (const float*)d_in[16];
  const float* proj_b       = (const float*)d_in[17];
  const float* emb_norm_w   = (const float*)d_in[18];
  const float* norm1_w      = (const float*)d_in[19];
  const float* Wq           = (const float*)d_in[20];
  const float* Wk           = (const float*)d_in[21];
  const float* Wv           = (const float*)d_in[22];
  const float* Wo           = (const float*)d_in[23];
  const float* norm2_w      = (const float*)d_in[24];
  const float* router_w     = (const float*)d_in[25];
  const float* Wg           = (const float*)d_in[26];
  const float* Wu           = (const float*)d_in[27];
  const float* Wd           = (const float*)d_in[28];
  const float* final_norm_w = (const float*)d_in[29];
  float* out = (float*)d_out;

  const size_t TD = (size_t)TTOK * 768;
  const size_t REG = (size_t)MAXSLOT * FDIM * 4;       // 113.25 MB shared regions
  char* base = (char*)d_ws;
  auto carve = [&](size_t bytes) { char* p = base; base += (bytes + 255) & ~(size_t)255; return p; };
  float* x    = (float*)carve(TD * 4);
  float* xn   = (float*)carve(TD * 4);
  float* cosb = (float*)carve(32768 * 4);
  float* sinb = (float*)carve(32768 * 4);
  float* ctx  = (float*)carve(4 * 1536 * 4);
  float* biasB= (float*)carve(4 * 768 * 4);
  float* tkw  = (float*)carve(8192 * 4);
  float* psum = (float*)carve(64);
  float* auxa = (float*)carve(64);
  int* cnt    = (int*)carve(64);
  int* fill   = (int*)carve(64);
  int* offs   = (int*)carve(64);
  int* tk_idx = (int*)carve(8192 * 4);
  int* tk_slot= (int*)carve(8192 * 4);
  int* slot_token = (int*)carve(MAXSLOT * 4);
  unsigned short* zp = (unsigned short*)carve(4096);
  unsigned short* xnb3 = (unsigned short*)carve(3 * TD * 2);
  char* QAH = carve(REG);                               // qkv+ax3 (attn) / h (moe)
  char* GT  = carve(REG);                               // gtmp / ob
  char* Wr  = carve(REG);                               // weight planes (sequential)
  float* qkv = (float*)QAH;
  unsigned short* ax3 = (unsigned short*)(QAH + (size_t)TTOK * 2304 * 4);
  float* hbf = (float*)QAH;
  unsigned short* hb16 = (unsigned short*)QAH;
  float* gtmp = (float*)GT;
  float* obf = (float*)GT;
  unsigned short* ob16 = (unsigned short*)GT;
  unsigned short* wpl = (unsigned short*)Wr;

  const size_t PS_D = (size_t)768 * 768;                // dense 768x768 plane stride
  const size_t PS_QKV = (size_t)2304 * 768;
  const size_t PS_E = (size_t)8 * FDIM * 768;           // expert-tensor plane stride

  hipMemsetAsync(auxa, 0, 64, stream);
  hipMemsetAsync(zp, 0, 4096, stream);
  rope_cache_k<<<dim3(1024), dim3(32), 0, stream>>>(cosb, sinb);
  build_ctx_k<<<dim3(4, 6), dim3(256), 0, stream>>>(time_slots, day_of_week, month, is_holiday,
      location_ids, road_types, weather_states, time_emb, dow_emb, month_emb, hol_emb,
      loc_emb, road_emb, weather_emb, ctx);
  build_bias_k<<<dim3(4, 3), dim3(256), 0, stream>>>(ctx, proj_w, proj_b, biasB);
  tconv3_k<<<dim3(24, 24, 1), dim3(32, 8), 0, stream>>>(proj_w, wpl, PS_D, 768, 768, 0, 0);
  gconv3_k<<<dim3(TTOK), dim3(192), 0, stream>>>(word_emb, input_ids, xnb3, TD);
  gemm3<3><<<dim3(6, 32), dim3(256), 0, stream>>>(xnb3, TD, wpl, PS_D, xn, 768, 768, biasB);
  rmsnorm_k<0><<<dim3(TTOK), dim3(256), 0, stream>>>(xn, emb_norm_w, x, nullptr, 0);

  for (int l = 0; l < 2; ++l) {
    const float* rw = router_w + (size_t)l * 768 * 8;
    // ---- attention (split-3, f32 accuracy) ----
    tconv3_k<<<dim3(24, 24, 1), dim3(32, 8), 0, stream>>>(Wq + (size_t)l * PS_D, wpl, PS_QKV, 768, 768, 0, 0);
    tconv3_k<<<dim3(24, 24, 1), dim3(32, 8), 0, stream>>>(Wk + (size_t)l * PS_D, wpl + PS_D, PS_QKV, 768, 768, 0, 0);
    tconv3_k<<<dim3(24, 24, 1), dim3(32, 8), 0, stream>>>(Wv + (size_t)l * PS_D, wpl + 2 * PS_D, PS_QKV, 768, 768, 0, 0);
    rmsnorm_k<1><<<dim3(TTOK), dim3(256), 0, stream>>>(x, norm1_w + l * 768, nullptr, xnb3, TD);
    gemm3<0><<<dim3(18, 32), dim3(256), 0, stream>>>(xnb3, TD, wpl, PS_QKV, qkv, 2304, 768, nullptr);
    rope_apply_k<<<dim3(6144), dim3(256), 0, stream>>>(qkv, cosb, sinb);
    attn_k<<<dim3(32, 12, 4), dim3(256), 0, stream>>>(qkv, ax3, TD);
    tconv3_k<<<dim3(24, 24, 1), dim3(32, 8), 0, stream>>>(Wo + (size_t)l * PS_D, wpl, PS_D, 768, 768, 0, 0);
    gemm3<2><<<dim3(6, 32), dim3(256), 0, stream>>>(ax3, TD, wpl, PS_D, x, 768, 768, nullptr);

    // ---- MoE ----
    if (l == 0)
      rmsnorm_k<2><<<dim3(TTOK), dim3(256), 0, stream>>>(x, norm2_w, xn, xnb3, TD);
    else
      rmsnorm_k<3><<<dim3(TTOK), dim3(256), 0, stream>>>(x, norm2_w + 768, xn, xnb3, TD);
    hipMemsetAsync(cnt, 0, 64, stream);
    hipMemsetAsync(fill, 0, 64, stream);
    hipMemsetAsync(psum, 0, 64, stream);
    hipMemsetAsync(slot_token, 0xFF, MAXSLOT * 4, stream);
    router_k<<<dim3(1024), dim3(256), 0, stream>>>(xn, rw, tk_idx, tkw, cnt, psum);
    moe_offsets_k<<<dim3(1), dim3(64), 0, stream>>>(cnt, offs, psum, auxa);
    moe_fill_k<<<dim3(32), dim3(256), 0, stream>>>(tk_idx, offs, fill, slot_token, tk_slot);
    if (l == 0) {
      // split-3 experts (feed layer-1 router: must be f32-accurate)
      tconv3_k<<<dim3(96, 24, 8), dim3(32, 8), 0, stream>>>(Wg, wpl, PS_E,
          768, FDIM, (size_t)768 * FDIM, (size_t)FDIM * 768);
      gemm3_gu<0><<<dim3(24, MAXSLOT / 128), dim3(256), 0, stream>>>(xnb3, TD, wpl, PS_E,
          gtmp, nullptr, slot_token, offs, zp);
      tconv3_k<<<dim3(96, 24, 8), dim3(32, 8), 0, stream>>>(Wu, wpl, PS_E,
          768, FDIM, (size_t)768 * FDIM, (size_t)FDIM * 768);
      gemm3_gu<1><<<dim3(24, MAXSLOT / 128), dim3(256), 0, stream>>>(xnb3, TD, wpl, PS_E,
          hbf, gtmp, slot_token, offs, zp);
      tconv3_k<<<dim3(24, 96, 8), dim3(32, 8), 0, stream>>>(Wd, wpl, PS_E,
          FDIM, 768, (size_t)FDIM * 768, (size_t)768 * FDIM);
      gemm3_dn<<<dim3(6, MAXSLOT / 128), dim3(256), 0, stream>>>(hbf, wpl, PS_E, obf, offs);
      moe_combine_k<0><<<dim3(TTOK), dim3(192), 0, stream>>>(x, obf, tk_slot, tkw);
    } else {
      // plain bf16 experts (feed only final output)
      const float* wg1 = Wg + (size_t)8 * 768 * FDIM;
      const float* wu1 = Wu + (size_t)8 * 768 * FDIM;
      const float* wd1 = Wd + (size_t)8 * FDIM * 768;
      tconv_k<<<dim3(96, 24, 8), dim3(32, 8), 0, stream>>>(wg1, wpl,
          768, FDIM, (size_t)768 * FDIM, (size_t)FDIM * 768);
      tconv_k<<<dim3(96, 24, 8), dim3(32, 8), 0, stream>>>(wu1, wpl + PS_E,
          768, FDIM, (size_t)768 * FDIM, (size_t)FDIM * 768);
      gemm_gu<<<dim3(24, MAXSLOT / 128), dim3(256), 0, stream>>>(xnb3, wpl, wpl + PS_E,
          hb16, slot_token, offs, zp);
      tconv_k<<<dim3(24, 96, 8), dim3(32, 8), 0, stream>>>(wd1, wpl,
          FDIM, 768, (size_t)FDIM * 768, (size_t)768 * FDIM);
      gemm_d<<<dim3(6, MAXSLOT / 128), dim3(256), 0, stream>>>(hb16, wpl, ob16, offs);
      moe_combine_k<1><<<dim3(TTOK), dim3(192), 0, stream>>>(x, ob16, tk_slot, tkw);
    }
  }

  rmsnorm_k<0><<<dim3(TTOK), dim3(256), 0, stream>>>(x, final_norm_w, out, nullptr, 0);
  write_aux_k<<<dim3(1), dim3(1), 0, stream>>>(auxa, out + TD);
}

// Round 4
// 2601.520 us; speedup vs baseline: 1.8489x; 1.1523x over previous
//
#include <hip/hip_runtime.h>
#include <math.h>

// Traffic foundation model, round 3.
// Round-2 passing structure (split-3 bf16-MFMA emulated-f32 for routing-critical
// GEMMs; plain bf16 MFMA for layer-1 experts; exact f32 router) with attn_k
// rewritten: 64x64 tiles, register-tiled 4x4 outer product, float4 LDS reads,
// P aliased onto K buffer, causal pair-balanced grid (8,12,4) -> uniform 17
// k-tiles/block. B=4 S=1024 D=768 H=12 HD=64 L=2 E=8 F=3072.

#define TTOK 4096
#define FDIM 3072
#define MAXSLOT 9216   // 8192 + 8*127 pad, 128-aligned offsets

typedef __attribute__((ext_vector_type(8))) short short8;
typedef __attribute__((ext_vector_type(4))) float f32x4;

__device__ __forceinline__ float bf2f(unsigned short u) {
  return __uint_as_float(((unsigned int)u) << 16);
}
__device__ __forceinline__ unsigned short f2bf(float f) {
  unsigned int u = __float_as_uint(f);
  u += 0x7fffu + ((u >> 16) & 1u);
  return (unsigned short)(u >> 16);
}
// exact 3-way bf16 split: a ~= h + m + l to ~24 mantissa bits
__device__ __forceinline__ void split3f(float a, unsigned short& h, unsigned short& m,
                                        unsigned short& l) {
  h = f2bf(a);
  float r = a - bf2f(h);
  m = f2bf(r);
  r -= bf2f(m);
  l = f2bf(r);
}
__device__ __forceinline__ void gload16(const void* g, void* l) {
  __builtin_amdgcn_global_load_lds((const __attribute__((address_space(1))) unsigned int*)g,
                                   (__attribute__((address_space(3))) unsigned int*)l, 16, 0, 0);
}

// 6-term split-3 MFMA accumulate (smallest terms first)
#define MFMA_TERM(ACC, PA, PB)                                                              \
  _Pragma("unroll") for (int i_ = 0; i_ < 4; ++i_)                                          \
      _Pragma("unroll") for (int j_ = 0; j_ < 4; ++j_)                                      \
          ACC[i_][j_] = __builtin_amdgcn_mfma_f32_16x16x32_bf16(af[PA][i_], bf[PB][j_],     \
                                                                ACC[i_][j_], 0, 0, 0);
#define MFMA_SPLIT3(ACC)  \
  MFMA_TERM(ACC, 0, 2) MFMA_TERM(ACC, 2, 0) MFMA_TERM(ACC, 1, 1) \
  MFMA_TERM(ACC, 0, 1) MFMA_TERM(ACC, 1, 0) MFMA_TERM(ACC, 0, 0)

// ---------------------------------------------------------------- small kernels

__global__ void rope_cache_k(float* __restrict__ cosb, float* __restrict__ sinb) {
  int s = blockIdx.x, i = threadIdx.x;                 // grid 1024 x 32
  float inv = powf(10000.0f, -(float)i / 32.0f);
  float a = (float)s * inv;
  cosb[s * 32 + i] = cosf(a);
  sinb[s * 32 + i] = sinf(a);
}

__global__ void build_ctx_k(const int* ts, const int* dow, const int* mon, const int* hol,
                            const int* loc, const int* road, const int* wth,
                            const float* te, const float* de, const float* me, const float* he,
                            const float* le, const float* re, const float* we,
                            float* __restrict__ ctx) {
  int b = blockIdx.x;
  int j = blockIdx.y * 256 + threadIdx.x;              // grid (4,6) x 256
  float v;
  if (j < 192)       v = te[ts[b] * 192 + j];
  else if (j < 384)  v = de[dow[b] * 192 + (j - 192)];
  else if (j < 576)  v = me[mon[b] * 192 + (j - 384)];
  else if (j < 768)  v = he[hol[b] * 192 + (j - 576)];
  else if (j < 1152) v = le[loc[b] * 384 + (j - 768)];
  else if (j < 1344) v = re[road[b] * 192 + (j - 1152)];
  else               v = we[wth[b] * 192 + (j - 1344)];
  ctx[b * 1536 + j] = v;
}

// biasB[b][d] = proj_b[d] + sum_j ctx[b][j] * proj_w[768+j][d]  (exact f32)
__global__ void build_bias_k(const float* __restrict__ ctx, const float* __restrict__ pw,
                             const float* __restrict__ pb, float* __restrict__ biasB) {
  int b = blockIdx.x;
  int d = blockIdx.y * 256 + threadIdx.x;              // grid (4,3) x 256
  float s = pb[d];
  const float* cb = ctx + b * 1536;
  for (int j = 0; j < 1536; ++j) s += cb[j] * pw[(size_t)(768 + j) * 768 + d];
  biasB[b * 768 + d] = s;
}

// transpose + split-3: dst[p][n][k] = split(src[k][n]). grid (N/32, K/32, batch), block (32,8)
__global__ void tconv3_k(const float* __restrict__ src, unsigned short* __restrict__ dst,
                         size_t dPS, int K, int N, size_t sstride, size_t dstride) {
  __shared__ float tile[32][33];
  src += (size_t)blockIdx.z * sstride;
  size_t dbase = (size_t)blockIdx.z * dstride;
  int n0 = blockIdx.x * 32, k0 = blockIdx.y * 32;
  int tx = threadIdx.x, ty = threadIdx.y;
  #pragma unroll
  for (int r = 0; r < 4; ++r)
    tile[ty + r * 8][tx] = src[(size_t)(k0 + ty + r * 8) * N + n0 + tx];
  __syncthreads();
  #pragma unroll
  for (int r = 0; r < 4; ++r) {
    int n = n0 + ty + r * 8;
    unsigned short h, m, lo;
    split3f(tile[tx][ty + r * 8], h, m, lo);
    size_t di = dbase + (size_t)n * K + k0 + tx;
    dst[di] = h; dst[di + dPS] = m; dst[di + 2 * dPS] = lo;
  }
}

// transpose-convert single plane (plain bf16, for layer-1 experts)
__global__ void tconv_k(const float* __restrict__ src, unsigned short* __restrict__ dst,
                        int K, int N, size_t sstride, size_t dstride) {
  __shared__ unsigned short tile[32][33];
  src += (size_t)blockIdx.z * sstride;
  unsigned short* d = dst + (size_t)blockIdx.z * dstride;
  int n0 = blockIdx.x * 32, k0 = blockIdx.y * 32;
  int tx = threadIdx.x, ty = threadIdx.y;
  #pragma unroll
  for (int r = 0; r < 4; ++r)
    tile[ty + r * 8][tx] = f2bf(src[(size_t)(k0 + ty + r * 8) * N + n0 + tx]);
  __syncthreads();
  #pragma unroll
  for (int r = 0; r < 4; ++r) {
    int n = n0 + ty + r * 8;
    d[(size_t)n * K + k0 + tx] = tile[tx][ty + r * 8];
  }
}

// gather word_emb rows -> 3 planes. grid 4096 x 192
__global__ void gconv3_k(const float* __restrict__ we, const int* __restrict__ ids,
                         unsigned short* __restrict__ x3, size_t pPS) {
  int t = blockIdx.x;
  int d = threadIdx.x << 2;
  float4 v = *(const float4*)(we + (size_t)ids[t] * 768 + d);
  ushort4 vh, vm, vl;
  split3f(v.x, vh.x, vm.x, vl.x);
  split3f(v.y, vh.y, vm.y, vl.y);
  split3f(v.z, vh.z, vm.z, vl.z);
  split3f(v.w, vh.w, vm.w, vl.w);
  size_t o = (size_t)t * 768 + d;
  *(ushort4*)(x3 + o) = vh;
  *(ushort4*)(x3 + pPS + o) = vm;
  *(ushort4*)(x3 + 2 * pPS + o) = vl;
}

// OUT: 0 f32 only; 1 3-plane only; 2 f32 + 3-plane; 3 f32 + single-bf16(plane0)
template <int OUT>
__global__ __launch_bounds__(256) void rmsnorm_k(const float* __restrict__ xin,
                                                 const float* __restrict__ w,
                                                 float* __restrict__ yf,
                                                 unsigned short* __restrict__ yb, size_t pPS) {
  int t = blockIdx.x;
  int tid = threadIdx.x;
  const float* xr = xin + (size_t)t * 768;
  float v0 = xr[tid], v1 = xr[tid + 256], v2 = xr[tid + 512];
  float ss = v0 * v0 + v1 * v1 + v2 * v2;
  #pragma unroll
  for (int o = 32; o > 0; o >>= 1) ss += __shfl_xor(ss, o);
  __shared__ float wss[4];
  if ((tid & 63) == 0) wss[tid >> 6] = ss;
  __syncthreads();
  float tot = wss[0] + wss[1] + wss[2] + wss[3];
  float inv = 1.0f / sqrtf(tot / 768.0f + 1e-6f);
  float o0 = v0 * inv * w[tid], o1 = v1 * inv * w[tid + 256], o2 = v2 * inv * w[tid + 512];
  if (OUT != 1) {
    float* yr = yf + (size_t)t * 768;
    yr[tid] = o0; yr[tid + 256] = o1; yr[tid + 512] = o2;
  }
  if (OUT == 1 || OUT == 2) {
    unsigned short* yr = yb + (size_t)t * 768;
    unsigned short h, m, l;
    split3f(o0, h, m, l); yr[tid] = h;       yr[tid + pPS] = m;       yr[tid + 2 * pPS] = l;
    split3f(o1, h, m, l); yr[tid + 256] = h; yr[tid + 256 + pPS] = m; yr[tid + 256 + 2 * pPS] = l;
    split3f(o2, h, m, l); yr[tid + 512] = h; yr[tid + 512 + pPS] = m; yr[tid + 512 + 2 * pPS] = l;
  }
  if (OUT == 3) {
    unsigned short* yr = yb + (size_t)t * 768;
    yr[tid] = f2bf(o0); yr[tid + 256] = f2bf(o1); yr[tid + 512] = f2bf(o2);
  }
}

// rope in-place on f32 qkv [T][2304] (q at 0, k at 768)
__global__ __launch_bounds__(256) void rope_apply_k(float* __restrict__ qkv,
                                                    const float* __restrict__ cosb,
                                                    const float* __restrict__ sinb) {
  int idx = blockIdx.x * 256 + threadIdx.x;            // grid 6144
  int j = idx & 31;
  int hh = (idx >> 5) % 12;
  int t = idx / 384;
  int s = t & 1023;
  float c = cosb[s * 32 + j], sn = sinb[s * 32 + j];
  size_t base = (size_t)t * 2304 + hh * 64 + j;
  float q1 = qkv[base], q2 = qkv[base + 32];
  qkv[base]      = q1 * c - q2 * sn;
  qkv[base + 32] = q2 * c + q1 * sn;
  size_t kb = base + 768;
  float k1 = qkv[kb], k2 = qkv[kb + 32];
  qkv[kb]      = k1 * c - k2 * sn;
  qkv[kb + 32] = k2 * c + k1 * sn;
}

// ---------------------------------------------------------------- split-3 dense GEMM
// C[M,N] = A@BT^T, A/BT 3-plane bf16 (plane strides aPS/bPS). 128x128 tile, 4 waves.
// EPI: 0 f32 store; 2 f32 +=; 3 f32 store + per-batch bias
template <int EPI>
__global__ __launch_bounds__(256) void gemm3(const unsigned short* __restrict__ A, size_t aPS,
                                             const unsigned short* __restrict__ BT, size_t bPS,
                                             float* __restrict__ Cf, int N, int K,
                                             const float* __restrict__ rowBias) {
  __shared__ __align__(16) unsigned short As[3][4096];
  __shared__ __align__(16) unsigned short Bs[3][4096];
  int tid = threadIdx.x, w = tid >> 6, l = tid & 63, lr = l & 15, lg = l >> 4;
  int m0 = blockIdx.y * 128, n0 = blockIdx.x * 128;
  size_t aoff = (size_t)(m0 + 32 * w + lr) * K + lg * 8;
  size_t boff = (size_t)(n0 + 32 * w + lr) * K + lg * 8;
  size_t aoff1 = aoff + (size_t)16 * K, boff1 = boff + (size_t)16 * K;
  f32x4 acc[4][4];
  #pragma unroll
  for (int i = 0; i < 4; ++i)
    #pragma unroll
    for (int j = 0; j < 4; ++j) acc[i][j] = (f32x4){0.f, 0.f, 0.f, 0.f};
  int wr = w >> 1, wc = w & 1;
  for (int k0 = 0; k0 < K; k0 += 32) {
    #pragma unroll
    for (int p = 0; p < 3; ++p) {
      gload16(A + p * aPS + aoff + k0,  &As[p][1024 * w]);
      gload16(A + p * aPS + aoff1 + k0, &As[p][1024 * w + 512]);
      gload16(BT + p * bPS + boff + k0,  &Bs[p][1024 * w]);
      gload16(BT + p * bPS + boff1 + k0, &Bs[p][1024 * w + 512]);
    }
    __syncthreads();
    short8 af[3][4], bf[3][4];
    #pragma unroll
    for (int p = 0; p < 3; ++p)
      #pragma unroll
      for (int i = 0; i < 4; ++i) {
        af[p][i] = *(const short8*)(&As[p][(wr * 4 + i) * 512 + l * 8]);
        bf[p][i] = *(const short8*)(&Bs[p][(wc * 4 + i) * 512 + l * 8]);
      }
    MFMA_SPLIT3(acc)
    __syncthreads();
  }
  int colb = n0 + wc * 64 + lr;
  int rowb = m0 + wr * 64 + lg * 4;
  #pragma unroll
  for (int i = 0; i < 4; ++i)
    #pragma unroll
    for (int j = 0; j < 4; ++j) {
      int col = colb + j * 16;
      #pragma unroll
      for (int r = 0; r < 4; ++r) {
        int row = rowb + i * 16 + r;
        size_t idx = (size_t)row * N + col;
        float v = acc[i][j][r];
        if (EPI == 0)      Cf[idx] = v;
        else if (EPI == 2) Cf[idx] += v;
        else               Cf[idx] = v + rowBias[(row >> 10) * 768 + col];
      }
    }
}

// split-3 MoE gate/up GEMM, gathered A rows. FUSE 0: store f32 (g pass);
// FUSE 1: read g, out = silu(g)*u (u pass). N=3072, K=768.
template <int FUSE>
__global__ __launch_bounds__(256) void gemm3_gu(const unsigned short* __restrict__ X3, size_t xPS,
    const unsigned short* __restrict__ W3, size_t wPS, float* __restrict__ outb,
    const float* __restrict__ gin, const int* __restrict__ slot_token,
    const int* __restrict__ offs, const unsigned short* __restrict__ zp) {
  __shared__ __align__(16) unsigned short As[3][4096];
  __shared__ __align__(16) unsigned short Bs[3][4096];
  int sb = blockIdx.y * 128;
  if (sb >= offs[8]) return;
  int e = 0;
  #pragma unroll
  for (int i = 1; i < 8; ++i) if (sb >= offs[i]) e = i;
  int tid = threadIdx.x, w = tid >> 6, l = tid & 63, lr = l & 15, lg = l >> 4;
  int n0 = blockIdx.x * 128;
  const unsigned short* WE = W3 + (size_t)e * FDIM * 768;
  int t0 = slot_token[sb + 32 * w + lr];
  int t1 = slot_token[sb + 32 * w + 16 + lr];
  const unsigned short* a0[3];
  const unsigned short* a1[3];
  #pragma unroll
  for (int p = 0; p < 3; ++p) {
    a0[p] = (t0 < 0 ? zp : X3 + p * xPS + (size_t)t0 * 768) + lg * 8;
    a1[p] = (t1 < 0 ? zp : X3 + p * xPS + (size_t)t1 * 768) + lg * 8;
  }
  size_t boff = (size_t)(n0 + 32 * w + lr) * 768 + lg * 8;
  size_t boff1 = boff + (size_t)16 * 768;
  f32x4 acc[4][4];
  #pragma unroll
  for (int i = 0; i < 4; ++i)
    #pragma unroll
    for (int j = 0; j < 4; ++j) acc[i][j] = (f32x4){0.f, 0.f, 0.f, 0.f};
  int wr = w >> 1, wc = w & 1;
  for (int k0 = 0; k0 < 768; k0 += 32) {
    #pragma unroll
    for (int p = 0; p < 3; ++p) {
      gload16(a0[p] + k0, &As[p][1024 * w]);
      gload16(a1[p] + k0, &As[p][1024 * w + 512]);
      gload16(WE + p * wPS + boff + k0,  &Bs[p][1024 * w]);
      gload16(WE + p * wPS + boff1 + k0, &Bs[p][1024 * w + 512]);
    }
    __syncthreads();
    short8 af[3][4], bf[3][4];
    #pragma unroll
    for (int p = 0; p < 3; ++p)
      #pragma unroll
      for (int i = 0; i < 4; ++i) {
        af[p][i] = *(const short8*)(&As[p][(wr * 4 + i) * 512 + l * 8]);
        bf[p][i] = *(const short8*)(&Bs[p][(wc * 4 + i) * 512 + l * 8]);
      }
    MFMA_SPLIT3(acc)
    __syncthreads();
  }
  int colb = n0 + wc * 64 + lr;
  int rowb = sb + wr * 64 + lg * 4;
  #pragma unroll
  for (int i = 0; i < 4; ++i)
    #pragma unroll
    for (int j = 0; j < 4; ++j) {
      int col = colb + j * 16;
      #pragma unroll
      for (int r = 0; r < 4; ++r) {
        size_t idx = (size_t)(rowb + i * 16 + r) * FDIM + col;
        float v = acc[i][j][r];
        if (FUSE == 0) outb[idx] = v;
        else {
          float g = gin[idx];
          outb[idx] = g / (1.0f + expf(-g)) * v;       // silu(g)*u
        }
      }
    }
}

// split-3 MoE down GEMM: A = h (f32, split in-kernel), B = wd planes. N=768, K=3072.
__global__ __launch_bounds__(256) void gemm3_dn(const float* __restrict__ hbf,
    const unsigned short* __restrict__ W3, size_t wPS, float* __restrict__ ob,
    const int* __restrict__ offs) {
  __shared__ __align__(16) unsigned short As[3][4096];
  __shared__ __align__(16) unsigned short Bs[3][4096];
  int sb = blockIdx.y * 128;
  if (sb >= offs[8]) return;
  int e = 0;
  #pragma unroll
  for (int i = 1; i < 8; ++i) if (sb >= offs[i]) e = i;
  int tid = threadIdx.x, w = tid >> 6, l = tid & 63, lr = l & 15, lg = l >> 4;
  int n0 = blockIdx.x * 128;
  const unsigned short* WE = W3 + (size_t)e * 768 * FDIM;
  size_t boff = (size_t)(n0 + 32 * w + lr) * FDIM + lg * 8;
  size_t boff1 = boff + (size_t)16 * FDIM;
  const float* ha0 = hbf + (size_t)(sb + 32 * w + lr) * FDIM + lg * 8;
  const float* ha1 = ha0 + (size_t)16 * FDIM;
  f32x4 acc[4][4];
  #pragma unroll
  for (int i = 0; i < 4; ++i)
    #pragma unroll
    for (int j = 0; j < 4; ++j) acc[i][j] = (f32x4){0.f, 0.f, 0.f, 0.f};
  int wr = w >> 1, wc = w & 1;
  for (int k0 = 0; k0 < FDIM; k0 += 32) {
    #pragma unroll
    for (int p = 0; p < 3; ++p) {
      gload16(WE + p * wPS + boff + k0,  &Bs[p][1024 * w]);
      gload16(WE + p * wPS + boff1 + k0, &Bs[p][1024 * w + 512]);
    }
    {
      float4 v0 = *(const float4*)(ha0 + k0);
      float4 v1 = *(const float4*)(ha0 + k0 + 4);
      float va[8] = {v0.x, v0.y, v0.z, v0.w, v1.x, v1.y, v1.z, v1.w};
      short8 sh, sm, sl;
      #pragma unroll
      for (int q = 0; q < 8; ++q) {
        unsigned short a, b, c;
        split3f(va[q], a, b, c);
        sh[q] = (short)a; sm[q] = (short)b; sl[q] = (short)c;
      }
      *(short8*)(&As[0][1024 * w + l * 8]) = sh;
      *(short8*)(&As[1][1024 * w + l * 8]) = sm;
      *(short8*)(&As[2][1024 * w + l * 8]) = sl;
      v0 = *(const float4*)(ha1 + k0);
      v1 = *(const float4*)(ha1 + k0 + 4);
      float vb[8] = {v0.x, v0.y, v0.z, v0.w, v1.x, v1.y, v1.z, v1.w};
      #pragma unroll
      for (int q = 0; q < 8; ++q) {
        unsigned short a, b, c;
        split3f(vb[q], a, b, c);
        sh[q] = (short)a; sm[q] = (short)b; sl[q] = (short)c;
      }
      *(short8*)(&As[0][1024 * w + 512 + l * 8]) = sh;
      *(short8*)(&As[1][1024 * w + 512 + l * 8]) = sm;
      *(short8*)(&As[2][1024 * w + 512 + l * 8]) = sl;
    }
    __syncthreads();
    short8 af[3][4], bf[3][4];
    #pragma unroll
    for (int p = 0; p < 3; ++p)
      #pragma unroll
      for (int i = 0; i < 4; ++i) {
        af[p][i] = *(const short8*)(&As[p][(wr * 4 + i) * 512 + l * 8]);
        bf[p][i] = *(const short8*)(&Bs[p][(wc * 4 + i) * 512 + l * 8]);
      }
    MFMA_SPLIT3(acc)
    __syncthreads();
  }
  int colb = n0 + wc * 64 + lr;
  int rowb = sb + wr * 64 + lg * 4;
  #pragma unroll
  for (int i = 0; i < 4; ++i)
    #pragma unroll
    for (int j = 0; j < 4; ++j) {
      int col = colb + j * 16;
      #pragma unroll
      for (int r = 0; r < 4; ++r)
        ob[(size_t)(rowb + i * 16 + r) * 768 + col] = acc[i][j][r];
    }
}

// ---------------------------------------------------------------- plain bf16 GEMMs (layer-1 MoE)

__global__ __launch_bounds__(256) void gemm_gu(const unsigned short* __restrict__ xnb,
    const unsigned short* __restrict__ wgT, const unsigned short* __restrict__ wuT,
    unsigned short* __restrict__ hb, const int* __restrict__ slot_token,
    const int* __restrict__ offs, const unsigned short* __restrict__ zp) {
  __shared__ __align__(16) unsigned short As[4096], Bg[4096], Bu[4096];
  int sb = blockIdx.y * 128;
  if (sb >= offs[8]) return;
  int e = 0;
  #pragma unroll
  for (int i = 1; i < 8; ++i) if (sb >= offs[i]) e = i;
  int tid = threadIdx.x, w = tid >> 6, l = tid & 63, lr = l & 15, lg = l >> 4;
  int n0 = blockIdx.x * 128;
  int t0 = slot_token[sb + 32 * w + lr];
  int t1 = slot_token[sb + 32 * w + 16 + lr];
  const unsigned short* ga0 = (t0 < 0 ? zp : xnb + (size_t)t0 * 768) + lg * 8;
  const unsigned short* ga1 = (t1 < 0 ? zp : xnb + (size_t)t1 * 768) + lg * 8;
  const unsigned short* WgE = wgT + (size_t)e * FDIM * 768;
  const unsigned short* WuE = wuT + (size_t)e * FDIM * 768;
  const unsigned short* gg0 = WgE + (size_t)(n0 + 32 * w + lr) * 768 + lg * 8;
  const unsigned short* gg1 = gg0 + 16 * 768;
  const unsigned short* gu0 = WuE + (size_t)(n0 + 32 * w + lr) * 768 + lg * 8;
  const unsigned short* gu1 = gu0 + 16 * 768;
  f32x4 ag[4][4], au[4][4];
  #pragma unroll
  for (int i = 0; i < 4; ++i)
    #pragma unroll
    for (int j = 0; j < 4; ++j) {
      ag[i][j] = (f32x4){0.f, 0.f, 0.f, 0.f};
      au[i][j] = (f32x4){0.f, 0.f, 0.f, 0.f};
    }
  int wr = w >> 1, wc = w & 1;
  for (int k0 = 0; k0 < 768; k0 += 32) {
    gload16(ga0 + k0, As + 1024 * w);
    gload16(ga1 + k0, As + 1024 * w + 512);
    gload16(gg0 + k0, Bg + 1024 * w);
    gload16(gg1 + k0, Bg + 1024 * w + 512);
    gload16(gu0 + k0, Bu + 1024 * w);
    gload16(gu1 + k0, Bu + 1024 * w + 512);
    __syncthreads();
    short8 af[4];
    #pragma unroll
    for (int i = 0; i < 4; ++i) af[i] = *(const short8*)(As + (wr * 4 + i) * 512 + l * 8);
    #pragma unroll
    for (int j = 0; j < 4; ++j) {
      short8 bg = *(const short8*)(Bg + (wc * 4 + j) * 512 + l * 8);
      short8 bu = *(const short8*)(Bu + (wc * 4 + j) * 512 + l * 8);
      #pragma unroll
      for (int i = 0; i < 4; ++i) {
        ag[i][j] = __builtin_amdgcn_mfma_f32_16x16x32_bf16(af[i], bg, ag[i][j], 0, 0, 0);
        au[i][j] = __builtin_amdgcn_mfma_f32_16x16x32_bf16(af[i], bu, au[i][j], 0, 0, 0);
      }
    }
    __syncthreads();
  }
  int colb = n0 + wc * 64 + lr;
  int rowb = sb + wr * 64 + lg * 4;
  #pragma unroll
  for (int i = 0; i < 4; ++i)
    #pragma unroll
    for (int j = 0; j < 4; ++j) {
      int col = colb + j * 16;
      #pragma unroll
      for (int r = 0; r < 4; ++r) {
        float g = ag[i][j][r], u = au[i][j][r];
        hb[(size_t)(rowb + i * 16 + r) * FDIM + col] = f2bf(g / (1.0f + expf(-g)) * u);
      }
    }
}

__global__ __launch_bounds__(256) void gemm_d(const unsigned short* __restrict__ hb,
    const unsigned short* __restrict__ wdT, unsigned short* __restrict__ ob,
    const int* __restrict__ offs) {
  __shared__ __align__(16) unsigned short As[4096], Bs[4096];
  int sb = blockIdx.y * 128;
  if (sb >= offs[8]) return;
  int e = 0;
  #pragma unroll
  for (int i = 1; i < 8; ++i) if (sb >= offs[i]) e = i;
  int tid = threadIdx.x, w = tid >> 6, l = tid & 63, lr = l & 15, lg = l >> 4;
  int n0 = blockIdx.x * 128;
  const unsigned short* ga0 = hb + (size_t)(sb + 32 * w + lr) * FDIM + lg * 8;
  const unsigned short* ga1 = ga0 + (size_t)16 * FDIM;
  const unsigned short* WdE = wdT + (size_t)e * 768 * FDIM;
  const unsigned short* gb0 = WdE + (size_t)(n0 + 32 * w + lr) * FDIM + lg * 8;
  const unsigned short* gb1 = gb0 + (size_t)16 * FDIM;
  f32x4 acc[4][4];
  #pragma unroll
  for (int i = 0; i < 4; ++i)
    #pragma unroll
    for (int j = 0; j < 4; ++j) acc[i][j] = (f32x4){0.f, 0.f, 0.f, 0.f};
  int wr = w >> 1, wc = w & 1;
  for (int k0 = 0; k0 < FDIM; k0 += 32) {
    gload16(ga0 + k0, As + 1024 * w);
    gload16(ga1 + k0, As + 1024 * w + 512);
    gload16(gb0 + k0, Bs + 1024 * w);
    gload16(gb1 + k0, Bs + 1024 * w + 512);
    __syncthreads();
    short8 af[4], bf[4];
    #pragma unroll
    for (int i = 0; i < 4; ++i) af[i] = *(const short8*)(As + (wr * 4 + i) * 512 + l * 8);
    #pragma unroll
    for (int j = 0; j < 4; ++j) bf[j] = *(const short8*)(Bs + (wc * 4 + j) * 512 + l * 8);
    #pragma unroll
    for (int i = 0; i < 4; ++i)
      #pragma unroll
      for (int j = 0; j < 4; ++j)
        acc[i][j] = __builtin_amdgcn_mfma_f32_16x16x32_bf16(af[i], bf[j], acc[i][j], 0, 0, 0);
    __syncthreads();
  }
  int colb = n0 + wc * 64 + lr;
  int rowb = sb + wr * 64 + lg * 4;
  #pragma unroll
  for (int i = 0; i < 4; ++i)
    #pragma unroll
    for (int j = 0; j < 4; ++j) {
      int col = colb + j * 16;
      #pragma unroll
      for (int r = 0; r < 4; ++r)
        ob[(size_t)(rowb + i * 16 + r) * 768 + col] = f2bf(acc[i][j][r]);
    }
}

// ---------------------------------------------------------------- attention (f32, register-tiled)
// 64x64 tiles. Block=256 threads, thread (ty,tx) owns 4q x 4k / 4q x 4d micro-tiles.
// Causal pair-balancing: block pr handles q-tiles pr and 15-pr -> uniform 17 k-tiles.
// P aliased onto K LDS buffer. LDS = 3*64*68*4 = 52 KB -> 3 blocks/CU.
__global__ __launch_bounds__(256) void attn_k(const float* __restrict__ qkv,
                                              unsigned short* __restrict__ ax3, size_t pPS) {
  int pr = blockIdx.x, h = blockIdx.y, b = blockIdx.z;
  int tid = threadIdx.x;
  int ty4 = (tid >> 4) << 2, tx4 = (tid & 15) << 2;
  __shared__ float qs[64][68];    // [d][q]
  __shared__ float kps[64][68];   // [d][k] during QK, then [q][k] = P during PV
  __shared__ float vs[64][68];    // [k][d]
  int lr = tid >> 2;              // 0..63 load row
  int lc = (tid & 3) << 4;        // 0,16,32,48 d-chunk
  for (int half = 0; half < 2; ++half) {
    int qt = half ? (15 - pr) : pr;
    int q0 = qt << 6;
    size_t qbase = ((size_t)(b * 1024 + q0 + lr)) * 2304 + h * 64 + lc;
    #pragma unroll
    for (int i = 0; i < 4; ++i) {
      float4 v = *(const float4*)(qkv + qbase + 4 * i);
      qs[lc + 4 * i + 0][lr] = v.x;
      qs[lc + 4 * i + 1][lr] = v.y;
      qs[lc + 4 * i + 2][lr] = v.z;
      qs[lc + 4 * i + 3][lr] = v.w;
    }
    float acc[4][4];
    float m[4], l[4];
    #pragma unroll
    for (int i = 0; i < 4; ++i) {
      m[i] = -3.0e38f; l[i] = 0.0f;
      #pragma unroll
      for (int j = 0; j < 4; ++j) acc[i][j] = 0.0f;
    }
    for (int kt = 0; kt <= qt; ++kt) {
      int k0 = kt << 6;
      __syncthreads();                                  // prev PV / Q-store ordering
      size_t kb = ((size_t)(b * 1024 + k0 + lr)) * 2304 + 768 + h * 64 + lc;
      #pragma unroll
      for (int i = 0; i < 4; ++i) {
        float4 kv = *(const float4*)(qkv + kb + 4 * i);
        kps[lc + 4 * i + 0][lr] = kv.x;
        kps[lc + 4 * i + 1][lr] = kv.y;
        kps[lc + 4 * i + 2][lr] = kv.z;
        kps[lc + 4 * i + 3][lr] = kv.w;
        *(float4*)&vs[lr][lc + 4 * i] = *(const float4*)(qkv + kb + 768 + 4 * i);
      }
      __syncthreads();                                  // K,V visible
      float s[4][4];
      #pragma unroll
      for (int i = 0; i < 4; ++i)
        #pragma unroll
        for (int j = 0; j < 4; ++j) s[i][j] = 0.0f;
      #pragma unroll 8
      for (int d = 0; d < 64; ++d) {
        float4 qv = *(const float4*)&qs[d][ty4];
        float4 kv = *(const float4*)&kps[d][tx4];
        float qa[4] = {qv.x, qv.y, qv.z, qv.w};
        float ka[4] = {kv.x, kv.y, kv.z, kv.w};
        #pragma unroll
        for (int i = 0; i < 4; ++i)
          #pragma unroll
          for (int j = 0; j < 4; ++j) s[i][j] += qa[i] * ka[j];
      }
      bool diag = (kt == qt);
      #pragma unroll
      for (int i = 0; i < 4; ++i) {
        #pragma unroll
        for (int j = 0; j < 4; ++j) {
          if (diag && (tx4 + j > ty4 + i)) s[i][j] = -1.0e30f;
          else s[i][j] *= 0.125f;                       // 1/sqrt(64)
        }
        float mx = fmaxf(fmaxf(s[i][0], s[i][1]), fmaxf(s[i][2], s[i][3]));
        mx = fmaxf(mx, __shfl_xor(mx, 1));
        mx = fmaxf(mx, __shfl_xor(mx, 2));
        mx = fmaxf(mx, __shfl_xor(mx, 4));
        mx = fmaxf(mx, __shfl_xor(mx, 8));
        float mnew = fmaxf(m[i], mx);
        float c = expf(m[i] - mnew);
        float rs = 0.0f;
        #pragma unroll
        for (int j = 0; j < 4; ++j) { s[i][j] = expf(s[i][j] - mnew); rs += s[i][j]; }
        rs += __shfl_xor(rs, 1);
        rs += __shfl_xor(rs, 2);
        rs += __shfl_xor(rs, 4);
        rs += __shfl_xor(rs, 8);
        l[i] = l[i] * c + rs;
        m[i] = mnew;
        #pragma unroll
        for (int j = 0; j < 4; ++j) acc[i][j] *= c;
      }
      __syncthreads();                                  // all QK reads of kps done
      #pragma unroll
      for (int i = 0; i < 4; ++i)
        *(float4*)&kps[ty4 + i][tx4] = make_float4(s[i][0], s[i][1], s[i][2], s[i][3]);
      __syncthreads();                                  // P visible
      #pragma unroll 4
      for (int kk = 0; kk < 16; ++kk) {
        float4 v0 = *(const float4*)&vs[(kk << 2) + 0][tx4];
        float4 v1 = *(const float4*)&vs[(kk << 2) + 1][tx4];
        float4 v2 = *(const float4*)&vs[(kk << 2) + 2][tx4];
        float4 v3 = *(const float4*)&vs[(kk << 2) + 3][tx4];
        #pragma unroll
        for (int i = 0; i < 4; ++i) {
          float4 p4 = *(const float4*)&kps[ty4 + i][kk << 2];
          acc[i][0] += p4.x * v0.x + p4.y * v1.x + p4.z * v2.x + p4.w * v3.x;
          acc[i][1] += p4.x * v0.y + p4.y * v1.y + p4.z * v2.y + p4.w * v3.y;
          acc[i][2] += p4.x * v0.z + p4.y * v1.z + p4.z * v2.z + p4.w * v3.z;
          acc[i][3] += p4.x * v0.w + p4.y * v1.w + p4.z * v2.w + p4.w * v3.w;
        }
      }
    }
    __syncthreads();                                    // PV done before buffers reused
    #pragma unroll
    for (int i = 0; i < 4; ++i) {
      float invl = 1.0f / l[i];
      size_t ob = ((size_t)(b * 1024 + q0 + ty4 + i)) * 768 + h * 64 + tx4;
      ushort4 vh, vm, vl;
      unsigned short a0, a1, a2;
      split3f(acc[i][0] * invl, a0, a1, a2); vh.x = a0; vm.x = a1; vl.x = a2;
      split3f(acc[i][1] * invl, a0, a1, a2); vh.y = a0; vm.y = a1; vl.y = a2;
      split3f(acc[i][2] * invl, a0, a1, a2); vh.z = a0; vm.z = a1; vl.z = a2;
      split3f(acc[i][3] * invl, a0, a1, a2); vh.w = a0; vm.w = a1; vl.w = a2;
      *(ushort4*)(ax3 + ob) = vh;
      *(ushort4*)(ax3 + pPS + ob) = vm;
      *(ushort4*)(ax3 + 2 * pPS + ob) = vl;
    }
  }
}

// ---------------------------------------------------------------- MoE routing (exact f32)
__global__ __launch_bounds__(256) void router_k(const float* __restrict__ xn,
                                                const float* __restrict__ rw,
                                                int* __restrict__ tk_idx, float* __restrict__ tk_w,
                                                int* __restrict__ cnt, float* __restrict__ psum) {
  __shared__ float bps[8];
  __shared__ int bcnt[8];
  int tid = threadIdx.x;
  if (tid < 8) { bps[tid] = 0.0f; bcnt[tid] = 0; }
  __syncthreads();
  int t = blockIdx.x * 4 + (tid >> 6);
  int lane = tid & 63;
  const float* xr = xn + (size_t)t * 768;
  float p[8] = {};
  for (int d = lane; d < 768; d += 64) {
    float xv = xr[d];
    const float* wr = rw + (size_t)d * 8;
    #pragma unroll
    for (int e = 0; e < 8; ++e) p[e] += xv * wr[e];
  }
  #pragma unroll
  for (int e = 0; e < 8; ++e) {
    float v = p[e];
    #pragma unroll
    for (int o = 32; o > 0; o >>= 1) v += __shfl_xor(v, o);
    p[e] = v;
  }
  if (lane == 0) {
    float mx = p[0];
    #pragma unroll
    for (int e = 1; e < 8; ++e) mx = fmaxf(mx, p[e]);
    float s = 0.0f;
    #pragma unroll
    for (int e = 0; e < 8; ++e) { p[e] = expf(p[e] - mx); s += p[e]; }
    float invs = 1.0f / s;
    #pragma unroll
    for (int e = 0; e < 8; ++e) p[e] *= invs;
    int i1 = 0; float v1 = p[0];
    #pragma unroll
    for (int e = 1; e < 8; ++e) if (p[e] > v1) { v1 = p[e]; i1 = e; }
    int i2 = (i1 == 0) ? 1 : 0; float v2 = p[i2];
    #pragma unroll
    for (int e = 0; e < 8; ++e) if (e != i1 && p[e] > v2) { v2 = p[e]; i2 = e; }
    float wsum = v1 + v2;
    tk_idx[t * 2] = i1; tk_idx[t * 2 + 1] = i2;
    tk_w[t * 2] = v1 / wsum; tk_w[t * 2 + 1] = v2 / wsum;
    atomicAdd(&bcnt[i1], 1); atomicAdd(&bcnt[i2], 1);
    #pragma unroll
    for (int e = 0; e < 8; ++e) atomicAdd(&bps[e], p[e]);
  }
  __syncthreads();
  if (tid < 8) {
    atomicAdd(&cnt[tid], bcnt[tid]);
    atomicAdd(&psum[tid], bps[tid]);
  }
}

__global__ void moe_offsets_k(const int* __restrict__ cnt, int* __restrict__ offs,
                              const float* __restrict__ psum, float* __restrict__ aux) {
  if (threadIdx.x == 0) {
    int o = 0; float a = 0.0f;
    for (int e = 0; e < 8; ++e) {
      offs[e] = o;
      o += (cnt[e] + 127) & ~127;
      a += ((float)cnt[e] / 4096.0f) * (psum[e] / 4096.0f);
    }
    offs[8] = o;
    aux[0] += a * 8.0f;
  }
}

__global__ void moe_fill_k(const int* __restrict__ tk_idx, const int* __restrict__ offs,
                           int* __restrict__ fill, int* __restrict__ slot_token,
                           int* __restrict__ tk_slot) {
  int i = blockIdx.x * 256 + threadIdx.x;              // grid 32
  int e = tk_idx[i];
  int pos = atomicAdd(&fill[e], 1);
  int slot = offs[e] + pos;
  slot_token[slot] = i >> 1;
  tk_slot[i] = slot;
}

template <int BF>  // 0: os f32; 1: os bf16
__global__ void moe_combine_k(float* __restrict__ x, const void* __restrict__ osv,
                              const int* __restrict__ tk_slot, const float* __restrict__ tk_w) {
  int t = blockIdx.x;                                  // grid 4096 x 192
  int d = threadIdx.x << 2;
  int s0 = tk_slot[t * 2], s1 = tk_slot[t * 2 + 1];
  float w0 = tk_w[t * 2], w1 = tk_w[t * 2 + 1];
  float a0, a1, a2, a3, b0, b1, b2, b3;
  if (BF == 0) {
    const float* os = (const float*)osv;
    float4 a = *(const float4*)(os + (size_t)s0 * 768 + d);
    float4 b = *(const float4*)(os + (size_t)s1 * 768 + d);
    a0 = a.x; a1 = a.y; a2 = a.z; a3 = a.w;
    b0 = b.x; b1 = b.y; b2 = b.z; b3 = b.w;
  } else {
    const unsigned short* os = (const unsigned short*)osv;
    ushort4 a = *(const ushort4*)(os + (size_t)s0 * 768 + d);
    ushort4 b = *(const ushort4*)(os + (size_t)s1 * 768 + d);
    a0 = bf2f(a.x); a1 = bf2f(a.y); a2 = bf2f(a.z); a3 = bf2f(a.w);
    b0 = bf2f(b.x); b1 = bf2f(b.y); b2 = bf2f(b.z); b3 = bf2f(b.w);
  }
  float4 c = *(const float4*)(x + (size_t)t * 768 + d);
  c.x += w0 * a0 + w1 * b0;
  c.y += w0 * a1 + w1 * b1;
  c.z += w0 * a2 + w1 * b2;
  c.w += w0 * a3 + w1 * b3;
  *(float4*)(x + (size_t)t * 768 + d) = c;
}

__global__ void write_aux_k(const float* __restrict__ aux, float* __restrict__ out) {
  out[0] = aux[0];
}

// ---------------------------------------------------------------- host launcher

extern "C" void kernel_launch(void* const* d_in, const int* in_sizes, int n_in,
                              void* d_out, int out_size, void* d_ws, size_t ws_size,
                              hipStream_t stream) {
  const int* input_ids      = (const int*)d_in[0];
  const int* time_slots     = (const int*)d_in[1];
  const int* day_of_week    = (const int*)d_in[2];
  const int* month          = (const int*)d_in[3];
  const int* is_holiday     = (const int*)d_in[4];
  const int* location_ids   = (const int*)d_in[5];
  const int* road_types     = (const int*)d_in[6];
  const int* weather_states = (const int*)d_in[7];
  const float* word_emb     = (const float*)d_in[8];
  const float* time_emb     = (const float*)d_in[9];
  const float* dow_emb      = (const float*)d_in[10];
  const float* month_emb    = (const float*)d_in[11];
  const float* hol_emb      = (const float*)d_in[12];
  const float* loc_emb      = (const float*)d_in[13];
  const float* road_emb     = (const float*)d_in[14];
  const float* weather_emb  = (const float*)d_in[15];
  const float* proj_w       = (const float*)d_in[16];
  const float* proj_b       = (const float*)d_in[17];
  const float* emb_norm_w   = (const float*)d_in[18];
  const float* norm1_w      = (const float*)d_in[19];
  const float* Wq           = (const float*)d_in[20];
  const float* Wk           = (const float*)d_in[21];
  const float* Wv           = (const float*)d_in[22];
  const float* Wo           = (const float*)d_in[23];
  const float* norm2_w      = (const float*)d_in[24];
  const float* router_w     = (const float*)d_in[25];
  const float* Wg           = (const float*)d_in[26];
  const float* Wu           = (const float*)d_in[27];
  const float* Wd           = (const float*)d_in[28];
  const float* final_norm_w = (const float*)d_in[29];
  float* out = (float*)d_out;

  const size_t TD = (size_t)TTOK * 768;
  const size_t REG = (size_t)MAXSLOT * FDIM * 4;       // 113.25 MB shared regions
  char* base = (char*)d_ws;
  auto carve = [&](size_t bytes) { char* p = base; base += (bytes + 255) & ~(size_t)255; return p; };
  float* x    = (float*)carve(TD * 4);
  float* xn   = (float*)carve(TD * 4);
  float* cosb = (float*)carve(32768 * 4);
  float* sinb = (float*)carve(32768 * 4);
  float* ctx  = (float*)carve(4 * 1536 * 4);
  float* biasB= (float*)carve(4 * 768 * 4);
  float* tkw  = (float*)carve(8192 * 4);
  float* psum = (float*)carve(64);
  float* auxa = (float*)carve(64);
  int* cnt    = (int*)carve(64);
  int* fill   = (int*)carve(64);
  int* offs   = (int*)carve(64);
  int* tk_idx = (int*)carve(8192 * 4);
  int* tk_slot= (int*)carve(8192 * 4);
  int* slot_token = (int*)carve(MAXSLOT * 4);
  unsigned short* zp = (unsigned short*)carve(4096);
  unsigned short* xnb3 = (unsigned short*)carve(3 * TD * 2);
  char* QAH = carve(REG);                               // qkv+ax3 (attn) / h (moe)
  char* GT  = carve(REG);                               // gtmp / ob
  char* Wr  = carve(REG);                               // weight planes (sequential)
  float* qkv = (float*)QAH;
  unsigned short* ax3 = (unsigned short*)(QAH + (size_t)TTOK * 2304 * 4);
  float* hbf = (float*)QAH;
  unsigned short* hb16 = (unsigned short*)QAH;
  float* gtmp = (float*)GT;
  float* obf = (float*)GT;
  unsigned short* ob16 = (unsigned short*)GT;
  unsigned short* wpl = (unsigned short*)Wr;

  const size_t PS_D = (size_t)768 * 768;                // dense 768x768 plane stride
  const size_t PS_QKV = (size_t)2304 * 768;
  const size_t PS_E = (size_t)8 * FDIM * 768;           // expert-tensor plane stride

  hipMemsetAsync(auxa, 0, 64, stream);
  hipMemsetAsync(zp, 0, 4096, stream);
  rope_cache_k<<<dim3(1024), dim3(32), 0, stream>>>(cosb, sinb);
  build_ctx_k<<<dim3(4, 6), dim3(256), 0, stream>>>(time_slots, day_of_week, month, is_holiday,
      location_ids, road_types, weather_states, time_emb, dow_emb, month_emb, hol_emb,
      loc_emb, road_emb, weather_emb, ctx);
  build_bias_k<<<dim3(4, 3), dim3(256), 0, stream>>>(ctx, proj_w, proj_b, biasB);
  tconv3_k<<<dim3(24, 24, 1), dim3(32, 8), 0, stream>>>(proj_w, wpl, PS_D, 768, 768, 0, 0);
  gconv3_k<<<dim3(TTOK), dim3(192), 0, stream>>>(word_emb, input_ids, xnb3, TD);
  gemm3<3><<<dim3(6, 32), dim3(256), 0, stream>>>(xnb3, TD, wpl, PS_D, xn, 768, 768, biasB);
  rmsnorm_k<0><<<dim3(TTOK), dim3(256), 0, stream>>>(xn, emb_norm_w, x, nullptr, 0);

  for (int l = 0; l < 2; ++l) {
    const float* rw = router_w + (size_t)l * 768 * 8;
    // ---- attention (split-3 GEMMs, f32 flash core) ----
    tconv3_k<<<dim3(24, 24, 1), dim3(32, 8), 0, stream>>>(Wq + (size_t)l * PS_D, wpl, PS_QKV, 768, 768, 0, 0);
    tconv3_k<<<dim3(24, 24, 1), dim3(32, 8), 0, stream>>>(Wk + (size_t)l * PS_D, wpl + PS_D, PS_QKV, 768, 768, 0, 0);
    tconv3_k<<<dim3(24, 24, 1), dim3(32, 8), 0, stream>>>(Wv + (size_t)l * PS_D, wpl + 2 * PS_D, PS_QKV, 768, 768, 0, 0);
    rmsnorm_k<1><<<dim3(TTOK), dim3(256), 0, stream>>>(x, norm1_w + l * 768, nullptr, xnb3, TD);
    gemm3<0><<<dim3(18, 32), dim3(256), 0, stream>>>(xnb3, TD, wpl, PS_QKV, qkv, 2304, 768, nullptr);
    rope_apply_k<<<dim3(6144), dim3(256), 0, stream>>>(qkv, cosb, sinb);
    attn_k<<<dim3(8, 12, 4), dim3(256), 0, stream>>>(qkv, ax3, TD);
    tconv3_k<<<dim3(24, 24, 1), dim3(32, 8), 0, stream>>>(Wo + (size_t)l * PS_D, wpl, PS_D, 768, 768, 0, 0);
    gemm3<2><<<dim3(6, 32), dim3(256), 0, stream>>>(ax3, TD, wpl, PS_D, x, 768, 768, nullptr);

    // ---- MoE ----
    if (l == 0)
      rmsnorm_k<2><<<dim3(TTOK), dim3(256), 0, stream>>>(x, norm2_w, xn, xnb3, TD);
    else
      rmsnorm_k<3><<<dim3(TTOK), dim3(256), 0, stream>>>(x, norm2_w + 768, xn, xnb3, TD);
    hipMemsetAsync(cnt, 0, 64, stream);
    hipMemsetAsync(fill, 0, 64, stream);
    hipMemsetAsync(psum, 0, 64, stream);
    hipMemsetAsync(slot_token, 0xFF, MAXSLOT * 4, stream);
    router_k<<<dim3(1024), dim3(256), 0, stream>>>(xn, rw, tk_idx, tkw, cnt, psum);
    moe_offsets_k<<<dim3(1), dim3(64), 0, stream>>>(cnt, offs, psum, auxa);
    moe_fill_k<<<dim3(32), dim3(256), 0, stream>>>(tk_idx, offs, fill, slot_token, tk_slot);
    if (l == 0) {
      // split-3 experts (feed layer-1 router: must be f32-accurate)
      tconv3_k<<<dim3(96, 24, 8), dim3(32, 8), 0, stream>>>(Wg, wpl, PS_E,
          768, FDIM, (size_t)768 * FDIM, (size_t)FDIM * 768);
      gemm3_gu<0><<<dim3(24, MAXSLOT / 128), dim3(256), 0, stream>>>(xnb3, TD, wpl, PS_E,
          gtmp, nullptr, slot_token, offs, zp);
      tconv3_k<<<dim3(96, 24, 8), dim3(32, 8), 0, stream>>>(Wu, wpl, PS_E,
          768, FDIM, (size_t)768 * FDIM, (size_t)FDIM * 768);
      gemm3_gu<1><<<dim3(24, MAXSLOT / 128), dim3(256), 0, stream>>>(xnb3, TD, wpl, PS_E,
          hbf, gtmp, slot_token, offs, zp);
      tconv3_k<<<dim3(24, 96, 8), dim3(32, 8), 0, stream>>>(Wd, wpl, PS_E,
          FDIM, 768, (size_t)FDIM * 768, (size_t)768 * FDIM);
      gemm3_dn<<<dim3(6, MAXSLOT / 128), dim3(256), 0, stream>>>(hbf, wpl, PS_E, obf, offs);
      moe_combine_k<0><<<dim3(TTOK), dim3(192), 0, stream>>>(x, obf, tk_slot, tkw);
    } else {
      // plain bf16 experts (feed only final output)
      const float* wg1 = Wg + (size_t)8 * 768 * FDIM;
      const float* wu1 = Wu + (size_t)8 * 768 * FDIM;
      const float* wd1 = Wd + (size_t)8 * FDIM * 768;
      tconv_k<<<dim3(96, 24, 8), dim3(32, 8), 0, stream>>>(wg1, wpl,
          768, FDIM, (size_t)768 * FDIM, (size_t)FDIM * 768);
      tconv_k<<<dim3(96, 24, 8), dim3(32, 8), 0, stream>>>(wu1, wpl + PS_E,
          768, FDIM, (size_t)768 * FDIM, (size_t)FDIM * 768);
      gemm_gu<<<dim3(24, MAXSLOT / 128), dim3(256), 0, stream>>>(xnb3, wpl, wpl + PS_E,
          hb16, slot_token, offs, zp);
      tconv_k<<<dim3(24, 96, 8), dim3(32, 8), 0, stream>>>(wd1, wpl,
          FDIM, 768, (size_t)FDIM * 768, (size_t)768 * FDIM);
      gemm_d<<<dim3(6, MAXSLOT / 128), dim3(256), 0, stream>>>(hb16, wpl, ob16, offs);
      moe_combine_k<1><<<dim3(TTOK), dim3(192), 0, stream>>>(x, ob16, tk_slot, tkw);
    }
  }

  rmsnorm_k<0><<<dim3(TTOK), dim3(256), 0, stream>>>(x, final_norm_w, out, nullptr, 0);
  write_aux_k<<<dim3(1), dim3(1), 0, stream>>>(auxa, out + TD);
}

// Round 5
// 2323.236 us; speedup vs baseline: 2.0704x; 1.1198x over previous
//
#include <hip/hip_runtime.h>
#include <math.h>

// Traffic foundation model, round 4.
// Change vs round 3 (single variable): layer-0 MoE expert GEMMs use split-2
// (hi+mid bf16 planes, 3 MFMA terms, ~17 mantissa bits) instead of split-3
// (6 terms). Expert outputs reach the layer-1 router only through the
// residual stream (damped), so 17-bit accuracy keeps routing exact w.h.p.
// proj/QKV/Wo stay split-3; router exact f32; layer-1 experts plain bf16.
// B=4 S=1024 D=768 H=12 HD=64 L=2 E=8 F=3072.

#define TTOK 4096
#define FDIM 3072
#define MAXSLOT 9216   // 8192 + 8*127 pad, 128-aligned offsets

typedef __attribute__((ext_vector_type(8))) short short8;
typedef __attribute__((ext_vector_type(4))) float f32x4;

__device__ __forceinline__ float bf2f(unsigned short u) {
  return __uint_as_float(((unsigned int)u) << 16);
}
__device__ __forceinline__ unsigned short f2bf(float f) {
  unsigned int u = __float_as_uint(f);
  u += 0x7fffu + ((u >> 16) & 1u);
  return (unsigned short)(u >> 16);
}
// exact 3-way bf16 split: a ~= h + m + l to ~24 mantissa bits
__device__ __forceinline__ void split3f(float a, unsigned short& h, unsigned short& m,
                                        unsigned short& l) {
  h = f2bf(a);
  float r = a - bf2f(h);
  m = f2bf(r);
  r -= bf2f(m);
  l = f2bf(r);
}
// 2-way bf16 split: a ~= h + m to ~17 mantissa bits
__device__ __forceinline__ void split2f(float a, unsigned short& h, unsigned short& m) {
  h = f2bf(a);
  m = f2bf(a - bf2f(h));
}
__device__ __forceinline__ void gload16(const void* g, void* l) {
  __builtin_amdgcn_global_load_lds((const __attribute__((address_space(1))) unsigned int*)g,
                                   (__attribute__((address_space(3))) unsigned int*)l, 16, 0, 0);
}

#define MFMA_TERM(ACC, PA, PB)                                                              \
  _Pragma("unroll") for (int i_ = 0; i_ < 4; ++i_)                                          \
      _Pragma("unroll") for (int j_ = 0; j_ < 4; ++j_)                                      \
          ACC[i_][j_] = __builtin_amdgcn_mfma_f32_16x16x32_bf16(af[PA][i_], bf[PB][j_],     \
                                                                ACC[i_][j_], 0, 0, 0);
// 6-term split-3 (smallest terms first)
#define MFMA_SPLIT3(ACC)  \
  MFMA_TERM(ACC, 0, 2) MFMA_TERM(ACC, 2, 0) MFMA_TERM(ACC, 1, 1) \
  MFMA_TERM(ACC, 0, 1) MFMA_TERM(ACC, 1, 0) MFMA_TERM(ACC, 0, 0)
// 3-term split-2
#define MFMA_SPLIT2(ACC)  \
  MFMA_TERM(ACC, 0, 1) MFMA_TERM(ACC, 1, 0) MFMA_TERM(ACC, 0, 0)

// ---------------------------------------------------------------- small kernels

__global__ void rope_cache_k(float* __restrict__ cosb, float* __restrict__ sinb) {
  int s = blockIdx.x, i = threadIdx.x;                 // grid 1024 x 32
  float inv = powf(10000.0f, -(float)i / 32.0f);
  float a = (float)s * inv;
  cosb[s * 32 + i] = cosf(a);
  sinb[s * 32 + i] = sinf(a);
}

__global__ void build_ctx_k(const int* ts, const int* dow, const int* mon, const int* hol,
                            const int* loc, const int* road, const int* wth,
                            const float* te, const float* de, const float* me, const float* he,
                            const float* le, const float* re, const float* we,
                            float* __restrict__ ctx) {
  int b = blockIdx.x;
  int j = blockIdx.y * 256 + threadIdx.x;              // grid (4,6) x 256
  float v;
  if (j < 192)       v = te[ts[b] * 192 + j];
  else if (j < 384)  v = de[dow[b] * 192 + (j - 192)];
  else if (j < 576)  v = me[mon[b] * 192 + (j - 384)];
  else if (j < 768)  v = he[hol[b] * 192 + (j - 576)];
  else if (j < 1152) v = le[loc[b] * 384 + (j - 768)];
  else if (j < 1344) v = re[road[b] * 192 + (j - 1152)];
  else               v = we[wth[b] * 192 + (j - 1344)];
  ctx[b * 1536 + j] = v;
}

// biasB[b][d] = proj_b[d] + sum_j ctx[b][j] * proj_w[768+j][d]  (exact f32)
__global__ void build_bias_k(const float* __restrict__ ctx, const float* __restrict__ pw,
                             const float* __restrict__ pb, float* __restrict__ biasB) {
  int b = blockIdx.x;
  int d = blockIdx.y * 256 + threadIdx.x;              // grid (4,3) x 256
  float s = pb[d];
  const float* cb = ctx + b * 1536;
  for (int j = 0; j < 1536; ++j) s += cb[j] * pw[(size_t)(768 + j) * 768 + d];
  biasB[b * 768 + d] = s;
}

// transpose + split-3: dst[p][n][k] = split(src[k][n]). grid (N/32, K/32, batch), block (32,8)
__global__ void tconv3_k(const float* __restrict__ src, unsigned short* __restrict__ dst,
                         size_t dPS, int K, int N, size_t sstride, size_t dstride) {
  __shared__ float tile[32][33];
  src += (size_t)blockIdx.z * sstride;
  size_t dbase = (size_t)blockIdx.z * dstride;
  int n0 = blockIdx.x * 32, k0 = blockIdx.y * 32;
  int tx = threadIdx.x, ty = threadIdx.y;
  #pragma unroll
  for (int r = 0; r < 4; ++r)
    tile[ty + r * 8][tx] = src[(size_t)(k0 + ty + r * 8) * N + n0 + tx];
  __syncthreads();
  #pragma unroll
  for (int r = 0; r < 4; ++r) {
    int n = n0 + ty + r * 8;
    unsigned short h, m, lo;
    split3f(tile[tx][ty + r * 8], h, m, lo);
    size_t di = dbase + (size_t)n * K + k0 + tx;
    dst[di] = h; dst[di + dPS] = m; dst[di + 2 * dPS] = lo;
  }
}

// transpose + split-2: dst[p][n][k], 2 planes
__global__ void tconv2_k(const float* __restrict__ src, unsigned short* __restrict__ dst,
                         size_t dPS, int K, int N, size_t sstride, size_t dstride) {
  __shared__ float tile[32][33];
  src += (size_t)blockIdx.z * sstride;
  size_t dbase = (size_t)blockIdx.z * dstride;
  int n0 = blockIdx.x * 32, k0 = blockIdx.y * 32;
  int tx = threadIdx.x, ty = threadIdx.y;
  #pragma unroll
  for (int r = 0; r < 4; ++r)
    tile[ty + r * 8][tx] = src[(size_t)(k0 + ty + r * 8) * N + n0 + tx];
  __syncthreads();
  #pragma unroll
  for (int r = 0; r < 4; ++r) {
    int n = n0 + ty + r * 8;
    unsigned short h, m;
    split2f(tile[tx][ty + r * 8], h, m);
    size_t di = dbase + (size_t)n * K + k0 + tx;
    dst[di] = h; dst[di + dPS] = m;
  }
}

// transpose-convert single plane (plain bf16, for layer-1 experts)
__global__ void tconv_k(const float* __restrict__ src, unsigned short* __restrict__ dst,
                        int K, int N, size_t sstride, size_t dstride) {
  __shared__ unsigned short tile[32][33];
  src += (size_t)blockIdx.z * sstride;
  unsigned short* d = dst + (size_t)blockIdx.z * dstride;
  int n0 = blockIdx.x * 32, k0 = blockIdx.y * 32;
  int tx = threadIdx.x, ty = threadIdx.y;
  #pragma unroll
  for (int r = 0; r < 4; ++r)
    tile[ty + r * 8][tx] = f2bf(src[(size_t)(k0 + ty + r * 8) * N + n0 + tx]);
  __syncthreads();
  #pragma unroll
  for (int r = 0; r < 4; ++r) {
    int n = n0 + ty + r * 8;
    d[(size_t)n * K + k0 + tx] = tile[tx][ty + r * 8];
  }
}

// gather word_emb rows -> 3 planes. grid 4096 x 192
__global__ void gconv3_k(const float* __restrict__ we, const int* __restrict__ ids,
                         unsigned short* __restrict__ x3, size_t pPS) {
  int t = blockIdx.x;
  int d = threadIdx.x << 2;
  float4 v = *(const float4*)(we + (size_t)ids[t] * 768 + d);
  ushort4 vh, vm, vl;
  split3f(v.x, vh.x, vm.x, vl.x);
  split3f(v.y, vh.y, vm.y, vl.y);
  split3f(v.z, vh.z, vm.z, vl.z);
  split3f(v.w, vh.w, vm.w, vl.w);
  size_t o = (size_t)t * 768 + d;
  *(ushort4*)(x3 + o) = vh;
  *(ushort4*)(x3 + pPS + o) = vm;
  *(ushort4*)(x3 + 2 * pPS + o) = vl;
}

// OUT: 0 f32 only; 1 3-plane only; 2 f32 + 3-plane; 3 f32 + single-bf16(plane0)
template <int OUT>
__global__ __launch_bounds__(256) void rmsnorm_k(const float* __restrict__ xin,
                                                 const float* __restrict__ w,
                                                 float* __restrict__ yf,
                                                 unsigned short* __restrict__ yb, size_t pPS) {
  int t = blockIdx.x;
  int tid = threadIdx.x;
  const float* xr = xin + (size_t)t * 768;
  float v0 = xr[tid], v1 = xr[tid + 256], v2 = xr[tid + 512];
  float ss = v0 * v0 + v1 * v1 + v2 * v2;
  #pragma unroll
  for (int o = 32; o > 0; o >>= 1) ss += __shfl_xor(ss, o);
  __shared__ float wss[4];
  if ((tid & 63) == 0) wss[tid >> 6] = ss;
  __syncthreads();
  float tot = wss[0] + wss[1] + wss[2] + wss[3];
  float inv = 1.0f / sqrtf(tot / 768.0f + 1e-6f);
  float o0 = v0 * inv * w[tid], o1 = v1 * inv * w[tid + 256], o2 = v2 * inv * w[tid + 512];
  if (OUT != 1) {
    float* yr = yf + (size_t)t * 768;
    yr[tid] = o0; yr[tid + 256] = o1; yr[tid + 512] = o2;
  }
  if (OUT == 1 || OUT == 2) {
    unsigned short* yr = yb + (size_t)t * 768;
    unsigned short h, m, l;
    split3f(o0, h, m, l); yr[tid] = h;       yr[tid + pPS] = m;       yr[tid + 2 * pPS] = l;
    split3f(o1, h, m, l); yr[tid + 256] = h; yr[tid + 256 + pPS] = m; yr[tid + 256 + 2 * pPS] = l;
    split3f(o2, h, m, l); yr[tid + 512] = h; yr[tid + 512 + pPS] = m; yr[tid + 512 + 2 * pPS] = l;
  }
  if (OUT == 3) {
    unsigned short* yr = yb + (size_t)t * 768;
    yr[tid] = f2bf(o0); yr[tid + 256] = f2bf(o1); yr[tid + 512] = f2bf(o2);
  }
}

// rope in-place on f32 qkv [T][2304] (q at 0, k at 768)
__global__ __launch_bounds__(256) void rope_apply_k(float* __restrict__ qkv,
                                                    const float* __restrict__ cosb,
                                                    const float* __restrict__ sinb) {
  int idx = blockIdx.x * 256 + threadIdx.x;            // grid 6144
  int j = idx & 31;
  int hh = (idx >> 5) % 12;
  int t = idx / 384;
  int s = t & 1023;
  float c = cosb[s * 32 + j], sn = sinb[s * 32 + j];
  size_t base = (size_t)t * 2304 + hh * 64 + j;
  float q1 = qkv[base], q2 = qkv[base + 32];
  qkv[base]      = q1 * c - q2 * sn;
  qkv[base + 32] = q2 * c + q1 * sn;
  size_t kb = base + 768;
  float k1 = qkv[kb], k2 = qkv[kb + 32];
  qkv[kb]      = k1 * c - k2 * sn;
  qkv[kb + 32] = k2 * c + k1 * sn;
}

// ---------------------------------------------------------------- split-3 dense GEMM
// C[M,N] = A@BT^T, A/BT 3-plane bf16 (plane strides aPS/bPS). 128x128 tile, 4 waves.
// EPI: 0 f32 store; 2 f32 +=; 3 f32 store + per-batch bias
template <int EPI>
__global__ __launch_bounds__(256) void gemm3(const unsigned short* __restrict__ A, size_t aPS,
                                             const unsigned short* __restrict__ BT, size_t bPS,
                                             float* __restrict__ Cf, int N, int K,
                                             const float* __restrict__ rowBias) {
  __shared__ __align__(16) unsigned short As[3][4096];
  __shared__ __align__(16) unsigned short Bs[3][4096];
  int tid = threadIdx.x, w = tid >> 6, l = tid & 63, lr = l & 15, lg = l >> 4;
  int m0 = blockIdx.y * 128, n0 = blockIdx.x * 128;
  size_t aoff = (size_t)(m0 + 32 * w + lr) * K + lg * 8;
  size_t boff = (size_t)(n0 + 32 * w + lr) * K + lg * 8;
  size_t aoff1 = aoff + (size_t)16 * K, boff1 = boff + (size_t)16 * K;
  f32x4 acc[4][4];
  #pragma unroll
  for (int i = 0; i < 4; ++i)
    #pragma unroll
    for (int j = 0; j < 4; ++j) acc[i][j] = (f32x4){0.f, 0.f, 0.f, 0.f};
  int wr = w >> 1, wc = w & 1;
  for (int k0 = 0; k0 < K; k0 += 32) {
    #pragma unroll
    for (int p = 0; p < 3; ++p) {
      gload16(A + p * aPS + aoff + k0,  &As[p][1024 * w]);
      gload16(A + p * aPS + aoff1 + k0, &As[p][1024 * w + 512]);
      gload16(BT + p * bPS + boff + k0,  &Bs[p][1024 * w]);
      gload16(BT + p * bPS + boff1 + k0, &Bs[p][1024 * w + 512]);
    }
    __syncthreads();
    short8 af[3][4], bf[3][4];
    #pragma unroll
    for (int p = 0; p < 3; ++p)
      #pragma unroll
      for (int i = 0; i < 4; ++i) {
        af[p][i] = *(const short8*)(&As[p][(wr * 4 + i) * 512 + l * 8]);
        bf[p][i] = *(const short8*)(&Bs[p][(wc * 4 + i) * 512 + l * 8]);
      }
    MFMA_SPLIT3(acc)
    __syncthreads();
  }
  int colb = n0 + wc * 64 + lr;
  int rowb = m0 + wr * 64 + lg * 4;
  #pragma unroll
  for (int i = 0; i < 4; ++i)
    #pragma unroll
    for (int j = 0; j < 4; ++j) {
      int col = colb + j * 16;
      #pragma unroll
      for (int r = 0; r < 4; ++r) {
        int row = rowb + i * 16 + r;
        size_t idx = (size_t)row * N + col;
        float v = acc[i][j][r];
        if (EPI == 0)      Cf[idx] = v;
        else if (EPI == 2) Cf[idx] += v;
        else               Cf[idx] = v + rowBias[(row >> 10) * 768 + col];
      }
    }
}

// split-2 MoE gate/up GEMM, gathered A rows (planes 0,1 of xnb3). FUSE 0: store f32
// (g pass); FUSE 1: read g, out = silu(g)*u (u pass). N=3072, K=768.
template <int FUSE>
__global__ __launch_bounds__(256) void gemm2_gu(const unsigned short* __restrict__ X3, size_t xPS,
    const unsigned short* __restrict__ W2, size_t wPS, float* __restrict__ outb,
    const float* __restrict__ gin, const int* __restrict__ slot_token,
    const int* __restrict__ offs, const unsigned short* __restrict__ zp) {
  __shared__ __align__(16) unsigned short As[2][4096];
  __shared__ __align__(16) unsigned short Bs[2][4096];
  int sb = blockIdx.y * 128;
  if (sb >= offs[8]) return;
  int e = 0;
  #pragma unroll
  for (int i = 1; i < 8; ++i) if (sb >= offs[i]) e = i;
  int tid = threadIdx.x, w = tid >> 6, l = tid & 63, lr = l & 15, lg = l >> 4;
  int n0 = blockIdx.x * 128;
  const unsigned short* WE = W2 + (size_t)e * FDIM * 768;
  int t0 = slot_token[sb + 32 * w + lr];
  int t1 = slot_token[sb + 32 * w + 16 + lr];
  const unsigned short* a0[2];
  const unsigned short* a1[2];
  #pragma unroll
  for (int p = 0; p < 2; ++p) {
    a0[p] = (t0 < 0 ? zp : X3 + p * xPS + (size_t)t0 * 768) + lg * 8;
    a1[p] = (t1 < 0 ? zp : X3 + p * xPS + (size_t)t1 * 768) + lg * 8;
  }
  size_t boff = (size_t)(n0 + 32 * w + lr) * 768 + lg * 8;
  size_t boff1 = boff + (size_t)16 * 768;
  f32x4 acc[4][4];
  #pragma unroll
  for (int i = 0; i < 4; ++i)
    #pragma unroll
    for (int j = 0; j < 4; ++j) acc[i][j] = (f32x4){0.f, 0.f, 0.f, 0.f};
  int wr = w >> 1, wc = w & 1;
  for (int k0 = 0; k0 < 768; k0 += 32) {
    #pragma unroll
    for (int p = 0; p < 2; ++p) {
      gload16(a0[p] + k0, &As[p][1024 * w]);
      gload16(a1[p] + k0, &As[p][1024 * w + 512]);
      gload16(WE + p * wPS + boff + k0,  &Bs[p][1024 * w]);
      gload16(WE + p * wPS + boff1 + k0, &Bs[p][1024 * w + 512]);
    }
    __syncthreads();
    short8 af[2][4], bf[2][4];
    #pragma unroll
    for (int p = 0; p < 2; ++p)
      #pragma unroll
      for (int i = 0; i < 4; ++i) {
        af[p][i] = *(const short8*)(&As[p][(wr * 4 + i) * 512 + l * 8]);
        bf[p][i] = *(const short8*)(&Bs[p][(wc * 4 + i) * 512 + l * 8]);
      }
    MFMA_SPLIT2(acc)
    __syncthreads();
  }
  int colb = n0 + wc * 64 + lr;
  int rowb = sb + wr * 64 + lg * 4;
  #pragma unroll
  for (int i = 0; i < 4; ++i)
    #pragma unroll
    for (int j = 0; j < 4; ++j) {
      int col = colb + j * 16;
      #pragma unroll
      for (int r = 0; r < 4; ++r) {
        size_t idx = (size_t)(rowb + i * 16 + r) * FDIM + col;
        float v = acc[i][j][r];
        if (FUSE == 0) outb[idx] = v;
        else {
          float g = gin[idx];
          outb[idx] = g / (1.0f + expf(-g)) * v;       // silu(g)*u
        }
      }
    }
}

// split-2 MoE down GEMM: A = h (f32, split-2 in-kernel), B = wd 2 planes. N=768, K=3072.
__global__ __launch_bounds__(256) void gemm2_dn(const float* __restrict__ hbf,
    const unsigned short* __restrict__ W2, size_t wPS, float* __restrict__ ob,
    const int* __restrict__ offs) {
  __shared__ __align__(16) unsigned short As[2][4096];
  __shared__ __align__(16) unsigned short Bs[2][4096];
  int sb = blockIdx.y * 128;
  if (sb >= offs[8]) return;
  int e = 0;
  #pragma unroll
  for (int i = 1; i < 8; ++i) if (sb >= offs[i]) e = i;
  int tid = threadIdx.x, w = tid >> 6, l = tid & 63, lr = l & 15, lg = l >> 4;
  int n0 = blockIdx.x * 128;
  const unsigned short* WE = W2 + (size_t)e * 768 * FDIM;
  size_t boff = (size_t)(n0 + 32 * w + lr) * FDIM + lg * 8;
  size_t boff1 = boff + (size_t)16 * FDIM;
  const float* ha0 = hbf + (size_t)(sb + 32 * w + lr) * FDIM + lg * 8;
  const float* ha1 = ha0 + (size_t)16 * FDIM;
  f32x4 acc[4][4];
  #pragma unroll
  for (int i = 0; i < 4; ++i)
    #pragma unroll
    for (int j = 0; j < 4; ++j) acc[i][j] = (f32x4){0.f, 0.f, 0.f, 0.f};
  int wr = w >> 1, wc = w & 1;
  for (int k0 = 0; k0 < FDIM; k0 += 32) {
    #pragma unroll
    for (int p = 0; p < 2; ++p) {
      gload16(WE + p * wPS + boff + k0,  &Bs[p][1024 * w]);
      gload16(WE + p * wPS + boff1 + k0, &Bs[p][1024 * w + 512]);
    }
    {
      float4 v0 = *(const float4*)(ha0 + k0);
      float4 v1 = *(const float4*)(ha0 + k0 + 4);
      float va[8] = {v0.x, v0.y, v0.z, v0.w, v1.x, v1.y, v1.z, v1.w};
      short8 sh, sm;
      #pragma unroll
      for (int q = 0; q < 8; ++q) {
        unsigned short a, b;
        split2f(va[q], a, b);
        sh[q] = (short)a; sm[q] = (short)b;
      }
      *(short8*)(&As[0][1024 * w + l * 8]) = sh;
      *(short8*)(&As[1][1024 * w + l * 8]) = sm;
      v0 = *(const float4*)(ha1 + k0);
      v1 = *(const float4*)(ha1 + k0 + 4);
      float vb[8] = {v0.x, v0.y, v0.z, v0.w, v1.x, v1.y, v1.z, v1.w};
      #pragma unroll
      for (int q = 0; q < 8; ++q) {
        unsigned short a, b;
        split2f(vb[q], a, b);
        sh[q] = (short)a; sm[q] = (short)b;
      }
      *(short8*)(&As[0][1024 * w + 512 + l * 8]) = sh;
      *(short8*)(&As[1][1024 * w + 512 + l * 8]) = sm;
    }
    __syncthreads();
    short8 af[2][4], bf[2][4];
    #pragma unroll
    for (int p = 0; p < 2; ++p)
      #pragma unroll
      for (int i = 0; i < 4; ++i) {
        af[p][i] = *(const short8*)(&As[p][(wr * 4 + i) * 512 + l * 8]);
        bf[p][i] = *(const short8*)(&Bs[p][(wc * 4 + i) * 512 + l * 8]);
      }
    MFMA_SPLIT2(acc)
    __syncthreads();
  }
  int colb = n0 + wc * 64 + lr;
  int rowb = sb + wr * 64 + lg * 4;
  #pragma unroll
  for (int i = 0; i < 4; ++i)
    #pragma unroll
    for (int j = 0; j < 4; ++j) {
      int col = colb + j * 16;
      #pragma unroll
      for (int r = 0; r < 4; ++r)
        ob[(size_t)(rowb + i * 16 + r) * 768 + col] = acc[i][j][r];
    }
}

// ---------------------------------------------------------------- plain bf16 GEMMs (layer-1 MoE)

__global__ __launch_bounds__(256) void gemm_gu(const unsigned short* __restrict__ xnb,
    const unsigned short* __restrict__ wgT, const unsigned short* __restrict__ wuT,
    unsigned short* __restrict__ hb, const int* __restrict__ slot_token,
    const int* __restrict__ offs, const unsigned short* __restrict__ zp) {
  __shared__ __align__(16) unsigned short As[4096], Bg[4096], Bu[4096];
  int sb = blockIdx.y * 128;
  if (sb >= offs[8]) return;
  int e = 0;
  #pragma unroll
  for (int i = 1; i < 8; ++i) if (sb >= offs[i]) e = i;
  int tid = threadIdx.x, w = tid >> 6, l = tid & 63, lr = l & 15, lg = l >> 4;
  int n0 = blockIdx.x * 128;
  int t0 = slot_token[sb + 32 * w + lr];
  int t1 = slot_token[sb + 32 * w + 16 + lr];
  const unsigned short* ga0 = (t0 < 0 ? zp : xnb + (size_t)t0 * 768) + lg * 8;
  const unsigned short* ga1 = (t1 < 0 ? zp : xnb + (size_t)t1 * 768) + lg * 8;
  const unsigned short* WgE = wgT + (size_t)e * FDIM * 768;
  const unsigned short* WuE = wuT + (size_t)e * FDIM * 768;
  const unsigned short* gg0 = WgE + (size_t)(n0 + 32 * w + lr) * 768 + lg * 8;
  const unsigned short* gg1 = gg0 + 16 * 768;
  const unsigned short* gu0 = WuE + (size_t)(n0 + 32 * w + lr) * 768 + lg * 8;
  const unsigned short* gu1 = gu0 + 16 * 768;
  f32x4 ag[4][4], au[4][4];
  #pragma unroll
  for (int i = 0; i < 4; ++i)
    #pragma unroll
    for (int j = 0; j < 4; ++j) {
      ag[i][j] = (f32x4){0.f, 0.f, 0.f, 0.f};
      au[i][j] = (f32x4){0.f, 0.f, 0.f, 0.f};
    }
  int wr = w >> 1, wc = w & 1;
  for (int k0 = 0; k0 < 768; k0 += 32) {
    gload16(ga0 + k0, As + 1024 * w);
    gload16(ga1 + k0, As + 1024 * w + 512);
    gload16(gg0 + k0, Bg + 1024 * w);
    gload16(gg1 + k0, Bg + 1024 * w + 512);
    gload16(gu0 + k0, Bu + 1024 * w);
    gload16(gu1 + k0, Bu + 1024 * w + 512);
    __syncthreads();
    short8 af[4];
    #pragma unroll
    for (int i = 0; i < 4; ++i) af[i] = *(const short8*)(As + (wr * 4 + i) * 512 + l * 8);
    #pragma unroll
    for (int j = 0; j < 4; ++j) {
      short8 bg = *(const short8*)(Bg + (wc * 4 + j) * 512 + l * 8);
      short8 bu = *(const short8*)(Bu + (wc * 4 + j) * 512 + l * 8);
      #pragma unroll
      for (int i = 0; i < 4; ++i) {
        ag[i][j] = __builtin_amdgcn_mfma_f32_16x16x32_bf16(af[i], bg, ag[i][j], 0, 0, 0);
        au[i][j] = __builtin_amdgcn_mfma_f32_16x16x32_bf16(af[i], bu, au[i][j], 0, 0, 0);
      }
    }
    __syncthreads();
  }
  int colb = n0 + wc * 64 + lr;
  int rowb = sb + wr * 64 + lg * 4;
  #pragma unroll
  for (int i = 0; i < 4; ++i)
    #pragma unroll
    for (int j = 0; j < 4; ++j) {
      int col = colb + j * 16;
      #pragma unroll
      for (int r = 0; r < 4; ++r) {
        float g = ag[i][j][r], u = au[i][j][r];
        hb[(size_t)(rowb + i * 16 + r) * FDIM + col] = f2bf(g / (1.0f + expf(-g)) * u);
      }
    }
}

__global__ __launch_bounds__(256) void gemm_d(const unsigned short* __restrict__ hb,
    const unsigned short* __restrict__ wdT, unsigned short* __restrict__ ob,
    const int* __restrict__ offs) {
  __shared__ __align__(16) unsigned short As[4096], Bs[4096];
  int sb = blockIdx.y * 128;
  if (sb >= offs[8]) return;
  int e = 0;
  #pragma unroll
  for (int i = 1; i < 8; ++i) if (sb >= offs[i]) e = i;
  int tid = threadIdx.x, w = tid >> 6, l = tid & 63, lr = l & 15, lg = l >> 4;
  int n0 = blockIdx.x * 128;
  const unsigned short* ga0 = hb + (size_t)(sb + 32 * w + lr) * FDIM + lg * 8;
  const unsigned short* ga1 = ga0 + (size_t)16 * FDIM;
  const unsigned short* WdE = wdT + (size_t)e * 768 * FDIM;
  const unsigned short* gb0 = WdE + (size_t)(n0 + 32 * w + lr) * FDIM + lg * 8;
  const unsigned short* gb1 = gb0 + (size_t)16 * FDIM;
  f32x4 acc[4][4];
  #pragma unroll
  for (int i = 0; i < 4; ++i)
    #pragma unroll
    for (int j = 0; j < 4; ++j) acc[i][j] = (f32x4){0.f, 0.f, 0.f, 0.f};
  int wr = w >> 1, wc = w & 1;
  for (int k0 = 0; k0 < FDIM; k0 += 32) {
    gload16(ga0 + k0, As + 1024 * w);
    gload16(ga1 + k0, As + 1024 * w + 512);
    gload16(gb0 + k0, Bs + 1024 * w);
    gload16(gb1 + k0, Bs + 1024 * w + 512);
    __syncthreads();
    short8 af[4], bf[4];
    #pragma unroll
    for (int i = 0; i < 4; ++i) af[i] = *(const short8*)(As + (wr * 4 + i) * 512 + l * 8);
    #pragma unroll
    for (int j = 0; j < 4; ++j) bf[j] = *(const short8*)(Bs + (wc * 4 + j) * 512 + l * 8);
    #pragma unroll
    for (int i = 0; i < 4; ++i)
      #pragma unroll
      for (int j = 0; j < 4; ++j)
        acc[i][j] = __builtin_amdgcn_mfma_f32_16x16x32_bf16(af[i], bf[j], acc[i][j], 0, 0, 0);
    __syncthreads();
  }
  int colb = n0 + wc * 64 + lr;
  int rowb = sb + wr * 64 + lg * 4;
  #pragma unroll
  for (int i = 0; i < 4; ++i)
    #pragma unroll
    for (int j = 0; j < 4; ++j) {
      int col = colb + j * 16;
      #pragma unroll
      for (int r = 0; r < 4; ++r)
        ob[(size_t)(rowb + i * 16 + r) * 768 + col] = f2bf(acc[i][j][r]);
    }
}

// ---------------------------------------------------------------- attention (f32, register-tiled)
// 64x64 tiles, 4x4 micro-tile/thread, P aliased onto K buffer, causal pair-balanced grid.
__global__ __launch_bounds__(256) void attn_k(const float* __restrict__ qkv,
                                              unsigned short* __restrict__ ax3, size_t pPS) {
  int pr = blockIdx.x, h = blockIdx.y, b = blockIdx.z;
  int tid = threadIdx.x;
  int ty4 = (tid >> 4) << 2, tx4 = (tid & 15) << 2;
  __shared__ float qs[64][68];    // [d][q]
  __shared__ float kps[64][68];   // [d][k] during QK, then [q][k] = P during PV
  __shared__ float vs[64][68];    // [k][d]
  int lr = tid >> 2;              // 0..63 load row
  int lc = (tid & 3) << 4;        // 0,16,32,48 d-chunk
  for (int half = 0; half < 2; ++half) {
    int qt = half ? (15 - pr) : pr;
    int q0 = qt << 6;
    size_t qbase = ((size_t)(b * 1024 + q0 + lr)) * 2304 + h * 64 + lc;
    #pragma unroll
    for (int i = 0; i < 4; ++i) {
      float4 v = *(const float4*)(qkv + qbase + 4 * i);
      qs[lc + 4 * i + 0][lr] = v.x;
      qs[lc + 4 * i + 1][lr] = v.y;
      qs[lc + 4 * i + 2][lr] = v.z;
      qs[lc + 4 * i + 3][lr] = v.w;
    }
    float acc[4][4];
    float m[4], l[4];
    #pragma unroll
    for (int i = 0; i < 4; ++i) {
      m[i] = -3.0e38f; l[i] = 0.0f;
      #pragma unroll
      for (int j = 0; j < 4; ++j) acc[i][j] = 0.0f;
    }
    for (int kt = 0; kt <= qt; ++kt) {
      int k0 = kt << 6;
      __syncthreads();                                  // prev PV / Q-store ordering
      size_t kb = ((size_t)(b * 1024 + k0 + lr)) * 2304 + 768 + h * 64 + lc;
      #pragma unroll
      for (int i = 0; i < 4; ++i) {
        float4 kv = *(const float4*)(qkv + kb + 4 * i);
        kps[lc + 4 * i + 0][lr] = kv.x;
        kps[lc + 4 * i + 1][lr] = kv.y;
        kps[lc + 4 * i + 2][lr] = kv.z;
        kps[lc + 4 * i + 3][lr] = kv.w;
        *(float4*)&vs[lr][lc + 4 * i] = *(const float4*)(qkv + kb + 768 + 4 * i);
      }
      __syncthreads();                                  // K,V visible
      float s[4][4];
      #pragma unroll
      for (int i = 0; i < 4; ++i)
        #pragma unroll
        for (int j = 0; j < 4; ++j) s[i][j] = 0.0f;
      #pragma unroll 8
      for (int d = 0; d < 64; ++d) {
        float4 qv = *(const float4*)&qs[d][ty4];
        float4 kv = *(const float4*)&kps[d][tx4];
        float qa[4] = {qv.x, qv.y, qv.z, qv.w};
        float ka[4] = {kv.x, kv.y, kv.z, kv.w};
        #pragma unroll
        for (int i = 0; i < 4; ++i)
          #pragma unroll
          for (int j = 0; j < 4; ++j) s[i][j] += qa[i] * ka[j];
      }
      bool diag = (kt == qt);
      #pragma unroll
      for (int i = 0; i < 4; ++i) {
        #pragma unroll
        for (int j = 0; j < 4; ++j) {
          if (diag && (tx4 + j > ty4 + i)) s[i][j] = -1.0e30f;
          else s[i][j] *= 0.125f;                       // 1/sqrt(64)
        }
        float mx = fmaxf(fmaxf(s[i][0], s[i][1]), fmaxf(s[i][2], s[i][3]));
        mx = fmaxf(mx, __shfl_xor(mx, 1));
        mx = fmaxf(mx, __shfl_xor(mx, 2));
        mx = fmaxf(mx, __shfl_xor(mx, 4));
        mx = fmaxf(mx, __shfl_xor(mx, 8));
        float mnew = fmaxf(m[i], mx);
        float c = expf(m[i] - mnew);
        float rs = 0.0f;
        #pragma unroll
        for (int j = 0; j < 4; ++j) { s[i][j] = expf(s[i][j] - mnew); rs += s[i][j]; }
        rs += __shfl_xor(rs, 1);
        rs += __shfl_xor(rs, 2);
        rs += __shfl_xor(rs, 4);
        rs += __shfl_xor(rs, 8);
        l[i] = l[i] * c + rs;
        m[i] = mnew;
        #pragma unroll
        for (int j = 0; j < 4; ++j) acc[i][j] *= c;
      }
      __syncthreads();                                  // all QK reads of kps done
      #pragma unroll
      for (int i = 0; i < 4; ++i)
        *(float4*)&kps[ty4 + i][tx4] = make_float4(s[i][0], s[i][1], s[i][2], s[i][3]);
      __syncthreads();                                  // P visible
      #pragma unroll 4
      for (int kk = 0; kk < 16; ++kk) {
        float4 v0 = *(const float4*)&vs[(kk << 2) + 0][tx4];
        float4 v1 = *(const float4*)&vs[(kk << 2) + 1][tx4];
        float4 v2 = *(const float4*)&vs[(kk << 2) + 2][tx4];
        float4 v3 = *(const float4*)&vs[(kk << 2) + 3][tx4];
        #pragma unroll
        for (int i = 0; i < 4; ++i) {
          float4 p4 = *(const float4*)&kps[ty4 + i][kk << 2];
          acc[i][0] += p4.x * v0.x + p4.y * v1.x + p4.z * v2.x + p4.w * v3.x;
          acc[i][1] += p4.x * v0.y + p4.y * v1.y + p4.z * v2.y + p4.w * v3.y;
          acc[i][2] += p4.x * v0.z + p4.y * v1.z + p4.z * v2.z + p4.w * v3.z;
          acc[i][3] += p4.x * v0.w + p4.y * v1.w + p4.z * v2.w + p4.w * v3.w;
        }
      }
    }
    __syncthreads();                                    // PV done before buffers reused
    #pragma unroll
    for (int i = 0; i < 4; ++i) {
      float invl = 1.0f / l[i];
      size_t ob = ((size_t)(b * 1024 + q0 + ty4 + i)) * 768 + h * 64 + tx4;
      ushort4 vh, vm, vl;
      unsigned short a0, a1, a2;
      split3f(acc[i][0] * invl, a0, a1, a2); vh.x = a0; vm.x = a1; vl.x = a2;
      split3f(acc[i][1] * invl, a0, a1, a2); vh.y = a0; vm.y = a1; vl.y = a2;
      split3f(acc[i][2] * invl, a0, a1, a2); vh.z = a0; vm.z = a1; vl.z = a2;
      split3f(acc[i][3] * invl, a0, a1, a2); vh.w = a0; vm.w = a1; vl.w = a2;
      *(ushort4*)(ax3 + ob) = vh;
      *(ushort4*)(ax3 + pPS + ob) = vm;
      *(ushort4*)(ax3 + 2 * pPS + ob) = vl;
    }
  }
}

// ---------------------------------------------------------------- MoE routing (exact f32)
__global__ __launch_bounds__(256) void router_k(const float* __restrict__ xn,
                                                const float* __restrict__ rw,
                                                int* __restrict__ tk_idx, float* __restrict__ tk_w,
                                                int* __restrict__ cnt, float* __restrict__ psum) {
  __shared__ float bps[8];
  __shared__ int bcnt[8];
  int tid = threadIdx.x;
  if (tid < 8) { bps[tid] = 0.0f; bcnt[tid] = 0; }
  __syncthreads();
  int t = blockIdx.x * 4 + (tid >> 6);
  int lane = tid & 63;
  const float* xr = xn + (size_t)t * 768;
  float p[8] = {};
  for (int d = lane; d < 768; d += 64) {
    float xv = xr[d];
    const float* wr = rw + (size_t)d * 8;
    #pragma unroll
    for (int e = 0; e < 8; ++e) p[e] += xv * wr[e];
  }
  #pragma unroll
  for (int e = 0; e < 8; ++e) {
    float v = p[e];
    #pragma unroll
    for (int o = 32; o > 0; o >>= 1) v += __shfl_xor(v, o);
    p[e] = v;
  }
  if (lane == 0) {
    float mx = p[0];
    #pragma unroll
    for (int e = 1; e < 8; ++e) mx = fmaxf(mx, p[e]);
    float s = 0.0f;
    #pragma unroll
    for (int e = 0; e < 8; ++e) { p[e] = expf(p[e] - mx); s += p[e]; }
    float invs = 1.0f / s;
    #pragma unroll
    for (int e = 0; e < 8; ++e) p[e] *= invs;
    int i1 = 0; float v1 = p[0];
    #pragma unroll
    for (int e = 1; e < 8; ++e) if (p[e] > v1) { v1 = p[e]; i1 = e; }
    int i2 = (i1 == 0) ? 1 : 0; float v2 = p[i2];
    #pragma unroll
    for (int e = 0; e < 8; ++e) if (e != i1 && p[e] > v2) { v2 = p[e]; i2 = e; }
    float wsum = v1 + v2;
    tk_idx[t * 2] = i1; tk_idx[t * 2 + 1] = i2;
    tk_w[t * 2] = v1 / wsum; tk_w[t * 2 + 1] = v2 / wsum;
    atomicAdd(&bcnt[i1], 1); atomicAdd(&bcnt[i2], 1);
    #pragma unroll
    for (int e = 0; e < 8; ++e) atomicAdd(&bps[e], p[e]);
  }
  __syncthreads();
  if (tid < 8) {
    atomicAdd(&cnt[tid], bcnt[tid]);
    atomicAdd(&psum[tid], bps[tid]);
  }
}

__global__ void moe_offsets_k(const int* __restrict__ cnt, int* __restrict__ offs,
                              const float* __restrict__ psum, float* __restrict__ aux) {
  if (threadIdx.x == 0) {
    int o = 0; float a = 0.0f;
    for (int e = 0; e < 8; ++e) {
      offs[e] = o;
      o += (cnt[e] + 127) & ~127;
      a += ((float)cnt[e] / 4096.0f) * (psum[e] / 4096.0f);
    }
    offs[8] = o;
    aux[0] += a * 8.0f;
  }
}

__global__ void moe_fill_k(const int* __restrict__ tk_idx, const int* __restrict__ offs,
                           int* __restrict__ fill, int* __restrict__ slot_token,
                           int* __restrict__ tk_slot) {
  int i = blockIdx.x * 256 + threadIdx.x;              // grid 32
  int e = tk_idx[i];
  int pos = atomicAdd(&fill[e], 1);
  int slot = offs[e] + pos;
  slot_token[slot] = i >> 1;
  tk_slot[i] = slot;
}

template <int BF>  // 0: os f32; 1: os bf16
__global__ void moe_combine_k(float* __restrict__ x, const void* __restrict__ osv,
                              const int* __restrict__ tk_slot, const float* __restrict__ tk_w) {
  int t = blockIdx.x;                                  // grid 4096 x 192
  int d = threadIdx.x << 2;
  int s0 = tk_slot[t * 2], s1 = tk_slot[t * 2 + 1];
  float w0 = tk_w[t * 2], w1 = tk_w[t * 2 + 1];
  float a0, a1, a2, a3, b0, b1, b2, b3;
  if (BF == 0) {
    const float* os = (const float*)osv;
    float4 a = *(const float4*)(os + (size_t)s0 * 768 + d);
    float4 b = *(const float4*)(os + (size_t)s1 * 768 + d);
    a0 = a.x; a1 = a.y; a2 = a.z; a3 = a.w;
    b0 = b.x; b1 = b.y; b2 = b.z; b3 = b.w;
  } else {
    const unsigned short* os = (const unsigned short*)osv;
    ushort4 a = *(const ushort4*)(os + (size_t)s0 * 768 + d);
    ushort4 b = *(const ushort4*)(os + (size_t)s1 * 768 + d);
    a0 = bf2f(a.x); a1 = bf2f(a.y); a2 = bf2f(a.z); a3 = bf2f(a.w);
    b0 = bf2f(b.x); b1 = bf2f(b.y); b2 = bf2f(b.z); b3 = bf2f(b.w);
  }
  float4 c = *(const float4*)(x + (size_t)t * 768 + d);
  c.x += w0 * a0 + w1 * b0;
  c.y += w0 * a1 + w1 * b1;
  c.z += w0 * a2 + w1 * b2;
  c.w += w0 * a3 + w1 * b3;
  *(float4*)(x + (size_t)t * 768 + d) = c;
}

__global__ void write_aux_k(const float* __restrict__ aux, float* __restrict__ out) {
  out[0] = aux[0];
}

// ---------------------------------------------------------------- host launcher

extern "C" void kernel_launch(void* const* d_in, const int* in_sizes, int n_in,
                              void* d_out, int out_size, void* d_ws, size_t ws_size,
                              hipStream_t stream) {
  const int* input_ids      = (const int*)d_in[0];
  const int* time_slots     = (const int*)d_in[1];
  const int* day_of_week    = (const int*)d_in[2];
  const int* month          = (const int*)d_in[3];
  const int* is_holiday     = (const int*)d_in[4];
  const int* location_ids   = (const int*)d_in[5];
  const int* road_types     = (const int*)d_in[6];
  const int* weather_states = (const int*)d_in[7];
  const float* word_emb     = (const float*)d_in[8];
  const float* time_emb     = (const float*)d_in[9];
  const float* dow_emb      = (const float*)d_in[10];
  const float* month_emb    = (const float*)d_in[11];
  const float* hol_emb      = (const float*)d_in[12];
  const float* loc_emb      = (const float*)d_in[13];
  const float* road_emb     = (const float*)d_in[14];
  const float* weather_emb  = (const float*)d_in[15];
  const float* proj_w       = (const float*)d_in[16];
  const float* proj_b       = (const float*)d_in[17];
  const float* emb_norm_w   = (const float*)d_in[18];
  const float* norm1_w     = (const float*)d_in[19];
  const float* Wq           = (const float*)d_in[20];
  const float* Wk           = (const float*)d_in[21];
  const float* Wv           = (const float*)d_in[22];
  const float* Wo           = (const float*)d_in[23];
  const float* norm2_w      = (const float*)d_in[24];
  const float* router_w     = (const float*)d_in[25];
  const float* Wg           = (const float*)d_in[26];
  const float* Wu           = (const float*)d_in[27];
  const float* Wd           = (const float*)d_in[28];
  const float* final_norm_w = (const float*)d_in[29];
  float* out = (float*)d_out;

  const size_t TD = (size_t)TTOK * 768;
  const size_t REG = (size_t)MAXSLOT * FDIM * 4;       // 113.25 MB shared regions
  char* base = (char*)d_ws;
  auto carve = [&](size_t bytes) { char* p = base; base += (bytes + 255) & ~(size_t)255; return p; };
  float* x    = (float*)carve(TD * 4);
  float* xn   = (float*)carve(TD * 4);
  float* cosb = (float*)carve(32768 * 4);
  float* sinb = (float*)carve(32768 * 4);
  float* ctx  = (float*)carve(4 * 1536 * 4);
  float* biasB= (float*)carve(4 * 768 * 4);
  float* tkw  = (float*)carve(8192 * 4);
  float* psum = (float*)carve(64);
  float* auxa = (float*)carve(64);
  int* cnt    = (int*)carve(64);
  int* fill   = (int*)carve(64);
  int* offs   = (int*)carve(64);
  int* tk_idx = (int*)carve(8192 * 4);
  int* tk_slot= (int*)carve(8192 * 4);
  int* slot_token = (int*)carve(MAXSLOT * 4);
  unsigned short* zp = (unsigned short*)carve(4096);
  unsigned short* xnb3 = (unsigned short*)carve(3 * TD * 2);
  char* QAH = carve(REG);                               // qkv+ax3 (attn) / h (moe)
  char* GT  = carve(REG);                               // gtmp / ob
  char* Wr  = carve(REG);                               // weight planes (sequential)
  float* qkv = (float*)QAH;
  unsigned short* ax3 = (unsigned short*)(QAH + (size_t)TTOK * 2304 * 4);
  float* hbf = (float*)QAH;
  unsigned short* hb16 = (unsigned short*)QAH;
  float* gtmp = (float*)GT;
  float* obf = (float*)GT;
  unsigned short* ob16 = (unsigned short*)GT;
  unsigned short* wpl = (unsigned short*)Wr;

  const size_t PS_D = (size_t)768 * 768;                // dense 768x768 plane stride
  const size_t PS_QKV = (size_t)2304 * 768;
  const size_t PS_E = (size_t)8 * FDIM * 768;           // expert-tensor plane stride

  hipMemsetAsync(auxa, 0, 64, stream);
  hipMemsetAsync(zp, 0, 4096, stream);
  rope_cache_k<<<dim3(1024), dim3(32), 0, stream>>>(cosb, sinb);
  build_ctx_k<<<dim3(4, 6), dim3(256), 0, stream>>>(time_slots, day_of_week, month, is_holiday,
      location_ids, road_types, weather_states, time_emb, dow_emb, month_emb, hol_emb,
      loc_emb, road_emb, weather_emb, ctx);
  build_bias_k<<<dim3(4, 3), dim3(256), 0, stream>>>(ctx, proj_w, proj_b, biasB);
  tconv3_k<<<dim3(24, 24, 1), dim3(32, 8), 0, stream>>>(proj_w, wpl, PS_D, 768, 768, 0, 0);
  gconv3_k<<<dim3(TTOK), dim3(192), 0, stream>>>(word_emb, input_ids, xnb3, TD);
  gemm3<3><<<dim3(6, 32), dim3(256), 0, stream>>>(xnb3, TD, wpl, PS_D, xn, 768, 768, biasB);
  rmsnorm_k<0><<<dim3(TTOK), dim3(256), 0, stream>>>(xn, emb_norm_w, x, nullptr, 0);

  for (int l = 0; l < 2; ++l) {
    const float* rw = router_w + (size_t)l * 768 * 8;
    // ---- attention (split-3 GEMMs, f32 flash core) ----
    tconv3_k<<<dim3(24, 24, 1), dim3(32, 8), 0, stream>>>(Wq + (size_t)l * PS_D, wpl, PS_QKV, 768, 768, 0, 0);
    tconv3_k<<<dim3(24, 24, 1), dim3(32, 8), 0, stream>>>(Wk + (size_t)l * PS_D, wpl + PS_D, PS_QKV, 768, 768, 0, 0);
    tconv3_k<<<dim3(24, 24, 1), dim3(32, 8), 0, stream>>>(Wv + (size_t)l * PS_D, wpl + 2 * PS_D, PS_QKV, 768, 768, 0, 0);
    rmsnorm_k<1><<<dim3(TTOK), dim3(256), 0, stream>>>(x, norm1_w + l * 768, nullptr, xnb3, TD);
    gemm3<0><<<dim3(18, 32), dim3(256), 0, stream>>>(xnb3, TD, wpl, PS_QKV, qkv, 2304, 768, nullptr);
    rope_apply_k<<<dim3(6144), dim3(256), 0, stream>>>(qkv, cosb, sinb);
    attn_k<<<dim3(8, 12, 4), dim3(256), 0, stream>>>(qkv, ax3, TD);
    tconv3_k<<<dim3(24, 24, 1), dim3(32, 8), 0, stream>>>(Wo + (size_t)l * PS_D, wpl, PS_D, 768, 768, 0, 0);
    gemm3<2><<<dim3(6, 32), dim3(256), 0, stream>>>(ax3, TD, wpl, PS_D, x, 768, 768, nullptr);

    // ---- MoE ----
    if (l == 0)
      rmsnorm_k<2><<<dim3(TTOK), dim3(256), 0, stream>>>(x, norm2_w, xn, xnb3, TD);
    else
      rmsnorm_k<3><<<dim3(TTOK), dim3(256), 0, stream>>>(x, norm2_w + 768, xn, xnb3, TD);
    hipMemsetAsync(cnt, 0, 64, stream);
    hipMemsetAsync(fill, 0, 64, stream);
    hipMemsetAsync(psum, 0, 64, stream);
    hipMemsetAsync(slot_token, 0xFF, MAXSLOT * 4, stream);
    router_k<<<dim3(1024), dim3(256), 0, stream>>>(xn, rw, tk_idx, tkw, cnt, psum);
    moe_offsets_k<<<dim3(1), dim3(64), 0, stream>>>(cnt, offs, psum, auxa);
    moe_fill_k<<<dim3(32), dim3(256), 0, stream>>>(tk_idx, offs, fill, slot_token, tk_slot);
    if (l == 0) {
      // split-2 experts (~17-bit): feed layer-1 router only via residual (damped)
      tconv2_k<<<dim3(96, 24, 8), dim3(32, 8), 0, stream>>>(Wg, wpl, PS_E,
          768, FDIM, (size_t)768 * FDIM, (size_t)FDIM * 768);
      gemm2_gu<0><<<dim3(24, MAXSLOT / 128), dim3(256), 0, stream>>>(xnb3, TD, wpl, PS_E,
          gtmp, nullptr, slot_token, offs, zp);
      tconv2_k<<<dim3(96, 24, 8), dim3(32, 8), 0, stream>>>(Wu, wpl, PS_E,
          768, FDIM, (size_t)768 * FDIM, (size_t)FDIM * 768);
      gemm2_gu<1><<<dim3(24, MAXSLOT / 128), dim3(256), 0, stream>>>(xnb3, TD, wpl, PS_E,
          hbf, gtmp, slot_token, offs, zp);
      tconv2_k<<<dim3(24, 96, 8), dim3(32, 8), 0, stream>>>(Wd, wpl, PS_E,
          FDIM, 768, (size_t)FDIM * 768, (size_t)768 * FDIM);
      gemm2_dn<<<dim3(6, MAXSLOT / 128), dim3(256), 0, stream>>>(hbf, wpl, PS_E, obf, offs);
      moe_combine_k<0><<<dim3(TTOK), dim3(192), 0, stream>>>(x, obf, tk_slot, tkw);
    } else {
      // plain bf16 experts (feed only final output)
      const float* wg1 = Wg + (size_t)8 * 768 * FDIM;
      const float* wu1 = Wu + (size_t)8 * 768 * FDIM;
      const float* wd1 = Wd + (size_t)8 * FDIM * 768;
      tconv_k<<<dim3(96, 24, 8), dim3(32, 8), 0, stream>>>(wg1, wpl,
          768, FDIM, (size_t)768 * FDIM, (size_t)FDIM * 768);
      tconv_k<<<dim3(96, 24, 8), dim3(32, 8), 0, stream>>>(wu1, wpl + PS_E,
          768, FDIM, (size_t)768 * FDIM, (size_t)FDIM * 768);
      gemm_gu<<<dim3(24, MAXSLOT / 128), dim3(256), 0, stream>>>(xnb3, wpl, wpl + PS_E,
          hb16, slot_token, offs, zp);
      tconv_k<<<dim3(24, 96, 8), dim3(32, 8), 0, stream>>>(wd1, wpl,
          FDIM, 768, (size_t)FDIM * 768, (size_t)768 * FDIM);
      gemm_d<<<dim3(6, MAXSLOT / 128), dim3(256), 0, stream>>>(hb16, wpl, ob16, offs);
      moe_combine_k<1><<<dim3(TTOK), dim3(192), 0, stream>>>(x, ob16, tk_slot, tkw);
    }
  }

  rmsnorm_k<0><<<dim3(TTOK), dim3(256), 0, stream>>>(x, final_norm_w, out, nullptr, 0);
  write_aux_k<<<dim3(1), dim3(1), 0, stream>>>(auxa, out + TD);
}

// Round 6
// 2129.214 us; speedup vs baseline: 2.2590x; 1.0911x over previous
//
#include <hip/hip_runtime.h>
#include <math.h>

// Traffic foundation model, round 5.
// vs round 4: (1) L1 gate/up GEMM restructured: N-concat single-accumulator
// kernel (VGPR ~104 vs 160, 16 MFMA/K-step) + separate silu_mul pass — fixes
// the 11.9% MfmaUtil / 11% occupancy latency stall. (2) QKV + Wo GEMMs move
// from split-3 to split-2 (17-bit) — round-4 validated that 17-bit GEMM error
// doesn't move router decisions (absmax bit-identical). proj stays split-3;
// router exact f32; L0 experts split-2; L1 experts plain bf16.

#define TTOK 4096
#define FDIM 3072
#define MAXSLOT 9216   // 8192 + 8*127 pad, 128-aligned offsets

typedef __attribute__((ext_vector_type(8))) short short8;
typedef __attribute__((ext_vector_type(4))) float f32x4;

__device__ __forceinline__ float bf2f(unsigned short u) {
  return __uint_as_float(((unsigned int)u) << 16);
}
__device__ __forceinline__ unsigned short f2bf(float f) {
  unsigned int u = __float_as_uint(f);
  u += 0x7fffu + ((u >> 16) & 1u);
  return (unsigned short)(u >> 16);
}
// exact 3-way bf16 split: a ~= h + m + l to ~24 mantissa bits
__device__ __forceinline__ void split3f(float a, unsigned short& h, unsigned short& m,
                                        unsigned short& l) {
  h = f2bf(a);
  float r = a - bf2f(h);
  m = f2bf(r);
  r -= bf2f(m);
  l = f2bf(r);
}
// 2-way bf16 split: a ~= h + m to ~17 mantissa bits
__device__ __forceinline__ void split2f(float a, unsigned short& h, unsigned short& m) {
  h = f2bf(a);
  m = f2bf(a - bf2f(h));
}
__device__ __forceinline__ void gload16(const void* g, void* l) {
  __builtin_amdgcn_global_load_lds((const __attribute__((address_space(1))) unsigned int*)g,
                                   (__attribute__((address_space(3))) unsigned int*)l, 16, 0, 0);
}

#define MFMA_TERM(ACC, PA, PB)                                                              \
  _Pragma("unroll") for (int i_ = 0; i_ < 4; ++i_)                                          \
      _Pragma("unroll") for (int j_ = 0; j_ < 4; ++j_)                                      \
          ACC[i_][j_] = __builtin_amdgcn_mfma_f32_16x16x32_bf16(af[PA][i_], bf[PB][j_],     \
                                                                ACC[i_][j_], 0, 0, 0);
// 6-term split-3 (smallest terms first)
#define MFMA_SPLIT3(ACC)  \
  MFMA_TERM(ACC, 0, 2) MFMA_TERM(ACC, 2, 0) MFMA_TERM(ACC, 1, 1) \
  MFMA_TERM(ACC, 0, 1) MFMA_TERM(ACC, 1, 0) MFMA_TERM(ACC, 0, 0)
// 3-term split-2
#define MFMA_SPLIT2(ACC)  \
  MFMA_TERM(ACC, 0, 1) MFMA_TERM(ACC, 1, 0) MFMA_TERM(ACC, 0, 0)

// ---------------------------------------------------------------- small kernels

__global__ void rope_cache_k(float* __restrict__ cosb, float* __restrict__ sinb) {
  int s = blockIdx.x, i = threadIdx.x;                 // grid 1024 x 32
  float inv = powf(10000.0f, -(float)i / 32.0f);
  float a = (float)s * inv;
  cosb[s * 32 + i] = cosf(a);
  sinb[s * 32 + i] = sinf(a);
}

__global__ void build_ctx_k(const int* ts, const int* dow, const int* mon, const int* hol,
                            const int* loc, const int* road, const int* wth,
                            const float* te, const float* de, const float* me, const float* he,
                            const float* le, const float* re, const float* we,
                            float* __restrict__ ctx) {
  int b = blockIdx.x;
  int j = blockIdx.y * 256 + threadIdx.x;              // grid (4,6) x 256
  float v;
  if (j < 192)       v = te[ts[b] * 192 + j];
  else if (j < 384)  v = de[dow[b] * 192 + (j - 192)];
  else if (j < 576)  v = me[mon[b] * 192 + (j - 384)];
  else if (j < 768)  v = he[hol[b] * 192 + (j - 576)];
  else if (j < 1152) v = le[loc[b] * 384 + (j - 768)];
  else if (j < 1344) v = re[road[b] * 192 + (j - 1152)];
  else               v = we[wth[b] * 192 + (j - 1344)];
  ctx[b * 1536 + j] = v;
}

// biasB[b][d] = proj_b[d] + sum_j ctx[b][j] * proj_w[768+j][d]  (exact f32)
__global__ void build_bias_k(const float* __restrict__ ctx, const float* __restrict__ pw,
                             const float* __restrict__ pb, float* __restrict__ biasB) {
  int b = blockIdx.x;
  int d = blockIdx.y * 256 + threadIdx.x;              // grid (4,3) x 256
  float s = pb[d];
  const float* cb = ctx + b * 1536;
  for (int j = 0; j < 1536; ++j) s += cb[j] * pw[(size_t)(768 + j) * 768 + d];
  biasB[b * 768 + d] = s;
}

// transpose + split-3: dst[p][n][k] = split(src[k][n]). grid (N/32, K/32, batch), block (32,8)
__global__ void tconv3_k(const float* __restrict__ src, unsigned short* __restrict__ dst,
                         size_t dPS, int K, int N, size_t sstride, size_t dstride) {
  __shared__ float tile[32][33];
  src += (size_t)blockIdx.z * sstride;
  size_t dbase = (size_t)blockIdx.z * dstride;
  int n0 = blockIdx.x * 32, k0 = blockIdx.y * 32;
  int tx = threadIdx.x, ty = threadIdx.y;
  #pragma unroll
  for (int r = 0; r < 4; ++r)
    tile[ty + r * 8][tx] = src[(size_t)(k0 + ty + r * 8) * N + n0 + tx];
  __syncthreads();
  #pragma unroll
  for (int r = 0; r < 4; ++r) {
    int n = n0 + ty + r * 8;
    unsigned short h, m, lo;
    split3f(tile[tx][ty + r * 8], h, m, lo);
    size_t di = dbase + (size_t)n * K + k0 + tx;
    dst[di] = h; dst[di + dPS] = m; dst[di + 2 * dPS] = lo;
  }
}

// transpose + split-2: dst[p][n][k], 2 planes
__global__ void tconv2_k(const float* __restrict__ src, unsigned short* __restrict__ dst,
                         size_t dPS, int K, int N, size_t sstride, size_t dstride) {
  __shared__ float tile[32][33];
  src += (size_t)blockIdx.z * sstride;
  size_t dbase = (size_t)blockIdx.z * dstride;
  int n0 = blockIdx.x * 32, k0 = blockIdx.y * 32;
  int tx = threadIdx.x, ty = threadIdx.y;
  #pragma unroll
  for (int r = 0; r < 4; ++r)
    tile[ty + r * 8][tx] = src[(size_t)(k0 + ty + r * 8) * N + n0 + tx];
  __syncthreads();
  #pragma unroll
  for (int r = 0; r < 4; ++r) {
    int n = n0 + ty + r * 8;
    unsigned short h, m;
    split2f(tile[tx][ty + r * 8], h, m);
    size_t di = dbase + (size_t)n * K + k0 + tx;
    dst[di] = h; dst[di + dPS] = m;
  }
}

// transpose-convert single plane (plain bf16, for layer-1 experts)
__global__ void tconv_k(const float* __restrict__ src, unsigned short* __restrict__ dst,
                        int K, int N, size_t sstride, size_t dstride) {
  __shared__ unsigned short tile[32][33];
  src += (size_t)blockIdx.z * sstride;
  unsigned short* d = dst + (size_t)blockIdx.z * dstride;
  int n0 = blockIdx.x * 32, k0 = blockIdx.y * 32;
  int tx = threadIdx.x, ty = threadIdx.y;
  #pragma unroll
  for (int r = 0; r < 4; ++r)
    tile[ty + r * 8][tx] = f2bf(src[(size_t)(k0 + ty + r * 8) * N + n0 + tx]);
  __syncthreads();
  #pragma unroll
  for (int r = 0; r < 4; ++r) {
    int n = n0 + ty + r * 8;
    d[(size_t)n * K + k0 + tx] = tile[tx][ty + r * 8];
  }
}

// gather word_emb rows -> 3 planes. grid 4096 x 192
__global__ void gconv3_k(const float* __restrict__ we, const int* __restrict__ ids,
                         unsigned short* __restrict__ x3, size_t pPS) {
  int t = blockIdx.x;
  int d = threadIdx.x << 2;
  float4 v = *(const float4*)(we + (size_t)ids[t] * 768 + d);
  ushort4 vh, vm, vl;
  split3f(v.x, vh.x, vm.x, vl.x);
  split3f(v.y, vh.y, vm.y, vl.y);
  split3f(v.z, vh.z, vm.z, vl.z);
  split3f(v.w, vh.w, vm.w, vl.w);
  size_t o = (size_t)t * 768 + d;
  *(ushort4*)(x3 + o) = vh;
  *(ushort4*)(x3 + pPS + o) = vm;
  *(ushort4*)(x3 + 2 * pPS + o) = vl;
}

// OUT: 0 f32 only; 1 2-plane only; 2 f32 + 2-plane; 3 f32 + single-bf16(plane0)
template <int OUT>
__global__ __launch_bounds__(256) void rmsnorm_k(const float* __restrict__ xin,
                                                 const float* __restrict__ w,
                                                 float* __restrict__ yf,
                                                 unsigned short* __restrict__ yb, size_t pPS) {
  int t = blockIdx.x;
  int tid = threadIdx.x;
  const float* xr = xin + (size_t)t * 768;
  float v0 = xr[tid], v1 = xr[tid + 256], v2 = xr[tid + 512];
  float ss = v0 * v0 + v1 * v1 + v2 * v2;
  #pragma unroll
  for (int o = 32; o > 0; o >>= 1) ss += __shfl_xor(ss, o);
  __shared__ float wss[4];
  if ((tid & 63) == 0) wss[tid >> 6] = ss;
  __syncthreads();
  float tot = wss[0] + wss[1] + wss[2] + wss[3];
  float inv = 1.0f / sqrtf(tot / 768.0f + 1e-6f);
  float o0 = v0 * inv * w[tid], o1 = v1 * inv * w[tid + 256], o2 = v2 * inv * w[tid + 512];
  if (OUT != 1) {
    float* yr = yf + (size_t)t * 768;
    yr[tid] = o0; yr[tid + 256] = o1; yr[tid + 512] = o2;
  }
  if (OUT == 1 || OUT == 2) {
    unsigned short* yr = yb + (size_t)t * 768;
    unsigned short h, m;
    split2f(o0, h, m); yr[tid] = h;       yr[tid + pPS] = m;
    split2f(o1, h, m); yr[tid + 256] = h; yr[tid + 256 + pPS] = m;
    split2f(o2, h, m); yr[tid + 512] = h; yr[tid + 512 + pPS] = m;
  }
  if (OUT == 3) {
    unsigned short* yr = yb + (size_t)t * 768;
    yr[tid] = f2bf(o0); yr[tid + 256] = f2bf(o1); yr[tid + 512] = f2bf(o2);
  }
}

// rope in-place on f32 qkv [T][2304] (q at 0, k at 768)
__global__ __launch_bounds__(256) void rope_apply_k(float* __restrict__ qkv,
                                                    const float* __restrict__ cosb,
                                                    const float* __restrict__ sinb) {
  int idx = blockIdx.x * 256 + threadIdx.x;            // grid 6144
  int j = idx & 31;
  int hh = (idx >> 5) % 12;
  int t = idx / 384;
  int s = t & 1023;
  float c = cosb[s * 32 + j], sn = sinb[s * 32 + j];
  size_t base = (size_t)t * 2304 + hh * 64 + j;
  float q1 = qkv[base], q2 = qkv[base + 32];
  qkv[base]      = q1 * c - q2 * sn;
  qkv[base + 32] = q2 * c + q1 * sn;
  size_t kb = base + 768;
  float k1 = qkv[kb], k2 = qkv[kb + 32];
  qkv[kb]      = k1 * c - k2 * sn;
  qkv[kb + 32] = k2 * c + k1 * sn;
}

// ---------------------------------------------------------------- split-3 dense GEMM (proj only)
// EPI 3: f32 store + per-batch bias
template <int EPI>
__global__ __launch_bounds__(256) void gemm3(const unsigned short* __restrict__ A, size_t aPS,
                                             const unsigned short* __restrict__ BT, size_t bPS,
                                             float* __restrict__ Cf, int N, int K,
                                             const float* __restrict__ rowBias) {
  __shared__ __align__(16) unsigned short As[3][4096];
  __shared__ __align__(16) unsigned short Bs[3][4096];
  int tid = threadIdx.x, w = tid >> 6, l = tid & 63, lr = l & 15, lg = l >> 4;
  int m0 = blockIdx.y * 128, n0 = blockIdx.x * 128;
  size_t aoff = (size_t)(m0 + 32 * w + lr) * K + lg * 8;
  size_t boff = (size_t)(n0 + 32 * w + lr) * K + lg * 8;
  size_t aoff1 = aoff + (size_t)16 * K, boff1 = boff + (size_t)16 * K;
  f32x4 acc[4][4];
  #pragma unroll
  for (int i = 0; i < 4; ++i)
    #pragma unroll
    for (int j = 0; j < 4; ++j) acc[i][j] = (f32x4){0.f, 0.f, 0.f, 0.f};
  int wr = w >> 1, wc = w & 1;
  for (int k0 = 0; k0 < K; k0 += 32) {
    #pragma unroll
    for (int p = 0; p < 3; ++p) {
      gload16(A + p * aPS + aoff + k0,  &As[p][1024 * w]);
      gload16(A + p * aPS + aoff1 + k0, &As[p][1024 * w + 512]);
      gload16(BT + p * bPS + boff + k0,  &Bs[p][1024 * w]);
      gload16(BT + p * bPS + boff1 + k0, &Bs[p][1024 * w + 512]);
    }
    __syncthreads();
    short8 af[3][4], bf[3][4];
    #pragma unroll
    for (int p = 0; p < 3; ++p)
      #pragma unroll
      for (int i = 0; i < 4; ++i) {
        af[p][i] = *(const short8*)(&As[p][(wr * 4 + i) * 512 + l * 8]);
        bf[p][i] = *(const short8*)(&Bs[p][(wc * 4 + i) * 512 + l * 8]);
      }
    MFMA_SPLIT3(acc)
    __syncthreads();
  }
  int colb = n0 + wc * 64 + lr;
  int rowb = m0 + wr * 64 + lg * 4;
  #pragma unroll
  for (int i = 0; i < 4; ++i)
    #pragma unroll
    for (int j = 0; j < 4; ++j) {
      int col = colb + j * 16;
      #pragma unroll
      for (int r = 0; r < 4; ++r) {
        int row = rowb + i * 16 + r;
        size_t idx = (size_t)row * N + col;
        float v = acc[i][j][r];
        if (EPI == 0)      Cf[idx] = v;
        else if (EPI == 2) Cf[idx] += v;
        else               Cf[idx] = v + rowBias[(row >> 10) * 768 + col];
      }
    }
}

// ---------------------------------------------------------------- split-2 dense GEMM (QKV, Wo)
// EPI: 0 f32 store; 2 f32 +=
template <int EPI>
__global__ __launch_bounds__(256) void gemm2(const unsigned short* __restrict__ A, size_t aPS,
                                             const unsigned short* __restrict__ BT, size_t bPS,
                                             float* __restrict__ Cf, int N, int K) {
  __shared__ __align__(16) unsigned short As[2][4096];
  __shared__ __align__(16) unsigned short Bs[2][4096];
  int tid = threadIdx.x, w = tid >> 6, l = tid & 63, lr = l & 15, lg = l >> 4;
  int m0 = blockIdx.y * 128, n0 = blockIdx.x * 128;
  size_t aoff = (size_t)(m0 + 32 * w + lr) * K + lg * 8;
  size_t boff = (size_t)(n0 + 32 * w + lr) * K + lg * 8;
  size_t aoff1 = aoff + (size_t)16 * K, boff1 = boff + (size_t)16 * K;
  f32x4 acc[4][4];
  #pragma unroll
  for (int i = 0; i < 4; ++i)
    #pragma unroll
    for (int j = 0; j < 4; ++j) acc[i][j] = (f32x4){0.f, 0.f, 0.f, 0.f};
  int wr = w >> 1, wc = w & 1;
  for (int k0 = 0; k0 < K; k0 += 32) {
    #pragma unroll
    for (int p = 0; p < 2; ++p) {
      gload16(A + p * aPS + aoff + k0,  &As[p][1024 * w]);
      gload16(A + p * aPS + aoff1 + k0, &As[p][1024 * w + 512]);
      gload16(BT + p * bPS + boff + k0,  &Bs[p][1024 * w]);
      gload16(BT + p * bPS + boff1 + k0, &Bs[p][1024 * w + 512]);
    }
    __syncthreads();
    short8 af[2][4], bf[2][4];
    #pragma unroll
    for (int p = 0; p < 2; ++p)
      #pragma unroll
      for (int i = 0; i < 4; ++i) {
        af[p][i] = *(const short8*)(&As[p][(wr * 4 + i) * 512 + l * 8]);
        bf[p][i] = *(const short8*)(&Bs[p][(wc * 4 + i) * 512 + l * 8]);
      }
    MFMA_SPLIT2(acc)
    __syncthreads();
  }
  int colb = n0 + wc * 64 + lr;
  int rowb = m0 + wr * 64 + lg * 4;
  #pragma unroll
  for (int i = 0; i < 4; ++i)
    #pragma unroll
    for (int j = 0; j < 4; ++j) {
      int col = colb + j * 16;
      #pragma unroll
      for (int r = 0; r < 4; ++r) {
        int row = rowb + i * 16 + r;
        size_t idx = (size_t)row * N + col;
        float v = acc[i][j][r];
        if (EPI == 0) Cf[idx] = v;
        else          Cf[idx] += v;
      }
    }
}

// split-2 MoE gate/up GEMM, gathered A rows (planes 0,1 of xnb3). FUSE 0: store f32
// (g pass); FUSE 1: read g, out = silu(g)*u (u pass). N=3072, K=768.
template <int FUSE>
__global__ __launch_bounds__(256) void gemm2_gu(const unsigned short* __restrict__ X3, size_t xPS,
    const unsigned short* __restrict__ W2, size_t wPS, float* __restrict__ outb,
    const float* __restrict__ gin, const int* __restrict__ slot_token,
    const int* __restrict__ offs, const unsigned short* __restrict__ zp) {
  __shared__ __align__(16) unsigned short As[2][4096];
  __shared__ __align__(16) unsigned short Bs[2][4096];
  int sb = blockIdx.y * 128;
  if (sb >= offs[8]) return;
  int e = 0;
  #pragma unroll
  for (int i = 1; i < 8; ++i) if (sb >= offs[i]) e = i;
  int tid = threadIdx.x, w = tid >> 6, l = tid & 63, lr = l & 15, lg = l >> 4;
  int n0 = blockIdx.x * 128;
  const unsigned short* WE = W2 + (size_t)e * FDIM * 768;
  int t0 = slot_token[sb + 32 * w + lr];
  int t1 = slot_token[sb + 32 * w + 16 + lr];
  const unsigned short* a0[2];
  const unsigned short* a1[2];
  #pragma unroll
  for (int p = 0; p < 2; ++p) {
    a0[p] = (t0 < 0 ? zp : X3 + p * xPS + (size_t)t0 * 768) + lg * 8;
    a1[p] = (t1 < 0 ? zp : X3 + p * xPS + (size_t)t1 * 768) + lg * 8;
  }
  size_t boff = (size_t)(n0 + 32 * w + lr) * 768 + lg * 8;
  size_t boff1 = boff + (size_t)16 * 768;
  f32x4 acc[4][4];
  #pragma unroll
  for (int i = 0; i < 4; ++i)
    #pragma unroll
    for (int j = 0; j < 4; ++j) acc[i][j] = (f32x4){0.f, 0.f, 0.f, 0.f};
  int wr = w >> 1, wc = w & 1;
  for (int k0 = 0; k0 < 768; k0 += 32) {
    #pragma unroll
    for (int p = 0; p < 2; ++p) {
      gload16(a0[p] + k0, &As[p][1024 * w]);
      gload16(a1[p] + k0, &As[p][1024 * w + 512]);
      gload16(WE + p * wPS + boff + k0,  &Bs[p][1024 * w]);
      gload16(WE + p * wPS + boff1 + k0, &Bs[p][1024 * w + 512]);
    }
    __syncthreads();
    short8 af[2][4], bf[2][4];
    #pragma unroll
    for (int p = 0; p < 2; ++p)
      #pragma unroll
      for (int i = 0; i < 4; ++i) {
        af[p][i] = *(const short8*)(&As[p][(wr * 4 + i) * 512 + l * 8]);
        bf[p][i] = *(const short8*)(&Bs[p][(wc * 4 + i) * 512 + l * 8]);
      }
    MFMA_SPLIT2(acc)
    __syncthreads();
  }
  int colb = n0 + wc * 64 + lr;
  int rowb = sb + wr * 64 + lg * 4;
  #pragma unroll
  for (int i = 0; i < 4; ++i)
    #pragma unroll
    for (int j = 0; j < 4; ++j) {
      int col = colb + j * 16;
      #pragma unroll
      for (int r = 0; r < 4; ++r) {
        size_t idx = (size_t)(rowb + i * 16 + r) * FDIM + col;
        float v = acc[i][j][r];
        if (FUSE == 0) outb[idx] = v;
        else {
          float g = gin[idx];
          outb[idx] = g / (1.0f + expf(-g)) * v;       // silu(g)*u
        }
      }
    }
}

// split-2 MoE down GEMM: A = h (f32, split-2 in-kernel), B = wd 2 planes. N=768, K=3072.
__global__ __launch_bounds__(256) void gemm2_dn(const float* __restrict__ hbf,
    const unsigned short* __restrict__ W2, size_t wPS, float* __restrict__ ob,
    const int* __restrict__ offs) {
  __shared__ __align__(16) unsigned short As[2][4096];
  __shared__ __align__(16) unsigned short Bs[2][4096];
  int sb = blockIdx.y * 128;
  if (sb >= offs[8]) return;
  int e = 0;
  #pragma unroll
  for (int i = 1; i < 8; ++i) if (sb >= offs[i]) e = i;
  int tid = threadIdx.x, w = tid >> 6, l = tid & 63, lr = l & 15, lg = l >> 4;
  int n0 = blockIdx.x * 128;
  const unsigned short* WE = W2 + (size_t)e * 768 * FDIM;
  size_t boff = (size_t)(n0 + 32 * w + lr) * FDIM + lg * 8;
  size_t boff1 = boff + (size_t)16 * FDIM;
  const float* ha0 = hbf + (size_t)(sb + 32 * w + lr) * FDIM + lg * 8;
  const float* ha1 = ha0 + (size_t)16 * FDIM;
  f32x4 acc[4][4];
  #pragma unroll
  for (int i = 0; i < 4; ++i)
    #pragma unroll
    for (int j = 0; j < 4; ++j) acc[i][j] = (f32x4){0.f, 0.f, 0.f, 0.f};
  int wr = w >> 1, wc = w & 1;
  for (int k0 = 0; k0 < FDIM; k0 += 32) {
    #pragma unroll
    for (int p = 0; p < 2; ++p) {
      gload16(WE + p * wPS + boff + k0,  &Bs[p][1024 * w]);
      gload16(WE + p * wPS + boff1 + k0, &Bs[p][1024 * w + 512]);
    }
    {
      float4 v0 = *(const float4*)(ha0 + k0);
      float4 v1 = *(const float4*)(ha0 + k0 + 4);
      float va[8] = {v0.x, v0.y, v0.z, v0.w, v1.x, v1.y, v1.z, v1.w};
      short8 sh, sm;
      #pragma unroll
      for (int q = 0; q < 8; ++q) {
        unsigned short a, b;
        split2f(va[q], a, b);
        sh[q] = (short)a; sm[q] = (short)b;
      }
      *(short8*)(&As[0][1024 * w + l * 8]) = sh;
      *(short8*)(&As[1][1024 * w + l * 8]) = sm;
      v0 = *(const float4*)(ha1 + k0);
      v1 = *(const float4*)(ha1 + k0 + 4);
      float vb[8] = {v0.x, v0.y, v0.z, v0.w, v1.x, v1.y, v1.z, v1.w};
      #pragma unroll
      for (int q = 0; q < 8; ++q) {
        unsigned short a, b;
        split2f(vb[q], a, b);
        sh[q] = (short)a; sm[q] = (short)b;
      }
      *(short8*)(&As[0][1024 * w + 512 + l * 8]) = sh;
      *(short8*)(&As[1][1024 * w + 512 + l * 8]) = sm;
    }
    __syncthreads();
    short8 af[2][4], bf[2][4];
    #pragma unroll
    for (int p = 0; p < 2; ++p)
      #pragma unroll
      for (int i = 0; i < 4; ++i) {
        af[p][i] = *(const short8*)(&As[p][(wr * 4 + i) * 512 + l * 8]);
        bf[p][i] = *(const short8*)(&Bs[p][(wc * 4 + i) * 512 + l * 8]);
      }
    MFMA_SPLIT2(acc)
    __syncthreads();
  }
  int colb = n0 + wc * 64 + lr;
  int rowb = sb + wr * 64 + lg * 4;
  #pragma unroll
  for (int i = 0; i < 4; ++i)
    #pragma unroll
    for (int j = 0; j < 4; ++j) {
      int col = colb + j * 16;
      #pragma unroll
      for (int r = 0; r < 4; ++r)
        ob[(size_t)(rowb + i * 16 + r) * 768 + col] = acc[i][j][r];
    }
}

// ---------------------------------------------------------------- layer-1 MoE (plain bf16)
// N-concat gate+up: block col n0<3072 -> x@Wg^T into g-half, else x@Wu^T into u-half.
// Single accumulator (VGPR ~104) -> 16 MFMA / K-step, good occupancy.
__global__ __launch_bounds__(256) void gemm_gu2(const unsigned short* __restrict__ xnb,
    const unsigned short* __restrict__ wgT, const unsigned short* __restrict__ wuT,
    unsigned short* __restrict__ gub, const int* __restrict__ slot_token,
    const int* __restrict__ offs, const unsigned short* __restrict__ zp) {
  __shared__ __align__(16) unsigned short As[4096], Bs[4096];
  int sb = blockIdx.y * 128;
  if (sb >= offs[8]) return;
  int e = 0;
  #pragma unroll
  for (int i = 1; i < 8; ++i) if (sb >= offs[i]) e = i;
  int tid = threadIdx.x, w = tid >> 6, l = tid & 63, lr = l & 15, lg = l >> 4;
  int n0 = blockIdx.x * 128;                           // grid x = 48 -> N=6144
  int nl = (n0 < FDIM) ? n0 : (n0 - FDIM);
  const unsigned short* WE = ((n0 < FDIM) ? wgT : wuT) + (size_t)e * FDIM * 768;
  unsigned short* OB = (n0 < FDIM) ? gub : (gub + (size_t)MAXSLOT * FDIM);
  int t0 = slot_token[sb + 32 * w + lr];
  int t1 = slot_token[sb + 32 * w + 16 + lr];
  const unsigned short* ga0 = (t0 < 0 ? zp : xnb + (size_t)t0 * 768) + lg * 8;
  const unsigned short* ga1 = (t1 < 0 ? zp : xnb + (size_t)t1 * 768) + lg * 8;
  const unsigned short* gb0 = WE + (size_t)(nl + 32 * w + lr) * 768 + lg * 8;
  const unsigned short* gb1 = gb0 + 16 * 768;
  f32x4 acc[4][4];
  #pragma unroll
  for (int i = 0; i < 4; ++i)
    #pragma unroll
    for (int j = 0; j < 4; ++j) acc[i][j] = (f32x4){0.f, 0.f, 0.f, 0.f};
  int wr = w >> 1, wc = w & 1;
  for (int k0 = 0; k0 < 768; k0 += 32) {
    gload16(ga0 + k0, As + 1024 * w);
    gload16(ga1 + k0, As + 1024 * w + 512);
    gload16(gb0 + k0, Bs + 1024 * w);
    gload16(gb1 + k0, Bs + 1024 * w + 512);
    __syncthreads();
    short8 af[4], bf[4];
    #pragma unroll
    for (int i = 0; i < 4; ++i) af[i] = *(const short8*)(As + (wr * 4 + i) * 512 + l * 8);
    #pragma unroll
    for (int j = 0; j < 4; ++j) bf[j] = *(const short8*)(Bs + (wc * 4 + j) * 512 + l * 8);
    #pragma unroll
    for (int i = 0; i < 4; ++i)
      #pragma unroll
      for (int j = 0; j < 4; ++j)
        acc[i][j] = __builtin_amdgcn_mfma_f32_16x16x32_bf16(af[i], bf[j], acc[i][j], 0, 0, 0);
    __syncthreads();
  }
  int colb = nl + wc * 64 + lr;
  int rowb = sb + wr * 64 + lg * 4;
  #pragma unroll
  for (int i = 0; i < 4; ++i)
    #pragma unroll
    for (int j = 0; j < 4; ++j) {
      int col = colb + j * 16;
      #pragma unroll
      for (int r = 0; r < 4; ++r)
        OB[(size_t)(rowb + i * 16 + r) * FDIM + col] = f2bf(acc[i][j][r]);
    }
}

// h = silu(g) * u, bf16 in/out. grid 13824 x 256 (8 elems/thread over MAXSLOT*FDIM)
__global__ void silu_mul_k(const unsigned short* __restrict__ gub,
                           unsigned short* __restrict__ hb) {
  size_t i = ((size_t)blockIdx.x * 256 + threadIdx.x) * 8;
  const unsigned short* u = gub + (size_t)MAXSLOT * FDIM;
  ushort4 g0 = *(const ushort4*)(gub + i);
  ushort4 g1 = *(const ushort4*)(gub + i + 4);
  ushort4 u0 = *(const ushort4*)(u + i);
  ushort4 u1 = *(const ushort4*)(u + i + 4);
  float gf[8] = {bf2f(g0.x), bf2f(g0.y), bf2f(g0.z), bf2f(g0.w),
                 bf2f(g1.x), bf2f(g1.y), bf2f(g1.z), bf2f(g1.w)};
  float uf[8] = {bf2f(u0.x), bf2f(u0.y), bf2f(u0.z), bf2f(u0.w),
                 bf2f(u1.x), bf2f(u1.y), bf2f(u1.z), bf2f(u1.w)};
  ushort4 h0, h1;
  h0.x = f2bf(gf[0] / (1.0f + expf(-gf[0])) * uf[0]);
  h0.y = f2bf(gf[1] / (1.0f + expf(-gf[1])) * uf[1]);
  h0.z = f2bf(gf[2] / (1.0f + expf(-gf[2])) * uf[2]);
  h0.w = f2bf(gf[3] / (1.0f + expf(-gf[3])) * uf[3]);
  h1.x = f2bf(gf[4] / (1.0f + expf(-gf[4])) * uf[4]);
  h1.y = f2bf(gf[5] / (1.0f + expf(-gf[5])) * uf[5]);
  h1.z = f2bf(gf[6] / (1.0f + expf(-gf[6])) * uf[6]);
  h1.w = f2bf(gf[7] / (1.0f + expf(-gf[7])) * uf[7]);
  *(ushort4*)(hb + i) = h0;
  *(ushort4*)(hb + i + 4) = h1;
}

__global__ __launch_bounds__(256) void gemm_d(const unsigned short* __restrict__ hb,
    const unsigned short* __restrict__ wdT, unsigned short* __restrict__ ob,
    const int* __restrict__ offs) {
  __shared__ __align__(16) unsigned short As[4096], Bs[4096];
  int sb = blockIdx.y * 128;
  if (sb >= offs[8]) return;
  int e = 0;
  #pragma unroll
  for (int i = 1; i < 8; ++i) if (sb >= offs[i]) e = i;
  int tid = threadIdx.x, w = tid >> 6, l = tid & 63, lr = l & 15, lg = l >> 4;
  int n0 = blockIdx.x * 128;
  const unsigned short* ga0 = hb + (size_t)(sb + 32 * w + lr) * FDIM + lg * 8;
  const unsigned short* ga1 = ga0 + (size_t)16 * FDIM;
  const unsigned short* WdE = wdT + (size_t)e * 768 * FDIM;
  const unsigned short* gb0 = WdE + (size_t)(n0 + 32 * w + lr) * FDIM + lg * 8;
  const unsigned short* gb1 = gb0 + (size_t)16 * FDIM;
  f32x4 acc[4][4];
  #pragma unroll
  for (int i = 0; i < 4; ++i)
    #pragma unroll
    for (int j = 0; j < 4; ++j) acc[i][j] = (f32x4){0.f, 0.f, 0.f, 0.f};
  int wr = w >> 1, wc = w & 1;
  for (int k0 = 0; k0 < FDIM; k0 += 32) {
    gload16(ga0 + k0, As + 1024 * w);
    gload16(ga1 + k0, As + 1024 * w + 512);
    gload16(gb0 + k0, Bs + 1024 * w);
    gload16(gb1 + k0, Bs + 1024 * w + 512);
    __syncthreads();
    short8 af[4], bf[4];
    #pragma unroll
    for (int i = 0; i < 4; ++i) af[i] = *(const short8*)(As + (wr * 4 + i) * 512 + l * 8);
    #pragma unroll
    for (int j = 0; j < 4; ++j) bf[j] = *(const short8*)(Bs + (wc * 4 + j) * 512 + l * 8);
    #pragma unroll
    for (int i = 0; i < 4; ++i)
      #pragma unroll
      for (int j = 0; j < 4; ++j)
        acc[i][j] = __builtin_amdgcn_mfma_f32_16x16x32_bf16(af[i], bf[j], acc[i][j], 0, 0, 0);
    __syncthreads();
  }
  int colb = n0 + wc * 64 + lr;
  int rowb = sb + wr * 64 + lg * 4;
  #pragma unroll
  for (int i = 0; i < 4; ++i)
    #pragma unroll
    for (int j = 0; j < 4; ++j) {
      int col = colb + j * 16;
      #pragma unroll
      for (int r = 0; r < 4; ++r)
        ob[(size_t)(rowb + i * 16 + r) * 768 + col] = f2bf(acc[i][j][r]);
    }
}

// ---------------------------------------------------------------- attention (f32, register-tiled)
// 64x64 tiles, 4x4 micro-tile/thread, P aliased onto K buffer, causal pair-balanced grid.
__global__ __launch_bounds__(256) void attn_k(const float* __restrict__ qkv,
                                              unsigned short* __restrict__ ax2, size_t pPS) {
  int pr = blockIdx.x, h = blockIdx.y, b = blockIdx.z;
  int tid = threadIdx.x;
  int ty4 = (tid >> 4) << 2, tx4 = (tid & 15) << 2;
  __shared__ float qs[64][68];    // [d][q]
  __shared__ float kps[64][68];   // [d][k] during QK, then [q][k] = P during PV
  __shared__ float vs[64][68];    // [k][d]
  int lr = tid >> 2;              // 0..63 load row
  int lc = (tid & 3) << 4;        // 0,16,32,48 d-chunk
  for (int half = 0; half < 2; ++half) {
    int qt = half ? (15 - pr) : pr;
    int q0 = qt << 6;
    size_t qbase = ((size_t)(b * 1024 + q0 + lr)) * 2304 + h * 64 + lc;
    #pragma unroll
    for (int i = 0; i < 4; ++i) {
      float4 v = *(const float4*)(qkv + qbase + 4 * i);
      qs[lc + 4 * i + 0][lr] = v.x;
      qs[lc + 4 * i + 1][lr] = v.y;
      qs[lc + 4 * i + 2][lr] = v.z;
      qs[lc + 4 * i + 3][lr] = v.w;
    }
    float acc[4][4];
    float m[4], l[4];
    #pragma unroll
    for (int i = 0; i < 4; ++i) {
      m[i] = -3.0e38f; l[i] = 0.0f;
      #pragma unroll
      for (int j = 0; j < 4; ++j) acc[i][j] = 0.0f;
    }
    for (int kt = 0; kt <= qt; ++kt) {
      int k0 = kt << 6;
      __syncthreads();                                  // prev PV / Q-store ordering
      size_t kb = ((size_t)(b * 1024 + k0 + lr)) * 2304 + 768 + h * 64 + lc;
      #pragma unroll
      for (int i = 0; i < 4; ++i) {
        float4 kv = *(const float4*)(qkv + kb + 4 * i);
        kps[lc + 4 * i + 0][lr] = kv.x;
        kps[lc + 4 * i + 1][lr] = kv.y;
        kps[lc + 4 * i + 2][lr] = kv.z;
        kps[lc + 4 * i + 3][lr] = kv.w;
        *(float4*)&vs[lr][lc + 4 * i] = *(const float4*)(qkv + kb + 768 + 4 * i);
      }
      __syncthreads();                                  // K,V visible
      float s[4][4];
      #pragma unroll
      for (int i = 0; i < 4; ++i)
        #pragma unroll
        for (int j = 0; j < 4; ++j) s[i][j] = 0.0f;
      #pragma unroll 8
      for (int d = 0; d < 64; ++d) {
        float4 qv = *(const float4*)&qs[d][ty4];
        float4 kv = *(const float4*)&kps[d][tx4];
        float qa[4] = {qv.x, qv.y, qv.z, qv.w};
        float ka[4] = {kv.x, kv.y, kv.z, kv.w};
        #pragma unroll
        for (int i = 0; i < 4; ++i)
          #pragma unroll
          for (int j = 0; j < 4; ++j) s[i][j] += qa[i] * ka[j];
      }
      bool diag = (kt == qt);
      #pragma unroll
      for (int i = 0; i < 4; ++i) {
        #pragma unroll
        for (int j = 0; j < 4; ++j) {
          if (diag && (tx4 + j > ty4 + i)) s[i][j] = -1.0e30f;
          else s[i][j] *= 0.125f;                       // 1/sqrt(64)
        }
        float mx = fmaxf(fmaxf(s[i][0], s[i][1]), fmaxf(s[i][2], s[i][3]));
        mx = fmaxf(mx, __shfl_xor(mx, 1));
        mx = fmaxf(mx, __shfl_xor(mx, 2));
        mx = fmaxf(mx, __shfl_xor(mx, 4));
        mx = fmaxf(mx, __shfl_xor(mx, 8));
        float mnew = fmaxf(m[i], mx);
        float c = expf(m[i] - mnew);
        float rs = 0.0f;
        #pragma unroll
        for (int j = 0; j < 4; ++j) { s[i][j] = expf(s[i][j] - mnew); rs += s[i][j]; }
        rs += __shfl_xor(rs, 1);
        rs += __shfl_xor(rs, 2);
        rs += __shfl_xor(rs, 4);
        rs += __shfl_xor(rs, 8);
        l[i] = l[i] * c + rs;
        m[i] = mnew;
        #pragma unroll
        for (int j = 0; j < 4; ++j) acc[i][j] *= c;
      }
      __syncthreads();                                  // all QK reads of kps done
      #pragma unroll
      for (int i = 0; i < 4; ++i)
        *(float4*)&kps[ty4 + i][tx4] = make_float4(s[i][0], s[i][1], s[i][2], s[i][3]);
      __syncthreads();                                  // P visible
      #pragma unroll 4
      for (int kk = 0; kk < 16; ++kk) {
        float4 v0 = *(const float4*)&vs[(kk << 2) + 0][tx4];
        float4 v1 = *(const float4*)&vs[(kk << 2) + 1][tx4];
        float4 v2 = *(const float4*)&vs[(kk << 2) + 2][tx4];
        float4 v3 = *(const float4*)&vs[(kk << 2) + 3][tx4];
        #pragma unroll
        for (int i = 0; i < 4; ++i) {
          float4 p4 = *(const float4*)&kps[ty4 + i][kk << 2];
          acc[i][0] += p4.x * v0.x + p4.y * v1.x + p4.z * v2.x + p4.w * v3.x;
          acc[i][1] += p4.x * v0.y + p4.y * v1.y + p4.z * v2.y + p4.w * v3.y;
          acc[i][2] += p4.x * v0.z + p4.y * v1.z + p4.z * v2.z + p4.w * v3.z;
          acc[i][3] += p4.x * v0.w + p4.y * v1.w + p4.z * v2.w + p4.w * v3.w;
        }
      }
    }
    __syncthreads();                                    // PV done before buffers reused
    #pragma unroll
    for (int i = 0; i < 4; ++i) {
      float invl = 1.0f / l[i];
      size_t ob = ((size_t)(b * 1024 + q0 + ty4 + i)) * 768 + h * 64 + tx4;
      ushort4 vh, vm;
      unsigned short a0, a1;
      split2f(acc[i][0] * invl, a0, a1); vh.x = a0; vm.x = a1;
      split2f(acc[i][1] * invl, a0, a1); vh.y = a0; vm.y = a1;
      split2f(acc[i][2] * invl, a0, a1); vh.z = a0; vm.z = a1;
      split2f(acc[i][3] * invl, a0, a1); vh.w = a0; vm.w = a1;
      *(ushort4*)(ax2 + ob) = vh;
      *(ushort4*)(ax2 + pPS + ob) = vm;
    }
  }
}

// ---------------------------------------------------------------- MoE routing (exact f32)
__global__ __launch_bounds__(256) void router_k(const float* __restrict__ xn,
                                                const float* __restrict__ rw,
                                                int* __restrict__ tk_idx, float* __restrict__ tk_w,
                                                int* __restrict__ cnt, float* __restrict__ psum) {
  __shared__ float bps[8];
  __shared__ int bcnt[8];
  int tid = threadIdx.x;
  if (tid < 8) { bps[tid] = 0.0f; bcnt[tid] = 0; }
  __syncthreads();
  int t = blockIdx.x * 4 + (tid >> 6);
  int lane = tid & 63;
  const float* xr = xn + (size_t)t * 768;
  float p[8] = {};
  for (int d = lane; d < 768; d += 64) {
    float xv = xr[d];
    const float* wr = rw + (size_t)d * 8;
    #pragma unroll
    for (int e = 0; e < 8; ++e) p[e] += xv * wr[e];
  }
  #pragma unroll
  for (int e = 0; e < 8; ++e) {
    float v = p[e];
    #pragma unroll
    for (int o = 32; o > 0; o >>= 1) v += __shfl_xor(v, o);
    p[e] = v;
  }
  if (lane == 0) {
    float mx = p[0];
    #pragma unroll
    for (int e = 1; e < 8; ++e) mx = fmaxf(mx, p[e]);
    float s = 0.0f;
    #pragma unroll
    for (int e = 0; e < 8; ++e) { p[e] = expf(p[e] - mx); s += p[e]; }
    float invs = 1.0f / s;
    #pragma unroll
    for (int e = 0; e < 8; ++e) p[e] *= invs;
    int i1 = 0; float v1 = p[0];
    #pragma unroll
    for (int e = 1; e < 8; ++e) if (p[e] > v1) { v1 = p[e]; i1 = e; }
    int i2 = (i1 == 0) ? 1 : 0; float v2 = p[i2];
    #pragma unroll
    for (int e = 0; e < 8; ++e) if (e != i1 && p[e] > v2) { v2 = p[e]; i2 = e; }
    float wsum = v1 + v2;
    tk_idx[t * 2] = i1; tk_idx[t * 2 + 1] = i2;
    tk_w[t * 2] = v1 / wsum; tk_w[t * 2 + 1] = v2 / wsum;
    atomicAdd(&bcnt[i1], 1); atomicAdd(&bcnt[i2], 1);
    #pragma unroll
    for (int e = 0; e < 8; ++e) atomicAdd(&bps[e], p[e]);
  }
  __syncthreads();
  if (tid < 8) {
    atomicAdd(&cnt[tid], bcnt[tid]);
    atomicAdd(&psum[tid], bps[tid]);
  }
}

__global__ void moe_offsets_k(const int* __restrict__ cnt, int* __restrict__ offs,
                              const float* __restrict__ psum, float* __restrict__ aux) {
  if (threadIdx.x == 0) {
    int o = 0; float a = 0.0f;
    for (int e = 0; e < 8; ++e) {
      offs[e] = o;
      o += (cnt[e] + 127) & ~127;
      a += ((float)cnt[e] / 4096.0f) * (psum[e] / 4096.0f);
    }
    offs[8] = o;
    aux[0] += a * 8.0f;
  }
}

__global__ void moe_fill_k(const int* __restrict__ tk_idx, const int* __restrict__ offs,
                           int* __restrict__ fill, int* __restrict__ slot_token,
                           int* __restrict__ tk_slot) {
  int i = blockIdx.x * 256 + threadIdx.x;              // grid 32
  int e = tk_idx[i];
  int pos = atomicAdd(&fill[e], 1);
  int slot = offs[e] + pos;
  slot_token[slot] = i >> 1;
  tk_slot[i] = slot;
}

template <int BF>  // 0: os f32; 1: os bf16
__global__ void moe_combine_k(float* __restrict__ x, const void* __restrict__ osv,
                              const int* __restrict__ tk_slot, const float* __restrict__ tk_w) {
  int t = blockIdx.x;                                  // grid 4096 x 192
  int d = threadIdx.x << 2;
  int s0 = tk_slot[t * 2], s1 = tk_slot[t * 2 + 1];
  float w0 = tk_w[t * 2], w1 = tk_w[t * 2 + 1];
  float a0, a1, a2, a3, b0, b1, b2, b3;
  if (BF == 0) {
    const float* os = (const float*)osv;
    float4 a = *(const float4*)(os + (size_t)s0 * 768 + d);
    float4 b = *(const float4*)(os + (size_t)s1 * 768 + d);
    a0 = a.x; a1 = a.y; a2 = a.z; a3 = a.w;
    b0 = b.x; b1 = b.y; b2 = b.z; b3 = b.w;
  } else {
    const unsigned short* os = (const unsigned short*)osv;
    ushort4 a = *(const ushort4*)(os + (size_t)s0 * 768 + d);
    ushort4 b = *(const ushort4*)(os + (size_t)s1 * 768 + d);
    a0 = bf2f(a.x); a1 = bf2f(a.y); a2 = bf2f(a.z); a3 = bf2f(a.w);
    b0 = bf2f(b.x); b1 = bf2f(b.y); b2 = bf2f(b.z); b3 = bf2f(b.w);
  }
  float4 c = *(const float4*)(x + (size_t)t * 768 + d);
  c.x += w0 * a0 + w1 * b0;
  c.y += w0 * a1 + w1 * b1;
  c.z += w0 * a2 + w1 * b2;
  c.w += w0 * a3 + w1 * b3;
  *(float4*)(x + (size_t)t * 768 + d) = c;
}

__global__ void write_aux_k(const float* __restrict__ aux, float* __restrict__ out) {
  out[0] = aux[0];
}

// ---------------------------------------------------------------- host launcher

extern "C" void kernel_launch(void* const* d_in, const int* in_sizes, int n_in,
                              void* d_out, int out_size, void* d_ws, size_t ws_size,
                              hipStream_t stream) {
  const int* input_ids      = (const int*)d_in[0];
  const int* time_slots     = (const int*)d_in[1];
  const int* day_of_week    = (const int*)d_in[2];
  const int* month          = (const int*)d_in[3];
  const int* is_holiday     = (const int*)d_in[4];
  const int* location_ids   = (const int*)d_in[5];
  const int* road_types     = (const int*)d_in[6];
  const int* weather_states = (const int*)d_in[7];
  const float* word_emb     = (const float*)d_in[8];
  const float* time_emb     = (const float*)d_in[9];
  const float* dow_emb      = (const float*)d_in[10];
  const float* month_emb    = (const float*)d_in[11];
  const float* hol_emb      = (const float*)d_in[12];
  const float* loc_emb      = (const float*)d_in[13];
  const float* road_emb     = (const float*)d_in[14];
  const float* weather_emb  = (const float*)d_in[15];
  const float* proj_w       = (const float*)d_in[16];
  const float* proj_b       = (const float*)d_in[17];
  const float* emb_norm_w   = (const float*)d_in[18];
  const float* norm1_w      = (const float*)d_in[19];
  const float* Wq           = (const float*)d_in[20];
  const float* Wk           = (const float*)d_in[21];
  const float* Wv           = (const float*)d_in[22];
  const float* Wo           = (const float*)d_in[23];
  const float* norm2_w      = (const float*)d_in[24];
  const float* router_w     = (const float*)d_in[25];
  const float* Wg           = (const float*)d_in[26];
  const float* Wu           = (const float*)d_in[27];
  const float* Wd           = (const float*)d_in[28];
  const float* final_norm_w = (const float*)d_in[29];
  float* out = (float*)d_out;

  const size_t TD = (size_t)TTOK * 768;
  const size_t REG = (size_t)MAXSLOT * FDIM * 4;       // 113.25 MB shared regions
  char* base = (char*)d_ws;
  auto carve = [&](size_t bytes) { char* p = base; base += (bytes + 255) & ~(size_t)255; return p; };
  float* x    = (float*)carve(TD * 4);
  float* xn   = (float*)carve(TD * 4);
  float* cosb = (float*)carve(32768 * 4);
  float* sinb = (float*)carve(32768 * 4);
  float* ctx  = (float*)carve(4 * 1536 * 4);
  float* biasB= (float*)carve(4 * 768 * 4);
  float* tkw  = (float*)carve(8192 * 4);
  float* psum = (float*)carve(64);
  float* auxa = (float*)carve(64);
  int* cnt    = (int*)carve(64);
  int* fill   = (int*)carve(64);
  int* offs   = (int*)carve(64);
  int* tk_idx = (int*)carve(8192 * 4);
  int* tk_slot= (int*)carve(8192 * 4);
  int* slot_token = (int*)carve(MAXSLOT * 4);
  unsigned short* zp = (unsigned short*)carve(4096);
  unsigned short* xnb3 = (unsigned short*)carve(3 * TD * 2);
  char* QAH = carve(REG);                               // qkv+ax2 (attn) / h (moe)
  char* GT  = carve(REG);                               // gtmp / g|u halves / ob
  char* Wr  = carve(REG);                               // weight planes (sequential)
  float* qkv = (float*)QAH;
  unsigned short* ax2 = (unsigned short*)(QAH + (size_t)TTOK * 2304 * 4);
  float* hbf = (float*)QAH;
  unsigned short* hb16 = (unsigned short*)QAH;
  float* gtmp = (float*)GT;
  float* obf = (float*)GT;
  unsigned short* gu16 = (unsigned short*)GT;           // L1: g at [0], u at +MAXSLOT*FDIM
  unsigned short* ob16 = (unsigned short*)GT;
  unsigned short* wpl = (unsigned short*)Wr;

  const size_t PS_D = (size_t)768 * 768;                // dense 768x768 plane stride
  const size_t PS_QKV = (size_t)2304 * 768;
  const size_t PS_E = (size_t)8 * FDIM * 768;           // expert-tensor plane stride

  hipMemsetAsync(auxa, 0, 64, stream);
  hipMemsetAsync(zp, 0, 4096, stream);
  rope_cache_k<<<dim3(1024), dim3(32), 0, stream>>>(cosb, sinb);
  build_ctx_k<<<dim3(4, 6), dim3(256), 0, stream>>>(time_slots, day_of_week, month, is_holiday,
      location_ids, road_types, weather_states, time_emb, dow_emb, month_emb, hol_emb,
      loc_emb, road_emb, weather_emb, ctx);
  build_bias_k<<<dim3(4, 3), dim3(256), 0, stream>>>(ctx, proj_w, proj_b, biasB);
  tconv3_k<<<dim3(24, 24, 1), dim3(32, 8), 0, stream>>>(proj_w, wpl, PS_D, 768, 768, 0, 0);
  gconv3_k<<<dim3(TTOK), dim3(192), 0, stream>>>(word_emb, input_ids, xnb3, TD);
  gemm3<3><<<dim3(6, 32), dim3(256), 0, stream>>>(xnb3, TD, wpl, PS_D, xn, 768, 768, biasB);
  rmsnorm_k<0><<<dim3(TTOK), dim3(256), 0, stream>>>(xn, emb_norm_w, x, nullptr, 0);

  for (int l = 0; l < 2; ++l) {
    const float* rw = router_w + (size_t)l * 768 * 8;
    // ---- attention (split-2 GEMMs, f32 flash core) ----
    tconv2_k<<<dim3(24, 24, 1), dim3(32, 8), 0, stream>>>(Wq + (size_t)l * PS_D, wpl, PS_QKV, 768, 768, 0, 0);
    tconv2_k<<<dim3(24, 24, 1), dim3(32, 8), 0, stream>>>(Wk + (size_t)l * PS_D, wpl + PS_D, PS_QKV, 768, 768, 0, 0);
    tconv2_k<<<dim3(24, 24, 1), dim3(32, 8), 0, stream>>>(Wv + (size_t)l * PS_D, wpl + 2 * PS_D, PS_QKV, 768, 768, 0, 0);
    rmsnorm_k<1><<<dim3(TTOK), dim3(256), 0, stream>>>(x, norm1_w + l * 768, nullptr, xnb3, TD);
    gemm2<0><<<dim3(18, 32), dim3(256), 0, stream>>>(xnb3, TD, wpl, PS_QKV, qkv, 2304, 768);
    rope_apply_k<<<dim3(6144), dim3(256), 0, stream>>>(qkv, cosb, sinb);
    attn_k<<<dim3(8, 12, 4), dim3(256), 0, stream>>>(qkv, ax2, TD);
    tconv2_k<<<dim3(24, 24, 1), dim3(32, 8), 0, stream>>>(Wo + (size_t)l * PS_D, wpl, PS_D, 768, 768, 0, 0);
    gemm2<2><<<dim3(6, 32), dim3(256), 0, stream>>>(ax2, TD, wpl, PS_D, x, 768, 768);

    // ---- MoE ----
    if (l == 0)
      rmsnorm_k<2><<<dim3(TTOK), dim3(256), 0, stream>>>(x, norm2_w, xn, xnb3, TD);
    else
      rmsnorm_k<3><<<dim3(TTOK), dim3(256), 0, stream>>>(x, norm2_w + 768, xn, xnb3, TD);
    hipMemsetAsync(cnt, 0, 64, stream);
    hipMemsetAsync(fill, 0, 64, stream);
    hipMemsetAsync(psum, 0, 64, stream);
    hipMemsetAsync(slot_token, 0xFF, MAXSLOT * 4, stream);
    router_k<<<dim3(1024), dim3(256), 0, stream>>>(xn, rw, tk_idx, tkw, cnt, psum);
    moe_offsets_k<<<dim3(1), dim3(64), 0, stream>>>(cnt, offs, psum, auxa);
    moe_fill_k<<<dim3(32), dim3(256), 0, stream>>>(tk_idx, offs, fill, slot_token, tk_slot);
    if (l == 0) {
      // split-2 experts (~17-bit, round-4 validated)
      tconv2_k<<<dim3(96, 24, 8), dim3(32, 8), 0, stream>>>(Wg, wpl, PS_E,
          768, FDIM, (size_t)768 * FDIM, (size_t)FDIM * 768);
      gemm2_gu<0><<<dim3(24, MAXSLOT / 128), dim3(256), 0, stream>>>(xnb3, TD, wpl, PS_E,
          gtmp, nullptr, slot_token, offs, zp);
      tconv2_k<<<dim3(96, 24, 8), dim3(32, 8), 0, stream>>>(Wu, wpl, PS_E,
          768, FDIM, (size_t)768 * FDIM, (size_t)FDIM * 768);
      gemm2_gu<1><<<dim3(24, MAXSLOT / 128), dim3(256), 0, stream>>>(xnb3, TD, wpl, PS_E,
          hbf, gtmp, slot_token, offs, zp);
      tconv2_k<<<dim3(24, 96, 8), dim3(32, 8), 0, stream>>>(Wd, wpl, PS_E,
          FDIM, 768, (size_t)FDIM * 768, (size_t)768 * FDIM);
      gemm2_dn<<<dim3(6, MAXSLOT / 128), dim3(256), 0, stream>>>(hbf, wpl, PS_E, obf, offs);
      moe_combine_k<0><<<dim3(TTOK), dim3(192), 0, stream>>>(x, obf, tk_slot, tkw);
    } else {
      // plain bf16 experts: N-concat single-acc GEMM + silu_mul + down
      const float* wg1 = Wg + (size_t)8 * 768 * FDIM;
      const float* wu1 = Wu + (size_t)8 * 768 * FDIM;
      const float* wd1 = Wd + (size_t)8 * FDIM * 768;
      tconv_k<<<dim3(96, 24, 8), dim3(32, 8), 0, stream>>>(wg1, wpl,
          768, FDIM, (size_t)768 * FDIM, (size_t)FDIM * 768);
      tconv_k<<<dim3(96, 24, 8), dim3(32, 8), 0, stream>>>(wu1, wpl + PS_E,
          768, FDIM, (size_t)768 * FDIM, (size_t)FDIM * 768);
      gemm_gu2<<<dim3(48, MAXSLOT / 128), dim3(256), 0, stream>>>(xnb3, wpl, wpl + PS_E,
          gu16, slot_token, offs, zp);
      silu_mul_k<<<dim3((int)((size_t)MAXSLOT * FDIM / 2048)), dim3(256), 0, stream>>>(gu16, hb16);
      tconv_k<<<dim3(24, 96, 8), dim3(32, 8), 0, stream>>>(wd1, wpl,
          FDIM, 768, (size_t)FDIM * 768, (size_t)768 * FDIM);
      gemm_d<<<dim3(6, MAXSLOT / 128), dim3(256), 0, stream>>>(hb16, wpl, ob16, offs);
      moe_combine_k<1><<<dim3(TTOK), dim3(192), 0, stream>>>(x, ob16, tk_slot, tkw);
    }
  }

  rmsnorm_k<0><<<dim3(TTOK), dim3(256), 0, stream>>>(x, final_norm_w, out, nullptr, 0);
  write_aux_k<<<dim3(1), dim3(1), 0, stream>>>(auxa, out + TD);
}